// Round 4
// baseline (10464.789 us; speedup 1.0000x reference)
//
#include <hip/hip_runtime.h>
#include <hip/hip_bf16.h>

#define TWO_PI_F 6.2831853071795864769f

__device__ __forceinline__ float bf2f_raw(unsigned short u) {
    return __uint_as_float(((unsigned int)u) << 16);
}
__device__ __forceinline__ unsigned short f2bf(float f) {
    unsigned int u = __float_as_uint(f);
    unsigned int r = (u + 0x7FFFu + ((u >> 16) & 1u)) >> 16;   // RNE
    return (unsigned short)r;
}
// runtime-dtype external input load (wave-uniform f32 flag)
__device__ __forceinline__ float loadIn(const void* p, size_t i, bool f32) {
    return f32 ? ((const float*)p)[i] : bf2f_raw(((const unsigned short*)p)[i]);
}

// ---------------- ws layout ----------------
// fp32 region (float offsets from (float*)d_ws):
static constexpr size_t OFF_WC0 = 0;          // cod_w0  3072
static constexpr size_t OFF_WC1 = 3072;       // cod_w1  131072
static constexpr size_t OFF_WC2 = 134144;     // cod_w2  131072
static constexpr size_t OFF_WG0 = 265216;     // gen_w0  688128
static constexpr size_t OFF_WG1 = 953344;     // gen_w1  524288
static constexpr size_t OFF_WG2 = 1477632;    // gen_w2  6144
static constexpr size_t OFF_P   = 1483776;    // small params
static constexpr size_t OFF_CB0 = OFF_P + 0;
static constexpr size_t OFF_CG0 = OFF_P + 64;
static constexpr size_t OFF_CBE0= OFF_P + 128;
static constexpr size_t OFF_CB1 = OFF_P + 192;
static constexpr size_t OFF_CG1 = OFF_P + 320;
static constexpr size_t OFF_CBE1= OFF_P + 448;
static constexpr size_t OFF_CB2 = OFF_P + 576;
static constexpr size_t OFF_GB0 = OFF_P + 640;
static constexpr size_t OFF_GG0 = OFF_P + 896;
static constexpr size_t OFF_GBE0= OFF_P + 1152;
static constexpr size_t OFF_GB1 = OFF_P + 1408;
static constexpr size_t OFF_GG1 = OFF_P + 1536;
static constexpr size_t OFF_GBE1= OFF_P + 1664;
static constexpr size_t OFF_GB2 = OFF_P + 1792; // 3
static constexpr size_t OFF_SSUM  = 1485824;    // 576
static constexpr size_t OFF_SSQ   = OFF_SSUM + 576;
static constexpr size_t OFF_SCALE = OFF_SSUM + 1152;
static constexpr size_t OFF_SHIFT = OFF_SCALE + 576;
static constexpr size_t OFF_K12   = OFF_SHIFT + 576;  // 1024 floats
static constexpr size_t OFF_FLAG  = OFF_K12 + 1024;   // 16 floats (flag in [0])
// fp32 region ends at 1489168 floats == 2978336 ushorts.
// bf16 region (ushort offsets from (unsigned short*)d_ws):
static constexpr size_t UZ = 2978336;               // Z: 64*168*256 = 2752512
static constexpr size_t UX = UZ + 2752512;          // X: max 64*256*32*32 = 16777216
static constexpr size_t UY = UX + 16777216;         // Y: max 64*128*64*64 = 33554432
static constexpr size_t WS_END_USHORT = UY + 33554432;
static constexpr size_t WS_NEED_BYTES = WS_END_USHORT * 2;   // ~112.1 MB

// stat slot offsets per BN layer: L0:0(64) L1:64(128) G0:192(256) G1:448(128)

// ---------------- input dtype detection ----------------
// bf16 N(0,1) data: exponent field never >= 0xC0 (|v| >= 2^65).
// fp32 data read as ushorts: low halves are mantissa bits -> ~25% hit rate.
__global__ void detect_kernel(const unsigned short* __restrict__ imgs, int* __restrict__ flag) {
    int t = threadIdx.x;  // 256
    unsigned short u = imgs[t];
    int e = (u >> 7) & 0xFF;
    unsigned long long b = __ballot(e >= 0xC0);
    __shared__ int cnt[4];
    if ((t & 63) == 0) cnt[t >> 6] = __popcll(b);
    __syncthreads();
    if (t == 0) flag[0] = (cnt[0] + cnt[1] + cnt[2] + cnt[3] >= 4) ? 1 : 0;
}

// ---------------- weight/param -> fp32 conversion ----------------
struct CvtJobs {
    const void* src[20];
    float* dst[20];
    int off[21];
};

__global__ void cvt_all_kernel(CvtJobs J, int total, const int* __restrict__ flg) {
    int i = blockIdx.x * 256 + threadIdx.x;
    if (i >= total) return;
    bool f32 = flg[0] != 0;
    int k = 0;
#pragma unroll
    for (int t = 0; t < 19; ++t) { if (i >= J.off[t + 1]) k = t + 1; }
    int r = i - J.off[k];
    J.dst[k][r] = loadIn(J.src[k], r, f32);
}

__global__ void zero_kernel(float* p, int n) {
    int i = blockIdx.x * 256 + threadIdx.x;
    if (i < n) p[i] = 0.f;
}

// ---------------- tiny MLP ----------------
__global__ void mlp_kernel(const void* __restrict__ Zg,
                           const void* __restrict__ lW, const void* __restrict__ lb,
                           const void* __restrict__ l1W, const void* __restrict__ l1b,
                           const void* __restrict__ l2W, const void* __restrict__ l2b,
                           float* __restrict__ K12, const int* __restrict__ flg) {
    bool f32 = flg[0] != 0;
    int b = blockIdx.x;
    int t = threadIdx.x;  // 64 threads
    __shared__ float xs[64];
    float acc = loadIn(lb, t, f32);
    for (int c = 0; c < 64; ++c)
        acc += loadIn(Zg, (size_t)(b * 64 + c) * 256, f32) * loadIn(lW, t * 64 + c, f32);
    xs[t] = fmaxf(acc, 0.f);
    __syncthreads();
    if (t < 16) {
        int p = t & 7;
        const void* Wp = (t < 8) ? l1W : l2W;
        const void* bp = (t < 8) ? l1b : l2b;
        float a = loadIn(bp, p, f32);
        for (int h = 0; h < 64; ++h) a += xs[h] * loadIn(Wp, p * 64 + h, f32);
        K12[b * 16 + t] = a;
    }
}

// ---------------- stride-2 conv (k=4,p=1), 2x2 quad/thread, +stats ----------------
__global__ void conv_s2_bn_kernel(const void* __restrict__ in, const float* __restrict__ w,
                                  const float* __restrict__ bias, unsigned short* __restrict__ out,
                                  float* __restrict__ ssum, float* __restrict__ ssq, int statoff,
                                  int IC, int IH, int IW, int OC, int OH, int OW, int tilesX,
                                  const int* __restrict__ flg, int useFlag) {
    bool f32 = useFlag && (flg[0] != 0);
    int b = blockIdx.z;
    int oc = blockIdx.y;
    int tX = blockIdx.x % tilesX;
    int tY = blockIdx.x / tilesX;
    int qx = tX * 16 + (threadIdx.x & 15);
    int qy = tY * 16 + (threadIdx.x >> 4);
    int iy0 = 4 * qy - 1;
    int ix0 = 4 * qx - 1;
    float a00 = 0.f, a01 = 0.f, a10 = 0.f, a11 = 0.f;
    for (int ic = 0; ic < IC; ++ic) {
        const float* wp = w + ((size_t)(oc * IC + ic) << 4);
        float wk[16];
#pragma unroll
        for (int t = 0; t < 16; ++t) wk[t] = wp[t];
        size_t base = (size_t)(b * IC + ic) * IH * IW;
        float v[6][6];
#pragma unroll
        for (int r = 0; r < 6; ++r) {
            int iy = iy0 + r;
            bool rv = (iy >= 0) & (iy < IH);
#pragma unroll
            for (int c = 0; c < 6; ++c) {
                int ix = ix0 + c;
                bool ok = rv & (ix >= 0) & (ix < IW);
                v[r][c] = ok ? loadIn(in, base + iy * IW + ix, f32) : 0.f;
            }
        }
#pragma unroll
        for (int ky = 0; ky < 4; ++ky)
#pragma unroll
            for (int kx = 0; kx < 4; ++kx) {
                float wv = wk[ky * 4 + kx];
                a00 = fmaf(v[ky][kx], wv, a00);
                a01 = fmaf(v[ky][kx + 2], wv, a01);
                a10 = fmaf(v[ky + 2][kx], wv, a10);
                a11 = fmaf(v[ky + 2][kx + 2], wv, a11);
            }
    }
    float bv = bias[oc];
    a00 += bv; a01 += bv; a10 += bv; a11 += bv;
    int oy = 2 * qy, ox = 2 * qx;
    size_t ob = (size_t)(b * OC + oc) * OH * OW;
    out[ob + (size_t)oy * OW + ox] = f2bf(a00);
    out[ob + (size_t)oy * OW + ox + 1] = f2bf(a01);
    out[ob + (size_t)(oy + 1) * OW + ox] = f2bf(a10);
    out[ob + (size_t)(oy + 1) * OW + ox + 1] = f2bf(a11);
    float s = a00 + a01 + a10 + a11;
    float q = a00 * a00 + a01 * a01 + a10 * a10 + a11 * a11;
#pragma unroll
    for (int o = 32; o > 0; o >>= 1) { s += __shfl_down(s, o); q += __shfl_down(q, o); }
    __shared__ float rs[4], rq[4];
    int wv_ = threadIdx.x >> 6, ln = threadIdx.x & 63;
    if (ln == 0) { rs[wv_] = s; rq[wv_] = q; }
    __syncthreads();
    if (threadIdx.x == 0) {
        atomicAdd(&ssum[statoff + oc], rs[0] + rs[1] + rs[2] + rs[3]);
        atomicAdd(&ssq[statoff + oc], rq[0] + rq[1] + rq[2] + rq[3]);
    }
}

// ---------------- conv2 + tanh -> Z channels [0,64) (IC=128, 32x32 -> 16x16) ----------------
__global__ void conv_s2_tanh_z(const unsigned short* __restrict__ in, const float* __restrict__ w,
                               const float* __restrict__ bias, unsigned short* __restrict__ z) {
    const int IC = 128, IH = 32, IW = 32;
    int b = blockIdx.z, oc = blockIdx.y;
    int qx = threadIdx.x & 7, qy = threadIdx.x >> 3;  // 64 threads
    int iy0 = 4 * qy - 1, ix0 = 4 * qx - 1;
    float a00 = 0.f, a01 = 0.f, a10 = 0.f, a11 = 0.f;
    for (int ic = 0; ic < IC; ++ic) {
        const float* wp = w + ((size_t)(oc * IC + ic) << 4);
        float wk[16];
#pragma unroll
        for (int t = 0; t < 16; ++t) wk[t] = wp[t];
        size_t base = (size_t)(b * IC + ic) * IH * IW;
        float v[6][6];
#pragma unroll
        for (int r = 0; r < 6; ++r) {
            int iy = iy0 + r;
            bool rv = (iy >= 0) & (iy < IH);
#pragma unroll
            for (int c = 0; c < 6; ++c) {
                int ix = ix0 + c;
                bool ok = rv & (ix >= 0) & (ix < IW);
                v[r][c] = ok ? bf2f_raw(in[base + iy * IW + ix]) : 0.f;
            }
        }
#pragma unroll
        for (int ky = 0; ky < 4; ++ky)
#pragma unroll
            for (int kx = 0; kx < 4; ++kx) {
                float wv = wk[ky * 4 + kx];
                a00 = fmaf(v[ky][kx], wv, a00);
                a01 = fmaf(v[ky][kx + 2], wv, a01);
                a10 = fmaf(v[ky + 2][kx], wv, a10);
                a11 = fmaf(v[ky + 2][kx + 2], wv, a11);
            }
    }
    float bv = bias[oc];
    int oy = 2 * qy, ox = 2 * qx;
    size_t ob = ((size_t)(b * 168 + oc)) * 256;
    z[ob + oy * 16 + ox]           = f2bf(tanhf(a00 + bv));
    z[ob + oy * 16 + ox + 1]       = f2bf(tanhf(a01 + bv));
    z[ob + (oy + 1) * 16 + ox]     = f2bf(tanhf(a10 + bv));
    z[ob + (oy + 1) * 16 + ox + 1] = f2bf(tanhf(a11 + bv));
}

// ---------------- assemble Z channels [64,168) ----------------
__global__ void assemble_z(const void* __restrict__ Zl, const void* __restrict__ Zg,
                           const void* __restrict__ phi, const float* __restrict__ K12,
                           unsigned short* __restrict__ Z, const int* __restrict__ flg) {
    bool f32 = flg[0] != 0;
    int i = blockIdx.x * 256 + threadIdx.x;
    const int TOT = 64 * 104 * 256;
    if (i >= TOT) return;
    int pos = i & 255;
    int t = i >> 8;
    int c104 = t % 104;
    int b = t / 104;
    float val;
    if (c104 < 32) {
        val = loadIn(Zl, ((size_t)(b * 32 + c104) << 8) + pos, f32);
    } else if (c104 < 96) {
        val = loadIn(Zg, ((size_t)(b * 64 + (c104 - 32)) << 8) + pos, f32);
    } else {
        int p = c104 - 96;
        int y = pos >> 4, x = pos & 15;
        float k1 = K12[b * 16 + p];
        float k2 = K12[b * 16 + 8 + p];
        val = sinf(k1 * (float)y + k2 * (float)x + loadIn(phi, b * 8 + p, f32) * TWO_PI_F);
    }
    Z[((size_t)(b * 168 + 64 + c104) << 8) + pos] = f2bf(val);
}

// ---------------- transposed conv stride2 (k=4,p=1), bf16 in/out, +stats ----------------
__global__ void deconv_s2_bn_kernel(const unsigned short* __restrict__ in, const float* __restrict__ w,
                                    const float* __restrict__ bias, unsigned short* __restrict__ out,
                                    float* __restrict__ ssum, float* __restrict__ ssq, int statoff,
                                    int IC, int IH, int IW, int OC, int OH, int OW, int tilesX) {
    int b = blockIdx.z, oc = blockIdx.y;
    int tX = blockIdx.x % tilesX, tY = blockIdx.x / tilesX;
    int qx = tX * 16 + (threadIdx.x & 15);
    int qy = tY * 16 + (threadIdx.x >> 4);
    float a00 = 0.f, a01 = 0.f, a10 = 0.f, a11 = 0.f;
    for (int ic = 0; ic < IC; ++ic) {
        const float* wp = w + ((size_t)(ic * OC + oc) << 4);  // w[ic][oc][ky][kx]
        float wk[16];
#pragma unroll
        for (int t = 0; t < 16; ++t) wk[t] = wp[t];
        size_t base = (size_t)(b * IC + ic) * IH * IW;
        float v[3][3];
#pragma unroll
        for (int r = 0; r < 3; ++r) {
            int iy = qy - 1 + r;
            bool rv = (iy >= 0) & (iy < IH);
#pragma unroll
            for (int c = 0; c < 3; ++c) {
                int ix = qx - 1 + c;
                bool ok = rv & (ix >= 0) & (ix < IW);
                v[r][c] = ok ? bf2f_raw(in[base + iy * IW + ix]) : 0.f;
            }
        }
        a00 = fmaf(v[1][1], wk[5],  a00); a00 = fmaf(v[1][0], wk[7],  a00);
        a00 = fmaf(v[0][1], wk[13], a00); a00 = fmaf(v[0][0], wk[15], a00);
        a01 = fmaf(v[1][2], wk[4],  a01); a01 = fmaf(v[1][1], wk[6],  a01);
        a01 = fmaf(v[0][2], wk[12], a01); a01 = fmaf(v[0][1], wk[14], a01);
        a10 = fmaf(v[2][1], wk[1],  a10); a10 = fmaf(v[2][0], wk[3],  a10);
        a10 = fmaf(v[1][1], wk[9],  a10); a10 = fmaf(v[1][0], wk[11], a10);
        a11 = fmaf(v[2][2], wk[0],  a11); a11 = fmaf(v[2][1], wk[2],  a11);
        a11 = fmaf(v[1][2], wk[8],  a11); a11 = fmaf(v[1][1], wk[10], a11);
    }
    float bv = bias[oc];
    a00 += bv; a01 += bv; a10 += bv; a11 += bv;
    int oy = 2 * qy, ox = 2 * qx;
    size_t ob = (size_t)(b * OC + oc) * OH * OW;
    out[ob + (size_t)oy * OW + ox] = f2bf(a00);
    out[ob + (size_t)oy * OW + ox + 1] = f2bf(a01);
    out[ob + (size_t)(oy + 1) * OW + ox] = f2bf(a10);
    out[ob + (size_t)(oy + 1) * OW + ox + 1] = f2bf(a11);
    float s = a00 + a01 + a10 + a11;
    float q = a00 * a00 + a01 * a01 + a10 * a10 + a11 * a11;
#pragma unroll
    for (int o = 32; o > 0; o >>= 1) { s += __shfl_down(s, o); q += __shfl_down(q, o); }
    __shared__ float rs[4], rq[4];
    int wv_ = threadIdx.x >> 6, ln = threadIdx.x & 63;
    if (ln == 0) { rs[wv_] = s; rq[wv_] = q; }
    __syncthreads();
    if (threadIdx.x == 0) {
        atomicAdd(&ssum[statoff + oc], rs[0] + rs[1] + rs[2] + rs[3]);
        atomicAdd(&ssq[statoff + oc], rq[0] + rq[1] + rq[2] + rq[3]);
    }
}

// ---------------- final transposed conv + tanh -> FP32 out (reference output dtype) ----------------
__global__ void deconv_s2_tanh_out(const unsigned short* __restrict__ in, const float* __restrict__ w,
                                   const float* __restrict__ bias, float* __restrict__ outp) {
    const int IC = 128, IH = 64, IW = 64, OC = 3, OH = 128, OW = 128;
    int b = blockIdx.z, oc = blockIdx.y;
    int tX = blockIdx.x & 3, tY = blockIdx.x >> 2;
    int qx = tX * 16 + (threadIdx.x & 15);
    int qy = tY * 16 + (threadIdx.x >> 4);
    float a00 = 0.f, a01 = 0.f, a10 = 0.f, a11 = 0.f;
    for (int ic = 0; ic < IC; ++ic) {
        const float* wp = w + ((size_t)(ic * OC + oc) << 4);
        float wk[16];
#pragma unroll
        for (int t = 0; t < 16; ++t) wk[t] = wp[t];
        size_t base = (size_t)(b * IC + ic) * IH * IW;
        float v[3][3];
#pragma unroll
        for (int r = 0; r < 3; ++r) {
            int iy = qy - 1 + r;
            bool rv = (iy >= 0) & (iy < IH);
#pragma unroll
            for (int c = 0; c < 3; ++c) {
                int ix = qx - 1 + c;
                bool ok = rv & (ix >= 0) & (ix < IW);
                v[r][c] = ok ? bf2f_raw(in[base + iy * IW + ix]) : 0.f;
            }
        }
        a00 = fmaf(v[1][1], wk[5],  a00); a00 = fmaf(v[1][0], wk[7],  a00);
        a00 = fmaf(v[0][1], wk[13], a00); a00 = fmaf(v[0][0], wk[15], a00);
        a01 = fmaf(v[1][2], wk[4],  a01); a01 = fmaf(v[1][1], wk[6],  a01);
        a01 = fmaf(v[0][2], wk[12], a01); a01 = fmaf(v[0][1], wk[14], a01);
        a10 = fmaf(v[2][1], wk[1],  a10); a10 = fmaf(v[2][0], wk[3],  a10);
        a10 = fmaf(v[1][1], wk[9],  a10); a10 = fmaf(v[1][0], wk[11], a10);
        a11 = fmaf(v[2][2], wk[0],  a11); a11 = fmaf(v[2][1], wk[2],  a11);
        a11 = fmaf(v[1][2], wk[8],  a11); a11 = fmaf(v[1][1], wk[10], a11);
    }
    float bv = bias[oc];
    int oy = 2 * qy, ox = 2 * qx;
    size_t ob = (size_t)(b * OC + oc) * OH * OW;
    outp[ob + (size_t)oy * OW + ox]           = tanhf(a00 + bv);
    outp[ob + (size_t)oy * OW + ox + 1]       = tanhf(a01 + bv);
    outp[ob + (size_t)(oy + 1) * OW + ox]     = tanhf(a10 + bv);
    outp[ob + (size_t)(oy + 1) * OW + ox + 1] = tanhf(a11 + bv);
}

// ---------------- BN finalize ----------------
__global__ void bn_fin_kernel(const float* __restrict__ ssum, const float* __restrict__ ssq,
                              const float* __restrict__ g, const float* __restrict__ be,
                              float* __restrict__ scale, float* __restrict__ shift,
                              int statoff, int C, float invN) {
    int c = threadIdx.x;
    if (c >= C) return;
    float m = ssum[statoff + c] * invN;
    float v = ssq[statoff + c] * invN - m * m;
    v = fmaxf(v, 0.f);
    float sc = g[c] * rsqrtf(v + 1e-5f);
    scale[statoff + c] = sc;
    shift[statoff + c] = be[c] - m * sc;
}

// ---------------- in-place BN affine + (leaky)relu on bf16 ----------------
__global__ void bn_act_kernel(unsigned short* __restrict__ x, const float* __restrict__ scale,
                              const float* __restrict__ shift, int statoff,
                              int n4, int hwShift, int cMask, float slope) {
    int i = blockIdx.x * 256 + threadIdx.x;
    if (i >= n4) return;
    int i4 = i << 2;
    int c = (i4 >> hwShift) & cMask;
    float sc = scale[statoff + c], sh = shift[statoff + c];
    ushort4 v = *reinterpret_cast<ushort4*>(x + i4);
    float f0 = bf2f_raw(v.x) * sc + sh; f0 = f0 > 0.f ? f0 : slope * f0;
    float f1 = bf2f_raw(v.y) * sc + sh; f1 = f1 > 0.f ? f1 : slope * f1;
    float f2 = bf2f_raw(v.z) * sc + sh; f2 = f2 > 0.f ? f2 : slope * f2;
    float f3 = bf2f_raw(v.w) * sc + sh; f3 = f3 > 0.f ? f3 : slope * f3;
    v.x = f2bf(f0); v.y = f2bf(f1); v.z = f2bf(f2); v.w = f2bf(f3);
    *reinterpret_cast<ushort4*>(x + i4) = v;
}

extern "C" void kernel_launch(void* const* d_in, const int* in_sizes, int n_in,
                              void* d_out, int out_size, void* d_ws, size_t ws_size,
                              hipStream_t stream) {
    // diagnostic guard: workspace too small -> zeros (signature absmax ~0.976)
    if (ws_size < WS_NEED_BYTES) {
        hipMemsetAsync(d_out, 0, (size_t)out_size * 4, stream);
        return;
    }

    float* W = (float*)d_ws;
    unsigned short* U = (unsigned short*)d_ws;
    int* FLG = (int*)(W + OFF_FLAG);

    // ---- detect input dtype (fp32 vs bf16) from imgs ----
    detect_kernel<<<1, 256, 0, stream>>>((const unsigned short*)d_in[2], FLG);

    // ---- convert weights/params -> fp32 ----
    CvtJobs J;
    const int srcIdx[20] = {10, 14, 18, 20, 24, 28, 11, 12, 13, 15, 16, 17, 19, 21, 22, 23, 25, 26, 27, 29};
    const int cnt[20]    = {3072, 131072, 131072, 688128, 524288, 6144,
                            64, 64, 64, 128, 128, 128, 64, 256, 256, 256, 128, 128, 128, 3};
    float* dsts[20] = {W + OFF_WC0, W + OFF_WC1, W + OFF_WC2, W + OFF_WG0, W + OFF_WG1, W + OFF_WG2,
                       W + OFF_CB0, W + OFF_CG0, W + OFF_CBE0, W + OFF_CB1, W + OFF_CG1, W + OFF_CBE1,
                       W + OFF_CB2, W + OFF_GB0, W + OFF_GG0, W + OFF_GBE0, W + OFF_GB1, W + OFF_GG1,
                       W + OFF_GBE1, W + OFF_GB2};
    int off = 0;
    for (int k = 0; k < 20; ++k) {
        J.src[k] = d_in[srcIdx[k]];
        J.dst[k] = dsts[k];
        J.off[k] = off;
        off += cnt[k];
    }
    J.off[20] = off;
    cvt_all_kernel<<<(off + 255) / 256, 256, 0, stream>>>(J, off, FLG);

    zero_kernel<<<5, 256, 0, stream>>>(W + OFF_SSUM, 1152);

    mlp_kernel<<<64, 64, 0, stream>>>(d_in[1], d_in[4], d_in[5], d_in[6], d_in[7],
                                      d_in[8], d_in[9], W + OFF_K12, FLG);

    // ---- encoder conv0: imgs(3,128,128) -> X(64,64,64) ----
    conv_s2_bn_kernel<<<dim3(4, 64, 64), 256, 0, stream>>>(
        d_in[2], W + OFF_WC0, W + OFF_CB0, U + UX, W + OFF_SSUM, W + OFF_SSQ, 0,
        3, 128, 128, 64, 64, 64, 2, FLG, 1);
    bn_fin_kernel<<<1, 256, 0, stream>>>(W + OFF_SSUM, W + OFF_SSQ, W + OFF_CG0, W + OFF_CBE0,
                                         W + OFF_SCALE, W + OFF_SHIFT, 0, 64, 1.f / 262144.f);
    bn_act_kernel<<<16384, 256, 0, stream>>>(U + UX, W + OFF_SCALE, W + OFF_SHIFT, 0,
                                             4194304, 12, 63, 0.2f);

    // ---- encoder conv1: X(64,64,64) -> Y(128,32,32) ----
    conv_s2_bn_kernel<<<dim3(1, 128, 64), 256, 0, stream>>>(
        U + UX, W + OFF_WC1, W + OFF_CB1, U + UY, W + OFF_SSUM, W + OFF_SSQ, 64,
        64, 64, 64, 128, 32, 32, 1, FLG, 0);
    bn_fin_kernel<<<1, 256, 0, stream>>>(W + OFF_SSUM, W + OFF_SSQ, W + OFF_CG1, W + OFF_CBE1,
                                         W + OFF_SCALE, W + OFF_SHIFT, 64, 128, 1.f / 65536.f);
    bn_act_kernel<<<8192, 256, 0, stream>>>(U + UY, W + OFF_SCALE, W + OFF_SHIFT, 64,
                                            2097152, 10, 127, 0.2f);

    // ---- encoder conv2 + tanh -> Z[0:64) ----
    conv_s2_tanh_z<<<dim3(1, 64, 64), 64, 0, stream>>>(U + UY, W + OFF_WC2, W + OFF_CB2, U + UZ);

    // ---- Z[64:168) ----
    assemble_z<<<6656, 256, 0, stream>>>(d_in[0], d_in[1], d_in[3], W + OFF_K12, U + UZ, FLG);

    // ---- gen deconv0: Z(168,16,16) -> X(256,32,32) ----
    deconv_s2_bn_kernel<<<dim3(1, 256, 64), 256, 0, stream>>>(
        U + UZ, W + OFF_WG0, W + OFF_GB0, U + UX, W + OFF_SSUM, W + OFF_SSQ, 192,
        168, 16, 16, 256, 32, 32, 1);
    bn_fin_kernel<<<1, 256, 0, stream>>>(W + OFF_SSUM, W + OFF_SSQ, W + OFF_GG0, W + OFF_GBE0,
                                         W + OFF_SCALE, W + OFF_SHIFT, 192, 256, 1.f / 65536.f);
    bn_act_kernel<<<16384, 256, 0, stream>>>(U + UX, W + OFF_SCALE, W + OFF_SHIFT, 192,
                                             4194304, 10, 255, 0.f);

    // ---- gen deconv1: X(256,32,32) -> Y(128,64,64) ----
    deconv_s2_bn_kernel<<<dim3(4, 128, 64), 256, 0, stream>>>(
        U + UX, W + OFF_WG1, W + OFF_GB1, U + UY, W + OFF_SSUM, W + OFF_SSQ, 448,
        256, 32, 32, 128, 64, 64, 2);
    bn_fin_kernel<<<1, 256, 0, stream>>>(W + OFF_SSUM, W + OFF_SSQ, W + OFF_GG1, W + OFF_GBE1,
                                         W + OFF_SCALE, W + OFF_SHIFT, 448, 128, 1.f / 262144.f);
    bn_act_kernel<<<32768, 256, 0, stream>>>(U + UY, W + OFF_SCALE, W + OFF_SHIFT, 448,
                                             8388608, 12, 127, 0.f);

    // ---- gen deconv2 + tanh -> d_out fp32 ----
    deconv_s2_tanh_out<<<dim3(16, 3, 64), 256, 0, stream>>>(
        U + UY, W + OFF_WG2, W + OFF_GB2, (float*)d_out);
}

// Round 5
// 3390.456 us; speedup vs baseline: 3.0865x; 3.0865x over previous
//
#include <hip/hip_runtime.h>
#include <hip/hip_bf16.h>

#define TWO_PI_F 6.2831853071795864769f

__device__ __forceinline__ float bf2f_raw(unsigned short u) {
    return __uint_as_float(((unsigned int)u) << 16);
}
__device__ __forceinline__ unsigned short f2bf(float f) {
    unsigned int u = __float_as_uint(f);
    unsigned int r = (u + 0x7FFFu + ((u >> 16) & 1u)) >> 16;   // RNE
    return (unsigned short)r;
}
__device__ __forceinline__ float loadIn(const void* p, size_t i, bool f32) {
    return f32 ? ((const float*)p)[i] : bf2f_raw(((const unsigned short*)p)[i]);
}

// ---------------- ws layout ----------------
static constexpr size_t OFF_WC0 = 0;          // cod_w0  3072
static constexpr size_t OFF_WC1 = 3072;       // cod_w1  131072
static constexpr size_t OFF_WC2 = 134144;     // cod_w2  131072
static constexpr size_t OFF_WG0 = 265216;     // gen_w0  688128
static constexpr size_t OFF_WG1 = 953344;     // gen_w1  524288
static constexpr size_t OFF_WG2 = 1477632;    // gen_w2  6144
static constexpr size_t OFF_P   = 1483776;    // small params
static constexpr size_t OFF_CB0 = OFF_P + 0;
static constexpr size_t OFF_CG0 = OFF_P + 64;
static constexpr size_t OFF_CBE0= OFF_P + 128;
static constexpr size_t OFF_CB1 = OFF_P + 192;
static constexpr size_t OFF_CG1 = OFF_P + 320;
static constexpr size_t OFF_CBE1= OFF_P + 448;
static constexpr size_t OFF_CB2 = OFF_P + 576;
static constexpr size_t OFF_GB0 = OFF_P + 640;
static constexpr size_t OFF_GG0 = OFF_P + 896;
static constexpr size_t OFF_GBE0= OFF_P + 1152;
static constexpr size_t OFF_GB1 = OFF_P + 1408;
static constexpr size_t OFF_GG1 = OFF_P + 1536;
static constexpr size_t OFF_GBE1= OFF_P + 1664;
static constexpr size_t OFF_GB2 = OFF_P + 1792; // 3
static constexpr size_t OFF_SSUM  = 1485824;    // 576
static constexpr size_t OFF_SSQ   = OFF_SSUM + 576;
static constexpr size_t OFF_SCALE = OFF_SSUM + 1152;
static constexpr size_t OFF_SHIFT = OFF_SCALE + 576;
static constexpr size_t OFF_K12   = OFF_SHIFT + 576;  // 1024 floats
static constexpr size_t OFF_FLAG  = OFF_K12 + 1024;   // 16 floats (flag in [0])
// fp32 region ends at 1489168 floats == 2978336 ushorts.
static constexpr size_t UZ = 2978336;               // Z: 64*168*256 = 2752512
static constexpr size_t UX = UZ + 2752512;          // X: max 64*256*32*32 = 16777216
static constexpr size_t UY = UX + 16777216;         // Y: max 64*128*64*64 = 33554432
static constexpr size_t WS_END_USHORT = UY + 33554432;
static constexpr size_t WS_NEED_BYTES = WS_END_USHORT * 2;   // ~112.1 MB

// stat slots: L0:0(64) L1:64(128) G0:192(256) G1:448(128)

// ---------------- input dtype detection ----------------
__global__ void detect_kernel(const unsigned short* __restrict__ imgs, int* __restrict__ flag) {
    int t = threadIdx.x;  // 256
    unsigned short u = imgs[t];
    int e = (u >> 7) & 0xFF;
    unsigned long long b = __ballot(e >= 0xC0);
    __shared__ int cnt[4];
    if ((t & 63) == 0) cnt[t >> 6] = __popcll(b);
    __syncthreads();
    if (t == 0) flag[0] = (cnt[0] + cnt[1] + cnt[2] + cnt[3] >= 4) ? 1 : 0;
}

// ---------------- weight/param -> fp32 conversion ----------------
struct CvtJobs {
    const void* src[20];
    float* dst[20];
    int off[21];
};

__global__ void cvt_all_kernel(CvtJobs J, int total, const int* __restrict__ flg) {
    int i = blockIdx.x * 256 + threadIdx.x;
    if (i >= total) return;
    bool f32 = flg[0] != 0;
    int k = 0;
#pragma unroll
    for (int t = 0; t < 19; ++t) { if (i >= J.off[t + 1]) k = t + 1; }
    int r = i - J.off[k];
    J.dst[k][r] = loadIn(J.src[k], r, f32);
}

__global__ void zero_kernel(float* p, int n) {
    int i = blockIdx.x * 256 + threadIdx.x;
    if (i < n) p[i] = 0.f;
}

// ---------------- tiny MLP ----------------
__global__ void mlp_kernel(const void* __restrict__ Zg,
                           const void* __restrict__ lW, const void* __restrict__ lb,
                           const void* __restrict__ l1W, const void* __restrict__ l1b,
                           const void* __restrict__ l2W, const void* __restrict__ l2b,
                           float* __restrict__ K12, const int* __restrict__ flg) {
    bool f32 = flg[0] != 0;
    int b = blockIdx.x;
    int t = threadIdx.x;  // 64
    __shared__ float xs[64];
    float acc = loadIn(lb, t, f32);
    for (int c = 0; c < 64; ++c)
        acc += loadIn(Zg, (size_t)(b * 64 + c) * 256, f32) * loadIn(lW, t * 64 + c, f32);
    xs[t] = fmaxf(acc, 0.f);
    __syncthreads();
    if (t < 16) {
        int p = t & 7;
        const void* Wp = (t < 8) ? l1W : l2W;
        const void* bp = (t < 8) ? l1b : l2b;
        float a = loadIn(bp, p, f32);
        for (int h = 0; h < 64; ++h) a += xs[h] * loadIn(Wp, p * 64 + h, f32);
        K12[b * 16 + t] = a;
    }
}

// ---------------- stride-2 conv (k=4,p=1), OCB oc per block, 2x2 quad/thread, +stats ----------------
template <int OCB>
__global__ void conv_s2_bn_kernel(const void* __restrict__ in, const float* __restrict__ w,
                                  const float* __restrict__ bias, unsigned short* __restrict__ out,
                                  float* __restrict__ ssum, float* __restrict__ ssq, int statoff,
                                  int IC, int IH, int IW, int OC, int OH, int OW, int tilesX,
                                  const int* __restrict__ flg, int useFlag) {
    bool f32 = useFlag && (flg[0] != 0);
    int b = blockIdx.z;
    int oc0 = blockIdx.y * OCB;
    int tX = blockIdx.x % tilesX;
    int tY = blockIdx.x / tilesX;
    int qx = tX * 16 + (threadIdx.x & 15);
    int qy = tY * 16 + (threadIdx.x >> 4);
    int iy0 = 4 * qy - 1;
    int ix0 = 4 * qx - 1;
    float acc[OCB][4];
#pragma unroll
    for (int o = 0; o < OCB; ++o) { acc[o][0] = acc[o][1] = acc[o][2] = acc[o][3] = 0.f; }
    for (int ic = 0; ic < IC; ++ic) {
        size_t base = (size_t)(b * IC + ic) * IH * IW;
        float v[6][6];
#pragma unroll
        for (int r = 0; r < 6; ++r) {
            int iy = iy0 + r;
            bool rv = (iy >= 0) & (iy < IH);
#pragma unroll
            for (int c = 0; c < 6; ++c) {
                int ix = ix0 + c;
                bool ok = rv & (ix >= 0) & (ix < IW);
                v[r][c] = ok ? loadIn(in, base + iy * IW + ix, f32) : 0.f;
            }
        }
#pragma unroll
        for (int o = 0; o < OCB; ++o) {
            const float* wp = w + ((size_t)((oc0 + o) * IC + ic) << 4);  // uniform -> s_load
#pragma unroll
            for (int ky = 0; ky < 4; ++ky)
#pragma unroll
                for (int kx = 0; kx < 4; ++kx) {
                    float wv = wp[ky * 4 + kx];
                    acc[o][0] = fmaf(v[ky][kx], wv, acc[o][0]);
                    acc[o][1] = fmaf(v[ky][kx + 2], wv, acc[o][1]);
                    acc[o][2] = fmaf(v[ky + 2][kx], wv, acc[o][2]);
                    acc[o][3] = fmaf(v[ky + 2][kx + 2], wv, acc[o][3]);
                }
        }
    }
    int oy = 2 * qy, ox = 2 * qx;
    __shared__ float rs[OCB][4], rq[OCB][4];
    int wv_ = threadIdx.x >> 6, ln = threadIdx.x & 63;
#pragma unroll
    for (int o = 0; o < OCB; ++o) {
        float bv = bias[oc0 + o];
        float a0 = acc[o][0] + bv, a1 = acc[o][1] + bv, a2 = acc[o][2] + bv, a3 = acc[o][3] + bv;
        size_t ob = (size_t)(b * OC + oc0 + o) * OH * OW;
        out[ob + (size_t)oy * OW + ox] = f2bf(a0);
        out[ob + (size_t)oy * OW + ox + 1] = f2bf(a1);
        out[ob + (size_t)(oy + 1) * OW + ox] = f2bf(a2);
        out[ob + (size_t)(oy + 1) * OW + ox + 1] = f2bf(a3);
        float s = a0 + a1 + a2 + a3;
        float q = a0 * a0 + a1 * a1 + a2 * a2 + a3 * a3;
#pragma unroll
        for (int off = 32; off > 0; off >>= 1) { s += __shfl_down(s, off); q += __shfl_down(q, off); }
        if (ln == 0) { rs[o][wv_] = s; rq[o][wv_] = q; }
    }
    __syncthreads();
    if (threadIdx.x < OCB) {
        int o = threadIdx.x;
        atomicAdd(&ssum[statoff + oc0 + o], rs[o][0] + rs[o][1] + rs[o][2] + rs[o][3]);
        atomicAdd(&ssq[statoff + oc0 + o], rq[o][0] + rq[o][1] + rq[o][2] + rq[o][3]);
    }
}

// ---------------- conv2 + tanh -> Z[0:64): 1 output/thread, 8 oc per block ----------------
__global__ void conv_s2_tanh_z(const unsigned short* __restrict__ in, const float* __restrict__ w,
                               const float* __restrict__ bias, unsigned short* __restrict__ z) {
    const int IC = 128, IH = 32, IW = 32, OC = 64;
    const int OCB = 8;
    int b = blockIdx.z;
    int oc0 = blockIdx.y * OCB;
    int ox = threadIdx.x & 15, oy = threadIdx.x >> 4;  // 256 threads = 16x16 outputs
    int iy0 = 2 * oy - 1, ix0 = 2 * ox - 1;
    float acc[OCB];
#pragma unroll
    for (int o = 0; o < OCB; ++o) acc[o] = 0.f;
    for (int ic = 0; ic < IC; ++ic) {
        size_t base = (size_t)(b * IC + ic) * IH * IW;
        float v[4][4];
#pragma unroll
        for (int r = 0; r < 4; ++r) {
            int iy = iy0 + r;
            bool rv = (iy >= 0) & (iy < IH);
#pragma unroll
            for (int c = 0; c < 4; ++c) {
                int ix = ix0 + c;
                bool ok = rv & (ix >= 0) & (ix < IW);
                v[r][c] = ok ? bf2f_raw(in[base + iy * IW + ix]) : 0.f;
            }
        }
#pragma unroll
        for (int o = 0; o < OCB; ++o) {
            const float* wp = w + ((size_t)((oc0 + o) * IC + ic) << 4);  // uniform
#pragma unroll
            for (int ky = 0; ky < 4; ++ky)
#pragma unroll
                for (int kx = 0; kx < 4; ++kx)
                    acc[o] = fmaf(v[ky][kx], wp[ky * 4 + kx], acc[o]);
        }
    }
#pragma unroll
    for (int o = 0; o < OCB; ++o) {
        size_t ob = ((size_t)(b * 168 + oc0 + o)) * 256;
        z[ob + oy * 16 + ox] = f2bf(tanhf(acc[o] + bias[oc0 + o]));
    }
}

// ---------------- assemble Z channels [64,168) ----------------
__global__ void assemble_z(const void* __restrict__ Zl, const void* __restrict__ Zg,
                           const void* __restrict__ phi, const float* __restrict__ K12,
                           unsigned short* __restrict__ Z, const int* __restrict__ flg) {
    bool f32 = flg[0] != 0;
    int i = blockIdx.x * 256 + threadIdx.x;
    const int TOT = 64 * 104 * 256;
    if (i >= TOT) return;
    int pos = i & 255;
    int t = i >> 8;
    int c104 = t % 104;
    int b = t / 104;
    float val;
    if (c104 < 32) {
        val = loadIn(Zl, ((size_t)(b * 32 + c104) << 8) + pos, f32);
    } else if (c104 < 96) {
        val = loadIn(Zg, ((size_t)(b * 64 + (c104 - 32)) << 8) + pos, f32);
    } else {
        int p = c104 - 96;
        int y = pos >> 4, x = pos & 15;
        float k1 = K12[b * 16 + p];
        float k2 = K12[b * 16 + 8 + p];
        val = sinf(k1 * (float)y + k2 * (float)x + loadIn(phi, b * 8 + p, f32) * TWO_PI_F);
    }
    Z[((size_t)(b * 168 + 64 + c104) << 8) + pos] = f2bf(val);
}

// ---------------- transposed conv stride2 (k=4,p=1), OCB oc/block, +stats ----------------
template <int OCB>
__global__ void deconv_s2_bn_kernel(const unsigned short* __restrict__ in, const float* __restrict__ w,
                                    const float* __restrict__ bias, unsigned short* __restrict__ out,
                                    float* __restrict__ ssum, float* __restrict__ ssq, int statoff,
                                    int IC, int IH, int IW, int OC, int OH, int OW, int tilesX) {
    int b = blockIdx.z;
    int oc0 = blockIdx.y * OCB;
    int tX = blockIdx.x % tilesX, tY = blockIdx.x / tilesX;
    int qx = tX * 16 + (threadIdx.x & 15);
    int qy = tY * 16 + (threadIdx.x >> 4);
    float acc[OCB][4];
#pragma unroll
    for (int o = 0; o < OCB; ++o) { acc[o][0] = acc[o][1] = acc[o][2] = acc[o][3] = 0.f; }
    for (int ic = 0; ic < IC; ++ic) {
        size_t base = (size_t)(b * IC + ic) * IH * IW;
        float v[3][3];
#pragma unroll
        for (int r = 0; r < 3; ++r) {
            int iy = qy - 1 + r;
            bool rv = (iy >= 0) & (iy < IH);
#pragma unroll
            for (int c = 0; c < 3; ++c) {
                int ix = qx - 1 + c;
                bool ok = rv & (ix >= 0) & (ix < IW);
                v[r][c] = ok ? bf2f_raw(in[base + iy * IW + ix]) : 0.f;
            }
        }
        const float* wp = w + ((size_t)(ic * OC + oc0) << 4);  // uniform; OCB*16 contiguous
#pragma unroll
        for (int o = 0; o < OCB; ++o) {
            const float* wo = wp + (o << 4);
            acc[o][0] = fmaf(v[1][1], wo[5],  acc[o][0]); acc[o][0] = fmaf(v[1][0], wo[7],  acc[o][0]);
            acc[o][0] = fmaf(v[0][1], wo[13], acc[o][0]); acc[o][0] = fmaf(v[0][0], wo[15], acc[o][0]);
            acc[o][1] = fmaf(v[1][2], wo[4],  acc[o][1]); acc[o][1] = fmaf(v[1][1], wo[6],  acc[o][1]);
            acc[o][1] = fmaf(v[0][2], wo[12], acc[o][1]); acc[o][1] = fmaf(v[0][1], wo[14], acc[o][1]);
            acc[o][2] = fmaf(v[2][1], wo[1],  acc[o][2]); acc[o][2] = fmaf(v[2][0], wo[3],  acc[o][2]);
            acc[o][2] = fmaf(v[1][1], wo[9],  acc[o][2]); acc[o][2] = fmaf(v[1][0], wo[11], acc[o][2]);
            acc[o][3] = fmaf(v[2][2], wo[0],  acc[o][3]); acc[o][3] = fmaf(v[2][1], wo[2],  acc[o][3]);
            acc[o][3] = fmaf(v[1][2], wo[8],  acc[o][3]); acc[o][3] = fmaf(v[1][1], wo[10], acc[o][3]);
        }
    }
    int oy = 2 * qy, ox = 2 * qx;
    __shared__ float rs[OCB][4], rq[OCB][4];
    int wv_ = threadIdx.x >> 6, ln = threadIdx.x & 63;
#pragma unroll
    for (int o = 0; o < OCB; ++o) {
        float bv = bias[oc0 + o];
        float a0 = acc[o][0] + bv, a1 = acc[o][1] + bv, a2 = acc[o][2] + bv, a3 = acc[o][3] + bv;
        size_t ob = (size_t)(b * OC + oc0 + o) * OH * OW;
        out[ob + (size_t)oy * OW + ox] = f2bf(a0);
        out[ob + (size_t)oy * OW + ox + 1] = f2bf(a1);
        out[ob + (size_t)(oy + 1) * OW + ox] = f2bf(a2);
        out[ob + (size_t)(oy + 1) * OW + ox + 1] = f2bf(a3);
        float s = a0 + a1 + a2 + a3;
        float q = a0 * a0 + a1 * a1 + a2 * a2 + a3 * a3;
#pragma unroll
        for (int off = 32; off > 0; off >>= 1) { s += __shfl_down(s, off); q += __shfl_down(q, off); }
        if (ln == 0) { rs[o][wv_] = s; rq[o][wv_] = q; }
    }
    __syncthreads();
    if (threadIdx.x < OCB) {
        int o = threadIdx.x;
        atomicAdd(&ssum[statoff + oc0 + o], rs[o][0] + rs[o][1] + rs[o][2] + rs[o][3]);
        atomicAdd(&ssq[statoff + oc0 + o], rq[o][0] + rq[o][1] + rq[o][2] + rq[o][3]);
    }
}

// ---------------- final transposed conv: all 3 oc in one block, + tanh -> fp32 out ----------------
__global__ void deconv_s2_tanh_out(const unsigned short* __restrict__ in, const float* __restrict__ w,
                                   const float* __restrict__ bias, float* __restrict__ outp) {
    const int IC = 128, IH = 64, IW = 64, OC = 3, OH = 128, OW = 128;
    int b = blockIdx.z;
    int tX = blockIdx.x & 3, tY = blockIdx.x >> 2;
    int qx = tX * 16 + (threadIdx.x & 15);
    int qy = tY * 16 + (threadIdx.x >> 4);
    float acc[3][4];
#pragma unroll
    for (int o = 0; o < 3; ++o) { acc[o][0] = acc[o][1] = acc[o][2] = acc[o][3] = 0.f; }
    for (int ic = 0; ic < IC; ++ic) {
        size_t base = (size_t)(b * IC + ic) * IH * IW;
        float v[3][3];
#pragma unroll
        for (int r = 0; r < 3; ++r) {
            int iy = qy - 1 + r;
            bool rv = (iy >= 0) & (iy < IH);
#pragma unroll
            for (int c = 0; c < 3; ++c) {
                int ix = qx - 1 + c;
                bool ok = rv & (ix >= 0) & (ix < IW);
                v[r][c] = ok ? bf2f_raw(in[base + iy * IW + ix]) : 0.f;
            }
        }
        const float* wp = w + ((size_t)(ic * OC) << 4);
#pragma unroll
        for (int o = 0; o < 3; ++o) {
            const float* wo = wp + (o << 4);
            acc[o][0] = fmaf(v[1][1], wo[5],  acc[o][0]); acc[o][0] = fmaf(v[1][0], wo[7],  acc[o][0]);
            acc[o][0] = fmaf(v[0][1], wo[13], acc[o][0]); acc[o][0] = fmaf(v[0][0], wo[15], acc[o][0]);
            acc[o][1] = fmaf(v[1][2], wo[4],  acc[o][1]); acc[o][1] = fmaf(v[1][1], wo[6],  acc[o][1]);
            acc[o][1] = fmaf(v[0][2], wo[12], acc[o][1]); acc[o][1] = fmaf(v[0][1], wo[14], acc[o][1]);
            acc[o][2] = fmaf(v[2][1], wo[1],  acc[o][2]); acc[o][2] = fmaf(v[2][0], wo[3],  acc[o][2]);
            acc[o][2] = fmaf(v[1][1], wo[9],  acc[o][2]); acc[o][2] = fmaf(v[1][0], wo[11], acc[o][2]);
            acc[o][3] = fmaf(v[2][2], wo[0],  acc[o][3]); acc[o][3] = fmaf(v[2][1], wo[2],  acc[o][3]);
            acc[o][3] = fmaf(v[1][2], wo[8],  acc[o][3]); acc[o][3] = fmaf(v[1][1], wo[10], acc[o][3]);
        }
    }
    int oy = 2 * qy, ox = 2 * qx;
#pragma unroll
    for (int o = 0; o < 3; ++o) {
        float bv = bias[o];
        size_t ob = (size_t)(b * OC + o) * OH * OW;
        outp[ob + (size_t)oy * OW + ox]           = tanhf(acc[o][0] + bv);
        outp[ob + (size_t)oy * OW + ox + 1]       = tanhf(acc[o][1] + bv);
        outp[ob + (size_t)(oy + 1) * OW + ox]     = tanhf(acc[o][2] + bv);
        outp[ob + (size_t)(oy + 1) * OW + ox + 1] = tanhf(acc[o][3] + bv);
    }
}

// ---------------- BN finalize ----------------
__global__ void bn_fin_kernel(const float* __restrict__ ssum, const float* __restrict__ ssq,
                              const float* __restrict__ g, const float* __restrict__ be,
                              float* __restrict__ scale, float* __restrict__ shift,
                              int statoff, int C, float invN) {
    int c = threadIdx.x;
    if (c >= C) return;
    float m = ssum[statoff + c] * invN;
    float v = ssq[statoff + c] * invN - m * m;
    v = fmaxf(v, 0.f);
    float sc = g[c] * rsqrtf(v + 1e-5f);
    scale[statoff + c] = sc;
    shift[statoff + c] = be[c] - m * sc;
}

// ---------------- in-place BN affine + (leaky)relu on bf16 ----------------
__global__ void bn_act_kernel(unsigned short* __restrict__ x, const float* __restrict__ scale,
                              const float* __restrict__ shift, int statoff,
                              int n4, int hwShift, int cMask, float slope) {
    int i = blockIdx.x * 256 + threadIdx.x;
    if (i >= n4) return;
    int i4 = i << 2;
    int c = (i4 >> hwShift) & cMask;
    float sc = scale[statoff + c], sh = shift[statoff + c];
    ushort4 v = *reinterpret_cast<ushort4*>(x + i4);
    float f0 = bf2f_raw(v.x) * sc + sh; f0 = f0 > 0.f ? f0 : slope * f0;
    float f1 = bf2f_raw(v.y) * sc + sh; f1 = f1 > 0.f ? f1 : slope * f1;
    float f2 = bf2f_raw(v.z) * sc + sh; f2 = f2 > 0.f ? f2 : slope * f2;
    float f3 = bf2f_raw(v.w) * sc + sh; f3 = f3 > 0.f ? f3 : slope * f3;
    v.x = f2bf(f0); v.y = f2bf(f1); v.z = f2bf(f2); v.w = f2bf(f3);
    *reinterpret_cast<ushort4*>(x + i4) = v;
}

extern "C" void kernel_launch(void* const* d_in, const int* in_sizes, int n_in,
                              void* d_out, int out_size, void* d_ws, size_t ws_size,
                              hipStream_t stream) {
    if (ws_size < WS_NEED_BYTES) {
        hipMemsetAsync(d_out, 0, (size_t)out_size * 4, stream);
        return;
    }

    float* W = (float*)d_ws;
    unsigned short* U = (unsigned short*)d_ws;
    int* FLG = (int*)(W + OFF_FLAG);

    detect_kernel<<<1, 256, 0, stream>>>((const unsigned short*)d_in[2], FLG);

    CvtJobs J;
    const int srcIdx[20] = {10, 14, 18, 20, 24, 28, 11, 12, 13, 15, 16, 17, 19, 21, 22, 23, 25, 26, 27, 29};
    const int cnt[20]    = {3072, 131072, 131072, 688128, 524288, 6144,
                            64, 64, 64, 128, 128, 128, 64, 256, 256, 256, 128, 128, 128, 3};
    float* dsts[20] = {W + OFF_WC0, W + OFF_WC1, W + OFF_WC2, W + OFF_WG0, W + OFF_WG1, W + OFF_WG2,
                       W + OFF_CB0, W + OFF_CG0, W + OFF_CBE0, W + OFF_CB1, W + OFF_CG1, W + OFF_CBE1,
                       W + OFF_CB2, W + OFF_GB0, W + OFF_GG0, W + OFF_GBE0, W + OFF_GB1, W + OFF_GG1,
                       W + OFF_GBE1, W + OFF_GB2};
    int off = 0;
    for (int k = 0; k < 20; ++k) {
        J.src[k] = d_in[srcIdx[k]];
        J.dst[k] = dsts[k];
        J.off[k] = off;
        off += cnt[k];
    }
    J.off[20] = off;
    cvt_all_kernel<<<(off + 255) / 256, 256, 0, stream>>>(J, off, FLG);

    zero_kernel<<<5, 256, 0, stream>>>(W + OFF_SSUM, 1152);

    mlp_kernel<<<64, 64, 0, stream>>>(d_in[1], d_in[4], d_in[5], d_in[6], d_in[7],
                                      d_in[8], d_in[9], W + OFF_K12, FLG);

    // ---- encoder conv0: imgs(3,128,128) -> X(64,64,64), OCB=8 ----
    conv_s2_bn_kernel<8><<<dim3(4, 8, 64), 256, 0, stream>>>(
        d_in[2], W + OFF_WC0, W + OFF_CB0, U + UX, W + OFF_SSUM, W + OFF_SSQ, 0,
        3, 128, 128, 64, 64, 64, 2, FLG, 1);
    bn_fin_kernel<<<1, 256, 0, stream>>>(W + OFF_SSUM, W + OFF_SSQ, W + OFF_CG0, W + OFF_CBE0,
                                         W + OFF_SCALE, W + OFF_SHIFT, 0, 64, 1.f / 262144.f);
    bn_act_kernel<<<16384, 256, 0, stream>>>(U + UX, W + OFF_SCALE, W + OFF_SHIFT, 0,
                                             4194304, 12, 63, 0.2f);

    // ---- encoder conv1: X(64,64,64) -> Y(128,32,32), OCB=8 ----
    conv_s2_bn_kernel<8><<<dim3(1, 16, 64), 256, 0, stream>>>(
        U + UX, W + OFF_WC1, W + OFF_CB1, U + UY, W + OFF_SSUM, W + OFF_SSQ, 64,
        64, 64, 64, 128, 32, 32, 1, FLG, 0);
    bn_fin_kernel<<<1, 256, 0, stream>>>(W + OFF_SSUM, W + OFF_SSQ, W + OFF_CG1, W + OFF_CBE1,
                                         W + OFF_SCALE, W + OFF_SHIFT, 64, 128, 1.f / 65536.f);
    bn_act_kernel<<<8192, 256, 0, stream>>>(U + UY, W + OFF_SCALE, W + OFF_SHIFT, 64,
                                            2097152, 10, 127, 0.2f);

    // ---- encoder conv2 + tanh -> Z[0:64), 1 out/thread, OCB=8 ----
    conv_s2_tanh_z<<<dim3(1, 8, 64), 256, 0, stream>>>(U + UY, W + OFF_WC2, W + OFF_CB2, U + UZ);

    // ---- Z[64:168) ----
    assemble_z<<<6656, 256, 0, stream>>>(d_in[0], d_in[1], d_in[3], W + OFF_K12, U + UZ, FLG);

    // ---- gen deconv0: Z(168,16,16) -> X(256,32,32), OCB=8 ----
    deconv_s2_bn_kernel<8><<<dim3(1, 32, 64), 256, 0, stream>>>(
        U + UZ, W + OFF_WG0, W + OFF_GB0, U + UX, W + OFF_SSUM, W + OFF_SSQ, 192,
        168, 16, 16, 256, 32, 32, 1);
    bn_fin_kernel<<<1, 256, 0, stream>>>(W + OFF_SSUM, W + OFF_SSQ, W + OFF_GG0, W + OFF_GBE0,
                                         W + OFF_SCALE, W + OFF_SHIFT, 192, 256, 1.f / 65536.f);
    bn_act_kernel<<<16384, 256, 0, stream>>>(U + UX, W + OFF_SCALE, W + OFF_SHIFT, 192,
                                             4194304, 10, 255, 0.f);

    // ---- gen deconv1: X(256,32,32) -> Y(128,64,64), OCB=8 ----
    deconv_s2_bn_kernel<8><<<dim3(4, 16, 64), 256, 0, stream>>>(
        U + UX, W + OFF_WG1, W + OFF_GB1, U + UY, W + OFF_SSUM, W + OFF_SSQ, 448,
        256, 32, 32, 128, 64, 64, 2);
    bn_fin_kernel<<<1, 256, 0, stream>>>(W + OFF_SSUM, W + OFF_SSQ, W + OFF_GG1, W + OFF_GBE1,
                                         W + OFF_SCALE, W + OFF_SHIFT, 448, 128, 1.f / 262144.f);
    bn_act_kernel<<<32768, 256, 0, stream>>>(U + UY, W + OFF_SCALE, W + OFF_SHIFT, 448,
                                             8388608, 12, 127, 0.f);

    // ---- gen deconv2 + tanh -> d_out fp32 (all 3 oc fused) ----
    deconv_s2_tanh_out<<<dim3(16, 1, 64), 256, 0, stream>>>(
        U + UY, W + OFF_WG2, W + OFF_GB2, (float*)d_out);
}

// Round 6
// 2364.570 us; speedup vs baseline: 4.4257x; 1.4339x over previous
//
#include <hip/hip_runtime.h>
#include <hip/hip_bf16.h>

#define TWO_PI_F 6.2831853071795864769f

typedef __attribute__((ext_vector_type(8))) __bf16 bf16x8;
typedef __attribute__((ext_vector_type(4))) float f32x4;

__device__ __forceinline__ float bf2f_raw(unsigned short u) {
    return __uint_as_float(((unsigned int)u) << 16);
}
__device__ __forceinline__ unsigned short f2bf(float f) {
    unsigned int u = __float_as_uint(f);
    unsigned int r = (u + 0x7FFFu + ((u >> 16) & 1u)) >> 16;   // RNE
    return (unsigned short)r;
}
__device__ __forceinline__ float loadIn(const void* p, size_t i, bool f32) {
    return f32 ? ((const float*)p)[i] : bf2f_raw(((const unsigned short*)p)[i]);
}

// ---------------- ws layout ----------------
// fp32 region (float offsets):
static constexpr size_t OFF_WC0 = 0;          // cod_w0  3072
static constexpr size_t OFF_WC1 = 3072;       // cod_w1  131072
static constexpr size_t OFF_WC2 = 134144;     // cod_w2  131072
static constexpr size_t OFF_WG0 = 265216;     // gen_w0  688128 (fp32, unused by MFMA path)
static constexpr size_t OFF_WG1 = 953344;     // gen_w1  524288
static constexpr size_t OFF_WG2 = 1477632;    // gen_w2  6144
static constexpr size_t OFF_P   = 1483776;
static constexpr size_t OFF_CB0 = OFF_P + 0;
static constexpr size_t OFF_CG0 = OFF_P + 64;
static constexpr size_t OFF_CBE0= OFF_P + 128;
static constexpr size_t OFF_CB1 = OFF_P + 192;
static constexpr size_t OFF_CG1 = OFF_P + 320;
static constexpr size_t OFF_CBE1= OFF_P + 448;
static constexpr size_t OFF_CB2 = OFF_P + 576;
static constexpr size_t OFF_GB0 = OFF_P + 640;
static constexpr size_t OFF_GG0 = OFF_P + 896;
static constexpr size_t OFF_GBE0= OFF_P + 1152;
static constexpr size_t OFF_GB1 = OFF_P + 1408;
static constexpr size_t OFF_GG1 = OFF_P + 1536;
static constexpr size_t OFF_GBE1= OFF_P + 1664;
static constexpr size_t OFF_GB2 = OFF_P + 1792;
static constexpr size_t OFF_SSUM  = 1485824;    // 576
static constexpr size_t OFF_SSQ   = OFF_SSUM + 576;
static constexpr size_t OFF_SCALE = OFF_SSUM + 1152;
static constexpr size_t OFF_SHIFT = OFF_SCALE + 576;
static constexpr size_t OFF_K12   = OFF_SHIFT + 576;
static constexpr size_t OFF_FLAG  = OFF_K12 + 1024;
// fp32 region ends at 1489168 floats == 2978336 ushorts.
// ushort (bf16) regions:
static constexpr size_t UXT = 2978336;                 // X region: conv0-out (b,64,64,64) THEN X_t (b,32,32,256); 16777216
static constexpr size_t UYT = UXT + 16777216;          // Y region: conv1-out (b,128,32,32) first 8388608, THEN Y_t (b,64,64,128); 33554432
static constexpr size_t UZT = UYT + 8388608;           // Z_t (b,16,16,192) = 3145728 (inside Y region tail; dead before Y_t write)
static constexpr size_t UW0 = UYT + 33554432;          // Wpack0 16*256*192 = 786432
static constexpr size_t UW1 = UW0 + 786432;            // Wpack1 16*128*256 = 524288
static constexpr size_t WS_END_USHORT = UW1 + 524288;  // 54620704
static constexpr size_t WS_NEED_BYTES = WS_END_USHORT * 2;  // ~109.2 MB

// stat slots: L0:0(64) L1:64(128) G0:192(256) G1:448(128)

// ---------------- input dtype detection ----------------
__global__ void detect_kernel(const unsigned short* __restrict__ imgs, int* __restrict__ flag) {
    int t = threadIdx.x;  // 256
    unsigned short u = imgs[t];
    int e = (u >> 7) & 0xFF;
    unsigned long long b = __ballot(e >= 0xC0);
    __shared__ int cnt[4];
    if ((t & 63) == 0) cnt[t >> 6] = __popcll(b);
    __syncthreads();
    if (t == 0) flag[0] = (cnt[0] + cnt[1] + cnt[2] + cnt[3] >= 4) ? 1 : 0;
}

// ---------------- weight/param -> fp32 conversion ----------------
struct CvtJobs {
    const void* src[20];
    float* dst[20];
    int off[21];
};

__global__ void cvt_all_kernel(CvtJobs J, int total, const int* __restrict__ flg) {
    int i = blockIdx.x * 256 + threadIdx.x;
    if (i >= total) return;
    bool f32 = flg[0] != 0;
    int k = 0;
#pragma unroll
    for (int t = 0; t < 19; ++t) { if (i >= J.off[t + 1]) k = t + 1; }
    int r = i - J.off[k];
    J.dst[k][r] = loadIn(J.src[k], r, f32);
}

__global__ void zero_kernel(float* p, int n) {
    int i = blockIdx.x * 256 + threadIdx.x;
    if (i < n) p[i] = 0.f;
}

// ---------------- deconv weight packing: Wpack[ktap][oc][ic] = w[ic][oc][ky][kx] (bf16, ic zero-padded) ----------------
__global__ void pack_w_kernel(const void* __restrict__ src, unsigned short* __restrict__ dst,
                              int ICreal, int ICP, int OC, const int* __restrict__ flg) {
    bool f32 = flg[0] != 0;
    int i = blockIdx.x * 256 + threadIdx.x;
    int total = 16 * OC * ICP;
    if (i >= total) return;
    int ic = i % ICP;
    int t = i / ICP;
    int oc = t % OC;
    int ktap = t / OC;
    unsigned short v = 0;
    if (ic < ICreal) {
        size_t si = ((size_t)(ic * OC + oc) << 4) + ktap;
        v = f2bf(loadIn(src, si, f32));
    }
    dst[i] = v;
}

// ---------------- tiny MLP ----------------
__global__ void mlp_kernel(const void* __restrict__ Zg,
                           const void* __restrict__ lW, const void* __restrict__ lb,
                           const void* __restrict__ l1W, const void* __restrict__ l1b,
                           const void* __restrict__ l2W, const void* __restrict__ l2b,
                           float* __restrict__ K12, const int* __restrict__ flg) {
    bool f32 = flg[0] != 0;
    int b = blockIdx.x;
    int t = threadIdx.x;  // 64
    __shared__ float xs[64];
    float acc = loadIn(lb, t, f32);
    for (int c = 0; c < 64; ++c)
        acc += loadIn(Zg, (size_t)(b * 64 + c) * 256, f32) * loadIn(lW, t * 64 + c, f32);
    xs[t] = fmaxf(acc, 0.f);
    __syncthreads();
    if (t < 16) {
        int p = t & 7;
        const void* Wp = (t < 8) ? l1W : l2W;
        const void* bp = (t < 8) ? l1b : l2b;
        float a = loadIn(bp, p, f32);
        for (int h = 0; h < 64; ++h) a += xs[h] * loadIn(Wp, p * 64 + h, f32);
        K12[b * 16 + t] = a;
    }
}

// ---------------- stride-2 conv (k=4,p=1), OCB oc/block, 2x2 quad/thread, +stats (encoder) ----------------
template <int OCB>
__global__ void conv_s2_bn_kernel(const void* __restrict__ in, const float* __restrict__ w,
                                  const float* __restrict__ bias, unsigned short* __restrict__ out,
                                  float* __restrict__ ssum, float* __restrict__ ssq, int statoff,
                                  int IC, int IH, int IW, int OC, int OH, int OW, int tilesX,
                                  const int* __restrict__ flg, int useFlag) {
    bool f32 = useFlag && (flg[0] != 0);
    int b = blockIdx.z;
    int oc0 = blockIdx.y * OCB;
    int tX = blockIdx.x % tilesX;
    int tY = blockIdx.x / tilesX;
    int qx = tX * 16 + (threadIdx.x & 15);
    int qy = tY * 16 + (threadIdx.x >> 4);
    int iy0 = 4 * qy - 1;
    int ix0 = 4 * qx - 1;
    float acc[OCB][4];
#pragma unroll
    for (int o = 0; o < OCB; ++o) { acc[o][0] = acc[o][1] = acc[o][2] = acc[o][3] = 0.f; }
    for (int ic = 0; ic < IC; ++ic) {
        size_t base = (size_t)(b * IC + ic) * IH * IW;
        float v[6][6];
#pragma unroll
        for (int r = 0; r < 6; ++r) {
            int iy = iy0 + r;
            bool rv = (iy >= 0) & (iy < IH);
#pragma unroll
            for (int c = 0; c < 6; ++c) {
                int ix = ix0 + c;
                bool ok = rv & (ix >= 0) & (ix < IW);
                v[r][c] = ok ? loadIn(in, base + iy * IW + ix, f32) : 0.f;
            }
        }
#pragma unroll
        for (int o = 0; o < OCB; ++o) {
            const float* wp = w + ((size_t)((oc0 + o) * IC + ic) << 4);
#pragma unroll
            for (int ky = 0; ky < 4; ++ky)
#pragma unroll
                for (int kx = 0; kx < 4; ++kx) {
                    float wv = wp[ky * 4 + kx];
                    acc[o][0] = fmaf(v[ky][kx], wv, acc[o][0]);
                    acc[o][1] = fmaf(v[ky][kx + 2], wv, acc[o][1]);
                    acc[o][2] = fmaf(v[ky + 2][kx], wv, acc[o][2]);
                    acc[o][3] = fmaf(v[ky + 2][kx + 2], wv, acc[o][3]);
                }
        }
    }
    int oy = 2 * qy, ox = 2 * qx;
    __shared__ float rs[OCB][4], rq[OCB][4];
    int wv_ = threadIdx.x >> 6, ln = threadIdx.x & 63;
#pragma unroll
    for (int o = 0; o < OCB; ++o) {
        float bv = bias[oc0 + o];
        float a0 = acc[o][0] + bv, a1 = acc[o][1] + bv, a2 = acc[o][2] + bv, a3 = acc[o][3] + bv;
        size_t ob = (size_t)(b * OC + oc0 + o) * OH * OW;
        out[ob + (size_t)oy * OW + ox] = f2bf(a0);
        out[ob + (size_t)oy * OW + ox + 1] = f2bf(a1);
        out[ob + (size_t)(oy + 1) * OW + ox] = f2bf(a2);
        out[ob + (size_t)(oy + 1) * OW + ox + 1] = f2bf(a3);
        float s = a0 + a1 + a2 + a3;
        float q = a0 * a0 + a1 * a1 + a2 * a2 + a3 * a3;
#pragma unroll
        for (int off = 32; off > 0; off >>= 1) { s += __shfl_down(s, off); q += __shfl_down(q, off); }
        if (ln == 0) { rs[o][wv_] = s; rq[o][wv_] = q; }
    }
    __syncthreads();
    if (threadIdx.x < OCB) {
        int o = threadIdx.x;
        atomicAdd(&ssum[statoff + oc0 + o], rs[o][0] + rs[o][1] + rs[o][2] + rs[o][3]);
        atomicAdd(&ssq[statoff + oc0 + o], rq[o][0] + rq[o][1] + rq[o][2] + rq[o][3]);
    }
}

// ---------------- conv2 + tanh -> Z_t[...][0:64) (channel-last) ----------------
__global__ void conv_s2_tanh_z(const unsigned short* __restrict__ in, const float* __restrict__ w,
                               const float* __restrict__ bias, unsigned short* __restrict__ zt) {
    const int IC = 128, IH = 32, IW = 32;
    const int OCB = 8;
    int b = blockIdx.z;
    int oc0 = blockIdx.y * OCB;
    int ox = threadIdx.x & 15, oy = threadIdx.x >> 4;  // 256 threads = 16x16 outputs
    int iy0 = 2 * oy - 1, ix0 = 2 * ox - 1;
    float acc[OCB];
#pragma unroll
    for (int o = 0; o < OCB; ++o) acc[o] = 0.f;
    for (int ic = 0; ic < IC; ++ic) {
        size_t base = (size_t)(b * IC + ic) * IH * IW;
        float v[4][4];
#pragma unroll
        for (int r = 0; r < 4; ++r) {
            int iy = iy0 + r;
            bool rv = (iy >= 0) & (iy < IH);
#pragma unroll
            for (int c = 0; c < 4; ++c) {
                int ix = ix0 + c;
                bool ok = rv & (ix >= 0) & (ix < IW);
                v[r][c] = ok ? bf2f_raw(in[base + iy * IW + ix]) : 0.f;
            }
        }
#pragma unroll
        for (int o = 0; o < OCB; ++o) {
            const float* wp = w + ((size_t)((oc0 + o) * IC + ic) << 4);
#pragma unroll
            for (int ky = 0; ky < 4; ++ky)
#pragma unroll
                for (int kx = 0; kx < 4; ++kx)
                    acc[o] = fmaf(v[ky][kx], wp[ky * 4 + kx], acc[o]);
        }
    }
    size_t ob = ((size_t)(b * 256 + oy * 16 + ox)) * 192 + oc0;
#pragma unroll
    for (int o = 0; o < OCB; ++o)
        zt[ob + o] = f2bf(tanhf(acc[o] + bias[oc0 + o]));
}

// ---------------- assemble Z_t[...][64:168) ----------------
__global__ void assemble_z(const void* __restrict__ Zl, const void* __restrict__ Zg,
                           const void* __restrict__ phi, const float* __restrict__ K12,
                           unsigned short* __restrict__ zt, const int* __restrict__ flg) {
    bool f32 = flg[0] != 0;
    int i = blockIdx.x * 256 + threadIdx.x;
    const int TOT = 64 * 104 * 256;
    if (i >= TOT) return;
    int pos = i & 255;
    int t = i >> 8;
    int c104 = t % 104;
    int b = t / 104;
    float val;
    if (c104 < 32) {
        val = loadIn(Zl, ((size_t)(b * 32 + c104) << 8) + pos, f32);
    } else if (c104 < 96) {
        val = loadIn(Zg, ((size_t)(b * 64 + (c104 - 32)) << 8) + pos, f32);
    } else {
        int p = c104 - 96;
        int y = pos >> 4, x = pos & 15;
        float k1 = K12[b * 16 + p];
        float k2 = K12[b * 16 + 8 + p];
        val = sinf(k1 * (float)y + k2 * (float)x + loadIn(phi, b * 8 + p, f32) * TWO_PI_F);
    }
    zt[((size_t)(b * 256 + pos)) * 192 + 64 + c104] = f2bf(val);
}

// ---------------- MFMA transposed-conv (stride2, k=4, p=1), channel-last in/out ----------------
// in_t (64, Q, Q, ICP) bf16; wp (16, OC, ICP) bf16 packed Wpack[ky*4+kx][oc][ic];
// out_t (64, 2Q, 2Q, OC) bf16 (conv + bias).
template <int ICP, int Q, int OC>
__global__ void deconv_mfma_kernel(const unsigned short* __restrict__ in_t,
                                   const unsigned short* __restrict__ wp,
                                   const float* __restrict__ bias,
                                   unsigned short* __restrict__ out_t) {
    constexpr int XT = Q / 16;
    constexpr int NOCT = OC / 64;
    constexpr int NWB = Q * XT * 4 * NOCT;
    int lane = threadIdx.x & 63;
    int gid = (blockIdx.x * 256 + threadIdx.x) >> 6;
    int b = gid / NWB;
    int r = gid % NWB;
    int oct = r % NOCT; r /= NOCT;
    int par = r & 3; r >>= 2;
    int xt = r % XT;
    int qy = r / XT;
    int dy = par >> 1, dx = par & 1;
    int oc0 = oct * 64;
    int m = lane & 15;          // A-row / C-col-n source: m = spatial for A, n for B/C
    int kq = lane >> 4;
    int qx = xt * 16 + m;

    f32x4 acc0 = {0.f, 0.f, 0.f, 0.f}, acc1 = acc0, acc2 = acc0, acc3 = acc0;

#pragma unroll
    for (int t = 0; t < 4; ++t) {
        int rr = t >> 1, cc = t & 1;
        int y = qy - 1 + dy + rr;
        int x = qx - 1 + dx + cc;
        bool ok = ((unsigned)y < (unsigned)Q) & ((unsigned)x < (unsigned)Q);
        const unsigned short* ap =
            in_t + ((size_t)((b * Q + (ok ? y : 0)) * Q + (ok ? x : 0)) * ICP) + kq * 8;
        int ktap = ((3 - dy) - 2 * rr) * 4 + ((3 - dx) - 2 * cc);
        const unsigned short* bp = wp + ((size_t)(ktap * OC + oc0 + m) * ICP) + kq * 8;
#pragma unroll
        for (int k0 = 0; k0 < ICP; k0 += 32) {
            bf16x8 af = {};
            if (ok) af = *(const bf16x8*)(ap + k0);
            bf16x8 b0 = *(const bf16x8*)(bp + k0);
            bf16x8 b1 = *(const bf16x8*)(bp + 16 * ICP + k0);
            bf16x8 b2 = *(const bf16x8*)(bp + 32 * ICP + k0);
            bf16x8 b3 = *(const bf16x8*)(bp + 48 * ICP + k0);
            acc0 = __builtin_amdgcn_mfma_f32_16x16x32_bf16(af, b0, acc0, 0, 0, 0);
            acc1 = __builtin_amdgcn_mfma_f32_16x16x32_bf16(af, b1, acc1, 0, 0, 0);
            acc2 = __builtin_amdgcn_mfma_f32_16x16x32_bf16(af, b2, acc2, 0, 0, 0);
            acc3 = __builtin_amdgcn_mfma_f32_16x16x32_bf16(af, b3, acc3, 0, 0, 0);
        }
    }
    int oy = 2 * qy + dy;
    int n = lane & 15;
    float bv0 = bias[oc0 + n], bv1 = bias[oc0 + 16 + n], bv2 = bias[oc0 + 32 + n], bv3 = bias[oc0 + 48 + n];
#pragma unroll
    for (int reg = 0; reg < 4; ++reg) {
        int mm = kq * 4 + reg;                      // C row = spatial index
        int ox = 2 * (xt * 16 + mm) + dx;
        size_t base = ((size_t)(b * 2 * Q + oy) * (2 * Q) + ox) * OC + oc0 + n;
        out_t[base]      = f2bf(acc0[reg] + bv0);
        out_t[base + 16] = f2bf(acc1[reg] + bv1);
        out_t[base + 32] = f2bf(acc2[reg] + bv2);
        out_t[base + 48] = f2bf(acc3[reg] + bv3);
    }
}

// ---------------- channel-last BN stat reduction ----------------
template <int C>
__global__ void stat_reduce_t(const unsigned short* __restrict__ x, int total4,
                              float* __restrict__ ssum, float* __restrict__ ssq, int statoff) {
    __shared__ float ls[C], lq[C];
    for (int c = threadIdx.x; c < C; c += 256) { ls[c] = 0.f; lq[c] = 0.f; }
    __syncthreads();
    int i0 = blockIdx.x * 256 + threadIdx.x;
    int stride = gridDim.x * 256;                 // stride*4 divisible by C -> c0 invariant
    int c0 = (i0 << 2) & (C - 1);
    float s0 = 0, s1 = 0, s2 = 0, s3 = 0, q0 = 0, q1 = 0, q2 = 0, q3 = 0;
    for (int i = i0; i < total4; i += stride) {
        ushort4 v = *(const ushort4*)(x + ((size_t)i << 2));
        float f0 = bf2f_raw(v.x), f1 = bf2f_raw(v.y), f2 = bf2f_raw(v.z), f3 = bf2f_raw(v.w);
        s0 += f0; s1 += f1; s2 += f2; s3 += f3;
        q0 += f0 * f0; q1 += f1 * f1; q2 += f2 * f2; q3 += f3 * f3;
    }
    atomicAdd(&ls[c0], s0); atomicAdd(&ls[c0 + 1], s1); atomicAdd(&ls[c0 + 2], s2); atomicAdd(&ls[c0 + 3], s3);
    atomicAdd(&lq[c0], q0); atomicAdd(&lq[c0 + 1], q1); atomicAdd(&lq[c0 + 2], q2); atomicAdd(&lq[c0 + 3], q3);
    __syncthreads();
    for (int c = threadIdx.x; c < C; c += 256) {
        atomicAdd(&ssum[statoff + c], ls[c]);
        atomicAdd(&ssq[statoff + c], lq[c]);
    }
}

// ---------------- BN finalize ----------------
__global__ void bn_fin_kernel(const float* __restrict__ ssum, const float* __restrict__ ssq,
                              const float* __restrict__ g, const float* __restrict__ be,
                              float* __restrict__ scale, float* __restrict__ shift,
                              int statoff, int C, float invN) {
    int c = threadIdx.x;
    if (c >= C) return;
    float m = ssum[statoff + c] * invN;
    float v = ssq[statoff + c] * invN - m * m;
    v = fmaxf(v, 0.f);
    float sc = g[c] * rsqrtf(v + 1e-5f);
    scale[statoff + c] = sc;
    shift[statoff + c] = be[c] - m * sc;
}

// ---------------- BN affine + act, channel-FIRST (encoder) ----------------
__global__ void bn_act_kernel(unsigned short* __restrict__ x, const float* __restrict__ scale,
                              const float* __restrict__ shift, int statoff,
                              int n4, int hwShift, int cMask, float slope) {
    int i = blockIdx.x * 256 + threadIdx.x;
    if (i >= n4) return;
    int i4 = i << 2;
    int c = (i4 >> hwShift) & cMask;
    float sc = scale[statoff + c], sh = shift[statoff + c];
    ushort4 v = *reinterpret_cast<ushort4*>(x + i4);
    float f0 = bf2f_raw(v.x) * sc + sh; f0 = f0 > 0.f ? f0 : slope * f0;
    float f1 = bf2f_raw(v.y) * sc + sh; f1 = f1 > 0.f ? f1 : slope * f1;
    float f2 = bf2f_raw(v.z) * sc + sh; f2 = f2 > 0.f ? f2 : slope * f2;
    float f3 = bf2f_raw(v.w) * sc + sh; f3 = f3 > 0.f ? f3 : slope * f3;
    v.x = f2bf(f0); v.y = f2bf(f1); v.z = f2bf(f2); v.w = f2bf(f3);
    *reinterpret_cast<ushort4*>(x + i4) = v;
}

// ---------------- BN affine + relu, channel-LAST (generator) ----------------
template <int C>
__global__ void bn_act_t_kernel(unsigned short* __restrict__ x, int total4,
                                const float* __restrict__ scale, const float* __restrict__ shift,
                                int statoff) {
    int i = blockIdx.x * 256 + threadIdx.x;
    if (i >= total4) return;
    int c0 = (i << 2) & (C - 1);
    float4 sc = *(const float4*)(scale + statoff + c0);
    float4 sh = *(const float4*)(shift + statoff + c0);
    ushort4 v = *(ushort4*)(x + ((size_t)i << 2));
    float f0 = fmaxf(bf2f_raw(v.x) * sc.x + sh.x, 0.f);
    float f1 = fmaxf(bf2f_raw(v.y) * sc.y + sh.y, 0.f);
    float f2 = fmaxf(bf2f_raw(v.z) * sc.z + sh.z, 0.f);
    float f3 = fmaxf(bf2f_raw(v.w) * sc.w + sh.w, 0.f);
    v.x = f2bf(f0); v.y = f2bf(f1); v.z = f2bf(f2); v.w = f2bf(f3);
    *(ushort4*)(x + ((size_t)i << 2)) = v;
}

// ---------------- final transposed conv (channel-last input) + tanh -> fp32 d_out ----------------
__global__ void deconv2_out_t_kernel(const unsigned short* __restrict__ yt,  // (64,64,64,128)
                                     const float* __restrict__ w,            // fp32 (128,3,4,4)
                                     const float* __restrict__ bias,
                                     float* __restrict__ outp) {
    int b = blockIdx.z;
    int tX = blockIdx.x & 3, tY = blockIdx.x >> 2;
    int qx = tX * 16 + (threadIdx.x & 15);
    int qy = tY * 16 + (threadIdx.x >> 4);
    float acc[3][4];
#pragma unroll
    for (int o = 0; o < 3; ++o) { acc[o][0] = acc[o][1] = acc[o][2] = acc[o][3] = 0.f; }
    for (int ic0 = 0; ic0 < 128; ic0 += 4) {
        float v[3][3][4];
#pragma unroll
        for (int r = 0; r < 3; ++r) {
            int y = qy - 1 + r;
            bool rv = (unsigned)y < 64u;
#pragma unroll
            for (int c = 0; c < 3; ++c) {
                int xx = qx - 1 + c;
                bool ok = rv & ((unsigned)xx < 64u);
                ushort4 u = {0, 0, 0, 0};
                if (ok) u = *(const ushort4*)(yt + ((size_t)((b * 64 + y) * 64 + xx) * 128) + ic0);
                v[r][c][0] = bf2f_raw(u.x); v[r][c][1] = bf2f_raw(u.y);
                v[r][c][2] = bf2f_raw(u.z); v[r][c][3] = bf2f_raw(u.w);
            }
        }
#pragma unroll
        for (int q = 0; q < 4; ++q) {
            const float* wic = w + (size_t)(ic0 + q) * 48;
#pragma unroll
            for (int o = 0; o < 3; ++o) {
                const float* wo = wic + o * 16;
                acc[o][0] = fmaf(v[1][1][q], wo[5],  acc[o][0]); acc[o][0] = fmaf(v[1][0][q], wo[7],  acc[o][0]);
                acc[o][0] = fmaf(v[0][1][q], wo[13], acc[o][0]); acc[o][0] = fmaf(v[0][0][q], wo[15], acc[o][0]);
                acc[o][1] = fmaf(v[1][2][q], wo[4],  acc[o][1]); acc[o][1] = fmaf(v[1][1][q], wo[6],  acc[o][1]);
                acc[o][1] = fmaf(v[0][2][q], wo[12], acc[o][1]); acc[o][1] = fmaf(v[0][1][q], wo[14], acc[o][1]);
                acc[o][2] = fmaf(v[2][1][q], wo[1],  acc[o][2]); acc[o][2] = fmaf(v[2][0][q], wo[3],  acc[o][2]);
                acc[o][2] = fmaf(v[1][1][q], wo[9],  acc[o][2]); acc[o][2] = fmaf(v[1][0][q], wo[11], acc[o][2]);
                acc[o][3] = fmaf(v[2][2][q], wo[0],  acc[o][3]); acc[o][3] = fmaf(v[2][1][q], wo[2],  acc[o][3]);
                acc[o][3] = fmaf(v[1][2][q], wo[8],  acc[o][3]); acc[o][3] = fmaf(v[1][1][q], wo[10], acc[o][3]);
            }
        }
    }
    int oy = 2 * qy, ox = 2 * qx;
#pragma unroll
    for (int o = 0; o < 3; ++o) {
        float bv = bias[o];
        size_t ob = (size_t)(b * 3 + o) * 128 * 128;
        outp[ob + (size_t)oy * 128 + ox]           = tanhf(acc[o][0] + bv);
        outp[ob + (size_t)oy * 128 + ox + 1]       = tanhf(acc[o][1] + bv);
        outp[ob + (size_t)(oy + 1) * 128 + ox]     = tanhf(acc[o][2] + bv);
        outp[ob + (size_t)(oy + 1) * 128 + ox + 1] = tanhf(acc[o][3] + bv);
    }
}

extern "C" void kernel_launch(void* const* d_in, const int* in_sizes, int n_in,
                              void* d_out, int out_size, void* d_ws, size_t ws_size,
                              hipStream_t stream) {
    if (ws_size < WS_NEED_BYTES) {
        hipMemsetAsync(d_out, 0, (size_t)out_size * 4, stream);
        return;
    }

    float* W = (float*)d_ws;
    unsigned short* U = (unsigned short*)d_ws;
    int* FLG = (int*)(W + OFF_FLAG);

    detect_kernel<<<1, 256, 0, stream>>>((const unsigned short*)d_in[2], FLG);

    CvtJobs J;
    const int srcIdx[20] = {10, 14, 18, 20, 24, 28, 11, 12, 13, 15, 16, 17, 19, 21, 22, 23, 25, 26, 27, 29};
    const int cnt[20]    = {3072, 131072, 131072, 688128, 524288, 6144,
                            64, 64, 64, 128, 128, 128, 64, 256, 256, 256, 128, 128, 128, 3};
    float* dsts[20] = {W + OFF_WC0, W + OFF_WC1, W + OFF_WC2, W + OFF_WG0, W + OFF_WG1, W + OFF_WG2,
                       W + OFF_CB0, W + OFF_CG0, W + OFF_CBE0, W + OFF_CB1, W + OFF_CG1, W + OFF_CBE1,
                       W + OFF_CB2, W + OFF_GB0, W + OFF_GG0, W + OFF_GBE0, W + OFF_GB1, W + OFF_GG1,
                       W + OFF_GBE1, W + OFF_GB2};
    int off = 0;
    for (int k = 0; k < 20; ++k) {
        J.src[k] = d_in[srcIdx[k]];
        J.dst[k] = dsts[k];
        J.off[k] = off;
        off += cnt[k];
    }
    J.off[20] = off;
    cvt_all_kernel<<<(off + 255) / 256, 256, 0, stream>>>(J, off, FLG);

    zero_kernel<<<5, 256, 0, stream>>>(W + OFF_SSUM, 1152);
    // zero Z_t (pad channels 168..192 must stay 0); 3145728 ushorts = 1572864 floats
    zero_kernel<<<6144, 256, 0, stream>>>((float*)(U + UZT), 1572864);

    // pack deconv weights -> bf16 [ktap][oc][ic]
    pack_w_kernel<<<3072, 256, 0, stream>>>(d_in[20], U + UW0, 168, 192, 256, FLG);
    pack_w_kernel<<<2048, 256, 0, stream>>>(d_in[24], U + UW1, 256, 256, 128, FLG);

    mlp_kernel<<<64, 64, 0, stream>>>(d_in[1], d_in[4], d_in[5], d_in[6], d_in[7],
                                      d_in[8], d_in[9], W + OFF_K12, FLG);

    // ---- encoder conv0: imgs(3,128,128) -> X_enc(64,64,64) [UXT region, ch-first] ----
    conv_s2_bn_kernel<8><<<dim3(4, 8, 64), 256, 0, stream>>>(
        d_in[2], W + OFF_WC0, W + OFF_CB0, U + UXT, W + OFF_SSUM, W + OFF_SSQ, 0,
        3, 128, 128, 64, 64, 64, 2, FLG, 1);
    bn_fin_kernel<<<1, 256, 0, stream>>>(W + OFF_SSUM, W + OFF_SSQ, W + OFF_CG0, W + OFF_CBE0,
                                         W + OFF_SCALE, W + OFF_SHIFT, 0, 64, 1.f / 262144.f);
    bn_act_kernel<<<16384, 256, 0, stream>>>(U + UXT, W + OFF_SCALE, W + OFF_SHIFT, 0,
                                             4194304, 12, 63, 0.2f);

    // ---- encoder conv1: X_enc -> Y_enc(128,32,32) [UYT region head, ch-first] ----
    conv_s2_bn_kernel<8><<<dim3(1, 16, 64), 256, 0, stream>>>(
        U + UXT, W + OFF_WC1, W + OFF_CB1, U + UYT, W + OFF_SSUM, W + OFF_SSQ, 64,
        64, 64, 64, 128, 32, 32, 1, FLG, 0);
    bn_fin_kernel<<<1, 256, 0, stream>>>(W + OFF_SSUM, W + OFF_SSQ, W + OFF_CG1, W + OFF_CBE1,
                                         W + OFF_SCALE, W + OFF_SHIFT, 64, 128, 1.f / 65536.f);
    bn_act_kernel<<<8192, 256, 0, stream>>>(U + UYT, W + OFF_SCALE, W + OFF_SHIFT, 64,
                                            2097152, 10, 127, 0.2f);

    // ---- encoder conv2 + tanh -> Z_t[..][0:64) ----
    conv_s2_tanh_z<<<dim3(1, 8, 64), 256, 0, stream>>>(U + UYT, W + OFF_WC2, W + OFF_CB2, U + UZT);

    // ---- Z_t[..][64:168) ----
    assemble_z<<<6656, 256, 0, stream>>>(d_in[0], d_in[1], d_in[3], W + OFF_K12, U + UZT, FLG);

    // ---- gen deconv0 (MFMA): Z_t(16,16,192) -> X_t(32,32,256) ----
    deconv_mfma_kernel<192, 16, 256><<<4096, 256, 0, stream>>>(U + UZT, U + UW0, W + OFF_GB0, U + UXT);
    stat_reduce_t<256><<<1024, 256, 0, stream>>>(U + UXT, 4194304, W + OFF_SSUM, W + OFF_SSQ, 192);
    bn_fin_kernel<<<1, 256, 0, stream>>>(W + OFF_SSUM, W + OFF_SSQ, W + OFF_GG0, W + OFF_GBE0,
                                         W + OFF_SCALE, W + OFF_SHIFT, 192, 256, 1.f / 65536.f);
    bn_act_t_kernel<256><<<16384, 256, 0, stream>>>(U + UXT, 4194304, W + OFF_SCALE, W + OFF_SHIFT, 192);

    // ---- gen deconv1 (MFMA): X_t(32,32,256) -> Y_t(64,64,128) ----
    deconv_mfma_kernel<256, 32, 128><<<8192, 256, 0, stream>>>(U + UXT, U + UW1, W + OFF_GB1, U + UYT);
    stat_reduce_t<128><<<1024, 256, 0, stream>>>(U + UYT, 8388608, W + OFF_SSUM, W + OFF_SSQ, 448);
    bn_fin_kernel<<<1, 256, 0, stream>>>(W + OFF_SSUM, W + OFF_SSQ, W + OFF_GG1, W + OFF_GBE1,
                                         W + OFF_SCALE, W + OFF_SHIFT, 448, 128, 1.f / 262144.f);
    bn_act_t_kernel<128><<<32768, 256, 0, stream>>>(U + UYT, 8388608, W + OFF_SCALE, W + OFF_SHIFT, 448);

    // ---- gen deconv2 + tanh -> d_out fp32 ----
    deconv2_out_t_kernel<<<dim3(16, 1, 64), 256, 0, stream>>>(U + UYT, W + OFF_WG2, W + OFF_GB2,
                                                              (float*)d_out);
}

// Round 7
// 1810.370 us; speedup vs baseline: 5.7805x; 1.3061x over previous
//
#include <hip/hip_runtime.h>
#include <hip/hip_bf16.h>

#define TWO_PI_F 6.2831853071795864769f

typedef __attribute__((ext_vector_type(8))) __bf16 bf16x8;
typedef __attribute__((ext_vector_type(4))) float f32x4;

__device__ __forceinline__ float bf2f_raw(unsigned short u) {
    return __uint_as_float(((unsigned int)u) << 16);
}
__device__ __forceinline__ unsigned short f2bf(float f) {
    unsigned int u = __float_as_uint(f);
    unsigned int r = (u + 0x7FFFu + ((u >> 16) & 1u)) >> 16;   // RNE
    return (unsigned short)r;
}
__device__ __forceinline__ float loadIn(const void* p, size_t i, bool f32) {
    return f32 ? ((const float*)p)[i] : bf2f_raw(((const unsigned short*)p)[i]);
}

// ---------------- ws layout ----------------
static constexpr size_t OFF_WC0 = 0;          // cod_w0  3072
static constexpr size_t OFF_WC1 = 3072;       // cod_w1  131072
static constexpr size_t OFF_WC2 = 134144;     // cod_w2  131072
static constexpr size_t OFF_WG0 = 265216;     // gen_w0  688128 (fp32; only bias path uses)
static constexpr size_t OFF_WG1 = 953344;     // gen_w1  524288
static constexpr size_t OFF_WG2 = 1477632;    // gen_w2  6144
static constexpr size_t OFF_P   = 1483776;
static constexpr size_t OFF_CB0 = OFF_P + 0;
static constexpr size_t OFF_CG0 = OFF_P + 64;
static constexpr size_t OFF_CBE0= OFF_P + 128;
static constexpr size_t OFF_CB1 = OFF_P + 192;
static constexpr size_t OFF_CG1 = OFF_P + 320;
static constexpr size_t OFF_CBE1= OFF_P + 448;
static constexpr size_t OFF_CB2 = OFF_P + 576;
static constexpr size_t OFF_GB0 = OFF_P + 640;
static constexpr size_t OFF_GG0 = OFF_P + 896;
static constexpr size_t OFF_GBE0= OFF_P + 1152;
static constexpr size_t OFF_GB1 = OFF_P + 1408;
static constexpr size_t OFF_GG1 = OFF_P + 1536;
static constexpr size_t OFF_GBE1= OFF_P + 1664;
static constexpr size_t OFF_GB2 = OFF_P + 1792;
static constexpr size_t OFF_SSUM  = 1485824;    // 576
static constexpr size_t OFF_SSQ   = OFF_SSUM + 576;
static constexpr size_t OFF_SCALE = OFF_SSUM + 1152;
static constexpr size_t OFF_SHIFT = OFF_SCALE + 576;
static constexpr size_t OFF_K12   = OFF_SHIFT + 576;
static constexpr size_t OFF_FLAG  = OFF_K12 + 1024;
// fp32 region ends at 1489168 floats == 2978336 ushorts.
static constexpr size_t UXT = 2978336;                 // X region: conv0-out (b,64,64,64) THEN X_t (b,32,32,256); 16777216
static constexpr size_t UYT = UXT + 16777216;          // Y region: conv1-out (b,128,32,32) head, THEN Y_t (b,64,64,128); 33554432
static constexpr size_t UZT = UYT + 8388608;           // Z_t (b,16,16,192) = 3145728 (dead before Y_t write)
static constexpr size_t UW0 = UYT + 33554432;          // Wpack0 16*256*192 = 786432
static constexpr size_t UW1 = UW0 + 786432;            // Wpack1 16*128*256 = 524288
static constexpr size_t WS_END_USHORT = UW1 + 524288;  // 54620704
static constexpr size_t WS_NEED_BYTES = WS_END_USHORT * 2;  // ~109.2 MB

// stat slots: L0:0(64) L1:64(128) G0:192(256) G1:448(128)

// ---------------- input dtype detection ----------------
__global__ void detect_kernel(const unsigned short* __restrict__ imgs, int* __restrict__ flag) {
    int t = threadIdx.x;  // 256
    unsigned short u = imgs[t];
    int e = (u >> 7) & 0xFF;
    unsigned long long b = __ballot(e >= 0xC0);
    __shared__ int cnt[4];
    if ((t & 63) == 0) cnt[t >> 6] = __popcll(b);
    __syncthreads();
    if (t == 0) flag[0] = (cnt[0] + cnt[1] + cnt[2] + cnt[3] >= 4) ? 1 : 0;
}

// ---------------- weight/param -> fp32 conversion ----------------
struct CvtJobs {
    const void* src[20];
    float* dst[20];
    int off[21];
};

__global__ void cvt_all_kernel(CvtJobs J, int total, const int* __restrict__ flg) {
    int i = blockIdx.x * 256 + threadIdx.x;
    if (i >= total) return;
    bool f32 = flg[0] != 0;
    int k = 0;
#pragma unroll
    for (int t = 0; t < 19; ++t) { if (i >= J.off[t + 1]) k = t + 1; }
    int r = i - J.off[k];
    J.dst[k][r] = loadIn(J.src[k], r, f32);
}

__global__ void zero_kernel(float* p, int n) {
    int i = blockIdx.x * 256 + threadIdx.x;
    if (i < n) p[i] = 0.f;
}

// ---------------- deconv weight packing v2: wave-coalesced B fragments ----------------
// dst[((((ktap*NOCT+oct)*NK + kc)*4 + j)*64 + lane)*8 + jj] = w[ic][oc][ktap]
//   lane = kq*16 + n ; ic = kc*32 + kq*8 + jj ; oc = oct*64 + j*16 + n
__global__ void pack_w2_kernel(const void* __restrict__ src, unsigned short* __restrict__ dst,
                               int ICreal, int ICP, int OC, const int* __restrict__ flg) {
    bool f32 = flg[0] != 0;
    int i = blockIdx.x * 256 + threadIdx.x;
    int total = 16 * OC * ICP;
    if (i >= total) return;
    int jj = i & 7;
    int t1 = i >> 3;
    int lane = t1 & 63;
    int t2 = t1 >> 6;
    int j = t2 & 3;
    int t3 = t2 >> 2;
    int NK = ICP / 32;
    int kc = t3 % NK;
    int t4 = t3 / NK;
    int NOCT = OC / 64;
    int oct = t4 % NOCT;
    int ktap = t4 / NOCT;
    int kq = lane >> 4, n = lane & 15;
    int ic = kc * 32 + kq * 8 + jj;
    int oc = oct * 64 + j * 16 + n;
    unsigned short v = 0;
    if (ic < ICreal) v = f2bf(loadIn(src, ((size_t)(ic * OC + oc) << 4) + ktap, f32));
    dst[i] = v;
}

// ---------------- tiny MLP ----------------
__global__ void mlp_kernel(const void* __restrict__ Zg,
                           const void* __restrict__ lW, const void* __restrict__ lb,
                           const void* __restrict__ l1W, const void* __restrict__ l1b,
                           const void* __restrict__ l2W, const void* __restrict__ l2b,
                           float* __restrict__ K12, const int* __restrict__ flg) {
    bool f32 = flg[0] != 0;
    int b = blockIdx.x;
    int t = threadIdx.x;  // 64
    __shared__ float xs[64];
    float acc = loadIn(lb, t, f32);
    for (int c = 0; c < 64; ++c)
        acc += loadIn(Zg, (size_t)(b * 64 + c) * 256, f32) * loadIn(lW, t * 64 + c, f32);
    xs[t] = fmaxf(acc, 0.f);
    __syncthreads();
    if (t < 16) {
        int p = t & 7;
        const void* Wp = (t < 8) ? l1W : l2W;
        const void* bp = (t < 8) ? l1b : l2b;
        float a = loadIn(bp, p, f32);
        for (int h = 0; h < 64; ++h) a += xs[h] * loadIn(Wp, p * 64 + h, f32);
        K12[b * 16 + t] = a;
    }
}

// ---------------- stride-2 conv (k=4,p=1), OCB oc/block, 2x2 quad/thread, +stats (encoder) ----------------
template <int OCB>
__global__ void conv_s2_bn_kernel(const void* __restrict__ in, const float* __restrict__ w,
                                  const float* __restrict__ bias, unsigned short* __restrict__ out,
                                  float* __restrict__ ssum, float* __restrict__ ssq, int statoff,
                                  int IC, int IH, int IW, int OC, int OH, int OW, int tilesX,
                                  const int* __restrict__ flg, int useFlag) {
    bool f32 = useFlag && (flg[0] != 0);
    int b = blockIdx.z;
    int oc0 = blockIdx.y * OCB;
    int tX = blockIdx.x % tilesX;
    int tY = blockIdx.x / tilesX;
    int qx = tX * 16 + (threadIdx.x & 15);
    int qy = tY * 16 + (threadIdx.x >> 4);
    int iy0 = 4 * qy - 1;
    int ix0 = 4 * qx - 1;
    float acc[OCB][4];
#pragma unroll
    for (int o = 0; o < OCB; ++o) { acc[o][0] = acc[o][1] = acc[o][2] = acc[o][3] = 0.f; }
    for (int ic = 0; ic < IC; ++ic) {
        size_t base = (size_t)(b * IC + ic) * IH * IW;
        float v[6][6];
#pragma unroll
        for (int r = 0; r < 6; ++r) {
            int iy = iy0 + r;
            bool rv = (iy >= 0) & (iy < IH);
#pragma unroll
            for (int c = 0; c < 6; ++c) {
                int ix = ix0 + c;
                bool ok = rv & (ix >= 0) & (ix < IW);
                v[r][c] = ok ? loadIn(in, base + iy * IW + ix, f32) : 0.f;
            }
        }
#pragma unroll
        for (int o = 0; o < OCB; ++o) {
            const float* wp = w + ((size_t)((oc0 + o) * IC + ic) << 4);
#pragma unroll
            for (int ky = 0; ky < 4; ++ky)
#pragma unroll
                for (int kx = 0; kx < 4; ++kx) {
                    float wv = wp[ky * 4 + kx];
                    acc[o][0] = fmaf(v[ky][kx], wv, acc[o][0]);
                    acc[o][1] = fmaf(v[ky][kx + 2], wv, acc[o][1]);
                    acc[o][2] = fmaf(v[ky + 2][kx], wv, acc[o][2]);
                    acc[o][3] = fmaf(v[ky + 2][kx + 2], wv, acc[o][3]);
                }
        }
    }
    int oy = 2 * qy, ox = 2 * qx;
    __shared__ float rs[OCB][4], rq[OCB][4];
    int wv_ = threadIdx.x >> 6, ln = threadIdx.x & 63;
#pragma unroll
    for (int o = 0; o < OCB; ++o) {
        float bv = bias[oc0 + o];
        float a0 = acc[o][0] + bv, a1 = acc[o][1] + bv, a2 = acc[o][2] + bv, a3 = acc[o][3] + bv;
        size_t ob = (size_t)(b * OC + oc0 + o) * OH * OW;
        out[ob + (size_t)oy * OW + ox] = f2bf(a0);
        out[ob + (size_t)oy * OW + ox + 1] = f2bf(a1);
        out[ob + (size_t)(oy + 1) * OW + ox] = f2bf(a2);
        out[ob + (size_t)(oy + 1) * OW + ox + 1] = f2bf(a3);
        float s = a0 + a1 + a2 + a3;
        float q = a0 * a0 + a1 * a1 + a2 * a2 + a3 * a3;
#pragma unroll
        for (int off = 32; off > 0; off >>= 1) { s += __shfl_down(s, off); q += __shfl_down(q, off); }
        if (ln == 0) { rs[o][wv_] = s; rq[o][wv_] = q; }
    }
    __syncthreads();
    if (threadIdx.x < OCB) {
        int o = threadIdx.x;
        atomicAdd(&ssum[statoff + oc0 + o], rs[o][0] + rs[o][1] + rs[o][2] + rs[o][3]);
        atomicAdd(&ssq[statoff + oc0 + o], rq[o][0] + rq[o][1] + rq[o][2] + rq[o][3]);
    }
}

// ---------------- conv2 + tanh -> Z_t[...][0:64) (channel-last) ----------------
__global__ void conv_s2_tanh_z(const unsigned short* __restrict__ in, const float* __restrict__ w,
                               const float* __restrict__ bias, unsigned short* __restrict__ zt) {
    const int IC = 128, IH = 32, IW = 32;
    const int OCB = 8;
    int b = blockIdx.z;
    int oc0 = blockIdx.y * OCB;
    int ox = threadIdx.x & 15, oy = threadIdx.x >> 4;  // 256 threads = 16x16 outputs
    int iy0 = 2 * oy - 1, ix0 = 2 * ox - 1;
    float acc[OCB];
#pragma unroll
    for (int o = 0; o < OCB; ++o) acc[o] = 0.f;
    for (int ic = 0; ic < IC; ++ic) {
        size_t base = (size_t)(b * IC + ic) * IH * IW;
        float v[4][4];
#pragma unroll
        for (int r = 0; r < 4; ++r) {
            int iy = iy0 + r;
            bool rv = (iy >= 0) & (iy < IH);
#pragma unroll
            for (int c = 0; c < 4; ++c) {
                int ix = ix0 + c;
                bool ok = rv & (ix >= 0) & (ix < IW);
                v[r][c] = ok ? bf2f_raw(in[base + iy * IW + ix]) : 0.f;
            }
        }
#pragma unroll
        for (int o = 0; o < OCB; ++o) {
            const float* wp = w + ((size_t)((oc0 + o) * IC + ic) << 4);
#pragma unroll
            for (int ky = 0; ky < 4; ++ky)
#pragma unroll
                for (int kx = 0; kx < 4; ++kx)
                    acc[o] = fmaf(v[ky][kx], wp[ky * 4 + kx], acc[o]);
        }
    }
    size_t ob = ((size_t)(b * 256 + oy * 16 + ox)) * 192 + oc0;
#pragma unroll
    for (int o = 0; o < OCB; ++o)
        zt[ob + o] = f2bf(tanhf(acc[o] + bias[oc0 + o]));
}

// ---------------- assemble Z_t[...][64:168) ----------------
__global__ void assemble_z(const void* __restrict__ Zl, const void* __restrict__ Zg,
                           const void* __restrict__ phi, const float* __restrict__ K12,
                           unsigned short* __restrict__ zt, const int* __restrict__ flg) {
    bool f32 = flg[0] != 0;
    int i = blockIdx.x * 256 + threadIdx.x;
    const int TOT = 64 * 104 * 256;
    if (i >= TOT) return;
    int pos = i & 255;
    int t = i >> 8;
    int c104 = t % 104;
    int b = t / 104;
    float val;
    if (c104 < 32) {
        val = loadIn(Zl, ((size_t)(b * 32 + c104) << 8) + pos, f32);
    } else if (c104 < 96) {
        val = loadIn(Zg, ((size_t)(b * 64 + (c104 - 32)) << 8) + pos, f32);
    } else {
        int p = c104 - 96;
        int y = pos >> 4, x = pos & 15;
        float k1 = K12[b * 16 + p];
        float k2 = K12[b * 16 + 8 + p];
        val = sinf(k1 * (float)y + k2 * (float)x + loadIn(phi, b * 8 + p, f32) * TWO_PI_F);
    }
    zt[((size_t)(b * 256 + pos)) * 192 + 64 + c104] = f2bf(val);
}

// ---------------- MFMA transposed-conv v2: LDS-staged A, coalesced packed B ----------------
// in_t (64,Q,Q,ICP) bf16; wp2 packed per pack_w2; out_t (64,2Q,2Q,OC) bf16 (+bias).
// Block = 256 thr = 4 waves = 4 parities; covers qy0..qy0+1 rows x one 16-wide x-tile.
template <int ICP, int Q, int OC>
__global__ void deconv_mfma2_kernel(const unsigned short* __restrict__ in_t,
                                    const unsigned short* __restrict__ wp2,
                                    const float* __restrict__ bias,
                                    unsigned short* __restrict__ out_t) {
    constexpr int NOCT = OC / 64;
    constexpr int NK = ICP / 32;
    constexpr int XT = Q / 16;
    constexpr int NQB = Q / 2;
    constexpr int STRIDE = ICP + 8;            // (ICP+8)*2B is a 16B multiple
    __shared__ unsigned short lds[4 * 18 * STRIDE];

    int bid = blockIdx.x;
    int xt = bid % XT;
    int t2 = bid / XT;
    int qp = t2 % NQB;
    int b = t2 / NQB;
    int qy0 = qp * 2;
    int x0 = xt * 16;

    // ---- stage A tile: rows qy0-1..qy0+2, cols x0-1..x0+16, all ICP (zeros OOB) ----
    constexpr int P8 = ICP / 8;
    constexpr int E8 = 4 * 18 * P8;
    for (int i = threadIdx.x; i < E8; i += 256) {
        int icc = i % P8;
        int rc = i / P8;
        int row = rc / 18, col = rc % 18;
        int y = qy0 - 1 + row, x = x0 - 1 + col;
        uint4 val = {0u, 0u, 0u, 0u};
        if (((unsigned)y < (unsigned)Q) & ((unsigned)x < (unsigned)Q))
            val = *(const uint4*)(in_t + (size_t)((b * Q + y) * Q + x) * ICP + icc * 8);
        *(uint4*)(lds + rc * STRIDE + icc * 8) = val;
    }
    __syncthreads();

    int wv = threadIdx.x >> 6, lane = threadIdx.x & 63;
    int dy = wv >> 1, dx = wv & 1;
    int m = lane & 15, kq = lane >> 4;

    for (int oct = 0; oct < NOCT; ++oct) {
        f32x4 acc[2][4];
#pragma unroll
        for (int q = 0; q < 2; ++q)
#pragma unroll
            for (int j = 0; j < 4; ++j) acc[q][j] = (f32x4){0.f, 0.f, 0.f, 0.f};

#pragma unroll
        for (int t = 0; t < 4; ++t) {
            int rr = t >> 1, cc = t & 1;
            int ktap = ((3 - dy) - 2 * rr) * 4 + ((3 - dx) - 2 * cc);
            int col = m + dx + cc;
            int row0 = dy + rr;
            const unsigned short* bbase = wp2 + (size_t)((ktap * NOCT + oct) * NK) * 2048;
#pragma unroll
            for (int kc = 0; kc < NK; ++kc) {
                bf16x8 a0 = *(const bf16x8*)(lds + (row0 * 18 + col) * STRIDE + kc * 32 + kq * 8);
                bf16x8 a1 = *(const bf16x8*)(lds + ((row0 + 1) * 18 + col) * STRIDE + kc * 32 + kq * 8);
                bf16x8 b0 = *(const bf16x8*)(bbase + (kc * 4 + 0) * 512 + lane * 8);
                bf16x8 b1 = *(const bf16x8*)(bbase + (kc * 4 + 1) * 512 + lane * 8);
                bf16x8 b2 = *(const bf16x8*)(bbase + (kc * 4 + 2) * 512 + lane * 8);
                bf16x8 b3 = *(const bf16x8*)(bbase + (kc * 4 + 3) * 512 + lane * 8);
                acc[0][0] = __builtin_amdgcn_mfma_f32_16x16x32_bf16(a0, b0, acc[0][0], 0, 0, 0);
                acc[0][1] = __builtin_amdgcn_mfma_f32_16x16x32_bf16(a0, b1, acc[0][1], 0, 0, 0);
                acc[0][2] = __builtin_amdgcn_mfma_f32_16x16x32_bf16(a0, b2, acc[0][2], 0, 0, 0);
                acc[0][3] = __builtin_amdgcn_mfma_f32_16x16x32_bf16(a0, b3, acc[0][3], 0, 0, 0);
                acc[1][0] = __builtin_amdgcn_mfma_f32_16x16x32_bf16(a1, b0, acc[1][0], 0, 0, 0);
                acc[1][1] = __builtin_amdgcn_mfma_f32_16x16x32_bf16(a1, b1, acc[1][1], 0, 0, 0);
                acc[1][2] = __builtin_amdgcn_mfma_f32_16x16x32_bf16(a1, b2, acc[1][2], 0, 0, 0);
                acc[1][3] = __builtin_amdgcn_mfma_f32_16x16x32_bf16(a1, b3, acc[1][3], 0, 0, 0);
            }
        }
        // epilogue for this oct
        int n = m;
        float bv0 = bias[oct * 64 + n];
        float bv1 = bias[oct * 64 + 16 + n];
        float bv2 = bias[oct * 64 + 32 + n];
        float bv3 = bias[oct * 64 + 48 + n];
#pragma unroll
        for (int qyl = 0; qyl < 2; ++qyl) {
            int oy = 2 * (qy0 + qyl) + dy;
#pragma unroll
            for (int reg = 0; reg < 4; ++reg) {
                int mm = kq * 4 + reg;
                int ox = 2 * (x0 + mm) + dx;
                size_t base = ((size_t)((b * 2 * Q + oy) * (2 * Q) + ox)) * OC + oct * 64 + n;
                out_t[base]      = f2bf(acc[qyl][0][reg] + bv0);
                out_t[base + 16] = f2bf(acc[qyl][1][reg] + bv1);
                out_t[base + 32] = f2bf(acc[qyl][2][reg] + bv2);
                out_t[base + 48] = f2bf(acc[qyl][3][reg] + bv3);
            }
        }
    }
}

// ---------------- channel-last BN stat reduction ----------------
template <int C>
__global__ void stat_reduce_t(const unsigned short* __restrict__ x, int total4,
                              float* __restrict__ ssum, float* __restrict__ ssq, int statoff) {
    __shared__ float ls[C], lq[C];
    for (int c = threadIdx.x; c < C; c += 256) { ls[c] = 0.f; lq[c] = 0.f; }
    __syncthreads();
    int i0 = blockIdx.x * 256 + threadIdx.x;
    int stride = gridDim.x * 256;
    int c0 = (i0 << 2) & (C - 1);
    float s0 = 0, s1 = 0, s2 = 0, s3 = 0, q0 = 0, q1 = 0, q2 = 0, q3 = 0;
    for (int i = i0; i < total4; i += stride) {
        ushort4 v = *(const ushort4*)(x + ((size_t)i << 2));
        float f0 = bf2f_raw(v.x), f1 = bf2f_raw(v.y), f2 = bf2f_raw(v.z), f3 = bf2f_raw(v.w);
        s0 += f0; s1 += f1; s2 += f2; s3 += f3;
        q0 += f0 * f0; q1 += f1 * f1; q2 += f2 * f2; q3 += f3 * f3;
    }
    atomicAdd(&ls[c0], s0); atomicAdd(&ls[c0 + 1], s1); atomicAdd(&ls[c0 + 2], s2); atomicAdd(&ls[c0 + 3], s3);
    atomicAdd(&lq[c0], q0); atomicAdd(&lq[c0 + 1], q1); atomicAdd(&lq[c0 + 2], q2); atomicAdd(&lq[c0 + 3], q3);
    __syncthreads();
    for (int c = threadIdx.x; c < C; c += 256) {
        atomicAdd(&ssum[statoff + c], ls[c]);
        atomicAdd(&ssq[statoff + c], lq[c]);
    }
}

// ---------------- BN finalize ----------------
__global__ void bn_fin_kernel(const float* __restrict__ ssum, const float* __restrict__ ssq,
                              const float* __restrict__ g, const float* __restrict__ be,
                              float* __restrict__ scale, float* __restrict__ shift,
                              int statoff, int C, float invN) {
    int c = threadIdx.x;
    if (c >= C) return;
    float m = ssum[statoff + c] * invN;
    float v = ssq[statoff + c] * invN - m * m;
    v = fmaxf(v, 0.f);
    float sc = g[c] * rsqrtf(v + 1e-5f);
    scale[statoff + c] = sc;
    shift[statoff + c] = be[c] - m * sc;
}

// ---------------- BN affine + act, channel-FIRST (encoder) ----------------
__global__ void bn_act_kernel(unsigned short* __restrict__ x, const float* __restrict__ scale,
                              const float* __restrict__ shift, int statoff,
                              int n4, int hwShift, int cMask, float slope) {
    int i = blockIdx.x * 256 + threadIdx.x;
    if (i >= n4) return;
    int i4 = i << 2;
    int c = (i4 >> hwShift) & cMask;
    float sc = scale[statoff + c], sh = shift[statoff + c];
    ushort4 v = *reinterpret_cast<ushort4*>(x + i4);
    float f0 = bf2f_raw(v.x) * sc + sh; f0 = f0 > 0.f ? f0 : slope * f0;
    float f1 = bf2f_raw(v.y) * sc + sh; f1 = f1 > 0.f ? f1 : slope * f1;
    float f2 = bf2f_raw(v.z) * sc + sh; f2 = f2 > 0.f ? f2 : slope * f2;
    float f3 = bf2f_raw(v.w) * sc + sh; f3 = f3 > 0.f ? f3 : slope * f3;
    v.x = f2bf(f0); v.y = f2bf(f1); v.z = f2bf(f2); v.w = f2bf(f3);
    *reinterpret_cast<ushort4*>(x + i4) = v;
}

// ---------------- BN affine + relu, channel-LAST (generator) ----------------
template <int C>
__global__ void bn_act_t_kernel(unsigned short* __restrict__ x, int total4,
                                const float* __restrict__ scale, const float* __restrict__ shift,
                                int statoff) {
    int i = blockIdx.x * 256 + threadIdx.x;
    if (i >= total4) return;
    int c0 = (i << 2) & (C - 1);
    float4 sc = *(const float4*)(scale + statoff + c0);
    float4 sh = *(const float4*)(shift + statoff + c0);
    ushort4 v = *(ushort4*)(x + ((size_t)i << 2));
    float f0 = fmaxf(bf2f_raw(v.x) * sc.x + sh.x, 0.f);
    float f1 = fmaxf(bf2f_raw(v.y) * sc.y + sh.y, 0.f);
    float f2 = fmaxf(bf2f_raw(v.z) * sc.z + sh.z, 0.f);
    float f3 = fmaxf(bf2f_raw(v.w) * sc.w + sh.w, 0.f);
    v.x = f2bf(f0); v.y = f2bf(f1); v.z = f2bf(f2); v.w = f2bf(f3);
    *(ushort4*)(x + ((size_t)i << 2)) = v;
}

// ---------------- final transposed conv (channel-last input) + tanh -> fp32 d_out ----------------
__global__ void deconv2_out_t_kernel(const unsigned short* __restrict__ yt,  // (64,64,64,128)
                                     const float* __restrict__ w,            // fp32 (128,3,4,4)
                                     const float* __restrict__ bias,
                                     float* __restrict__ outp) {
    int b = blockIdx.z;
    int tX = blockIdx.x & 3, tY = blockIdx.x >> 2;
    int qx = tX * 16 + (threadIdx.x & 15);
    int qy = tY * 16 + (threadIdx.x >> 4);
    float acc[3][4];
#pragma unroll
    for (int o = 0; o < 3; ++o) { acc[o][0] = acc[o][1] = acc[o][2] = acc[o][3] = 0.f; }
    for (int ic0 = 0; ic0 < 128; ic0 += 4) {
        float v[3][3][4];
#pragma unroll
        for (int r = 0; r < 3; ++r) {
            int y = qy - 1 + r;
            bool rv = (unsigned)y < 64u;
#pragma unroll
            for (int c = 0; c < 3; ++c) {
                int xx = qx - 1 + c;
                bool ok = rv & ((unsigned)xx < 64u);
                ushort4 u = {0, 0, 0, 0};
                if (ok) u = *(const ushort4*)(yt + ((size_t)((b * 64 + y) * 64 + xx) * 128) + ic0);
                v[r][c][0] = bf2f_raw(u.x); v[r][c][1] = bf2f_raw(u.y);
                v[r][c][2] = bf2f_raw(u.z); v[r][c][3] = bf2f_raw(u.w);
            }
        }
#pragma unroll
        for (int q = 0; q < 4; ++q) {
            const float* wic = w + (size_t)(ic0 + q) * 48;
#pragma unroll
            for (int o = 0; o < 3; ++o) {
                const float* wo = wic + o * 16;
                acc[o][0] = fmaf(v[1][1][q], wo[5],  acc[o][0]); acc[o][0] = fmaf(v[1][0][q], wo[7],  acc[o][0]);
                acc[o][0] = fmaf(v[0][1][q], wo[13], acc[o][0]); acc[o][0] = fmaf(v[0][0][q], wo[15], acc[o][0]);
                acc[o][1] = fmaf(v[1][2][q], wo[4],  acc[o][1]); acc[o][1] = fmaf(v[1][1][q], wo[6],  acc[o][1]);
                acc[o][1] = fmaf(v[0][2][q], wo[12], acc[o][1]); acc[o][1] = fmaf(v[0][1][q], wo[14], acc[o][1]);
                acc[o][2] = fmaf(v[2][1][q], wo[1],  acc[o][2]); acc[o][2] = fmaf(v[2][0][q], wo[3],  acc[o][2]);
                acc[o][2] = fmaf(v[1][1][q], wo[9],  acc[o][2]); acc[o][2] = fmaf(v[1][0][q], wo[11], acc[o][2]);
                acc[o][3] = fmaf(v[2][2][q], wo[0],  acc[o][3]); acc[o][3] = fmaf(v[2][1][q], wo[2],  acc[o][3]);
                acc[o][3] = fmaf(v[1][2][q], wo[8],  acc[o][3]); acc[o][3] = fmaf(v[1][1][q], wo[10], acc[o][3]);
            }
        }
    }
    int oy = 2 * qy, ox = 2 * qx;
#pragma unroll
    for (int o = 0; o < 3; ++o) {
        float bv = bias[o];
        size_t ob = (size_t)(b * 3 + o) * 128 * 128;
        outp[ob + (size_t)oy * 128 + ox]           = tanhf(acc[o][0] + bv);
        outp[ob + (size_t)oy * 128 + ox + 1]       = tanhf(acc[o][1] + bv);
        outp[ob + (size_t)(oy + 1) * 128 + ox]     = tanhf(acc[o][2] + bv);
        outp[ob + (size_t)(oy + 1) * 128 + ox + 1] = tanhf(acc[o][3] + bv);
    }
}

extern "C" void kernel_launch(void* const* d_in, const int* in_sizes, int n_in,
                              void* d_out, int out_size, void* d_ws, size_t ws_size,
                              hipStream_t stream) {
    if (ws_size < WS_NEED_BYTES) {
        hipMemsetAsync(d_out, 0, (size_t)out_size * 4, stream);
        return;
    }

    float* W = (float*)d_ws;
    unsigned short* U = (unsigned short*)d_ws;
    int* FLG = (int*)(W + OFF_FLAG);

    detect_kernel<<<1, 256, 0, stream>>>((const unsigned short*)d_in[2], FLG);

    CvtJobs J;
    const int srcIdx[20] = {10, 14, 18, 20, 24, 28, 11, 12, 13, 15, 16, 17, 19, 21, 22, 23, 25, 26, 27, 29};
    const int cnt[20]    = {3072, 131072, 131072, 688128, 524288, 6144,
                            64, 64, 64, 128, 128, 128, 64, 256, 256, 256, 128, 128, 128, 3};
    float* dsts[20] = {W + OFF_WC0, W + OFF_WC1, W + OFF_WC2, W + OFF_WG0, W + OFF_WG1, W + OFF_WG2,
                       W + OFF_CB0, W + OFF_CG0, W + OFF_CBE0, W + OFF_CB1, W + OFF_CG1, W + OFF_CBE1,
                       W + OFF_CB2, W + OFF_GB0, W + OFF_GG0, W + OFF_GBE0, W + OFF_GB1, W + OFF_GG1,
                       W + OFF_GBE1, W + OFF_GB2};
    int off = 0;
    for (int k = 0; k < 20; ++k) {
        J.src[k] = d_in[srcIdx[k]];
        J.dst[k] = dsts[k];
        J.off[k] = off;
        off += cnt[k];
    }
    J.off[20] = off;
    cvt_all_kernel<<<(off + 255) / 256, 256, 0, stream>>>(J, off, FLG);

    zero_kernel<<<5, 256, 0, stream>>>(W + OFF_SSUM, 1152);
    // zero Z_t (pad channels 168..192 must stay 0)
    zero_kernel<<<6144, 256, 0, stream>>>((float*)(U + UZT), 1572864);

    // pack deconv weights (wave-coalesced fragments)
    pack_w2_kernel<<<3072, 256, 0, stream>>>(d_in[20], U + UW0, 168, 192, 256, FLG);
    pack_w2_kernel<<<2048, 256, 0, stream>>>(d_in[24], U + UW1, 256, 256, 128, FLG);

    mlp_kernel<<<64, 64, 0, stream>>>(d_in[1], d_in[4], d_in[5], d_in[6], d_in[7],
                                      d_in[8], d_in[9], W + OFF_K12, FLG);

    // ---- encoder conv0: imgs(3,128,128) -> X_enc(64,64,64) [UXT region, ch-first] ----
    conv_s2_bn_kernel<8><<<dim3(4, 8, 64), 256, 0, stream>>>(
        d_in[2], W + OFF_WC0, W + OFF_CB0, U + UXT, W + OFF_SSUM, W + OFF_SSQ, 0,
        3, 128, 128, 64, 64, 64, 2, FLG, 1);
    bn_fin_kernel<<<1, 256, 0, stream>>>(W + OFF_SSUM, W + OFF_SSQ, W + OFF_CG0, W + OFF_CBE0,
                                         W + OFF_SCALE, W + OFF_SHIFT, 0, 64, 1.f / 262144.f);
    bn_act_kernel<<<16384, 256, 0, stream>>>(U + UXT, W + OFF_SCALE, W + OFF_SHIFT, 0,
                                             4194304, 12, 63, 0.2f);

    // ---- encoder conv1: X_enc -> Y_enc(128,32,32) [UYT region head, ch-first] ----
    conv_s2_bn_kernel<8><<<dim3(1, 16, 64), 256, 0, stream>>>(
        U + UXT, W + OFF_WC1, W + OFF_CB1, U + UYT, W + OFF_SSUM, W + OFF_SSQ, 64,
        64, 64, 64, 128, 32, 32, 1, FLG, 0);
    bn_fin_kernel<<<1, 256, 0, stream>>>(W + OFF_SSUM, W + OFF_SSQ, W + OFF_CG1, W + OFF_CBE1,
                                         W + OFF_SCALE, W + OFF_SHIFT, 64, 128, 1.f / 65536.f);
    bn_act_kernel<<<8192, 256, 0, stream>>>(U + UYT, W + OFF_SCALE, W + OFF_SHIFT, 64,
                                            2097152, 10, 127, 0.2f);

    // ---- encoder conv2 + tanh -> Z_t[..][0:64) ----
    conv_s2_tanh_z<<<dim3(1, 8, 64), 256, 0, stream>>>(U + UYT, W + OFF_WC2, W + OFF_CB2, U + UZT);

    // ---- Z_t[..][64:168) ----
    assemble_z<<<6656, 256, 0, stream>>>(d_in[0], d_in[1], d_in[3], W + OFF_K12, U + UZT, FLG);

    // ---- gen deconv0 (MFMA v2): Z_t(16,16,192) -> X_t(32,32,256) ----
    deconv_mfma2_kernel<192, 16, 256><<<512, 256, 0, stream>>>(U + UZT, U + UW0, W + OFF_GB0, U + UXT);
    stat_reduce_t<256><<<1024, 256, 0, stream>>>(U + UXT, 4194304, W + OFF_SSUM, W + OFF_SSQ, 192);
    bn_fin_kernel<<<1, 256, 0, stream>>>(W + OFF_SSUM, W + OFF_SSQ, W + OFF_GG0, W + OFF_GBE0,
                                         W + OFF_SCALE, W + OFF_SHIFT, 192, 256, 1.f / 65536.f);
    bn_act_t_kernel<256><<<16384, 256, 0, stream>>>(U + UXT, 4194304, W + OFF_SCALE, W + OFF_SHIFT, 192);

    // ---- gen deconv1 (MFMA v2): X_t(32,32,256) -> Y_t(64,64,128) ----
    deconv_mfma2_kernel<256, 32, 128><<<2048, 256, 0, stream>>>(U + UXT, U + UW1, W + OFF_GB1, U + UYT);
    stat_reduce_t<128><<<1024, 256, 0, stream>>>(U + UYT, 8388608, W + OFF_SSUM, W + OFF_SSQ, 448);
    bn_fin_kernel<<<1, 256, 0, stream>>>(W + OFF_SSUM, W + OFF_SSQ, W + OFF_GG1, W + OFF_GBE1,
                                         W + OFF_SCALE, W + OFF_SHIFT, 448, 128, 1.f / 262144.f);
    bn_act_t_kernel<128><<<32768, 256, 0, stream>>>(U + UYT, 8388608, W + OFF_SCALE, W + OFF_SHIFT, 448);

    // ---- gen deconv2 + tanh -> d_out fp32 ----
    deconv2_out_t_kernel<<<dim3(16, 1, 64), 256, 0, stream>>>(U + UYT, W + OFF_WG2, W + OFF_GB2,
                                                              (float*)d_out);
}

// Round 8
// 1169.928 us; speedup vs baseline: 8.9448x; 1.5474x over previous
//
#include <hip/hip_runtime.h>
#include <hip/hip_bf16.h>

#define TWO_PI_F 6.2831853071795864769f

typedef __attribute__((ext_vector_type(8))) __bf16 bf16x8;
typedef __attribute__((ext_vector_type(4))) float f32x4;

__device__ __forceinline__ float bf2f_raw(unsigned short u) {
    return __uint_as_float(((unsigned int)u) << 16);
}
__device__ __forceinline__ unsigned short f2bf(float f) {
    unsigned int u = __float_as_uint(f);
    unsigned int r = (u + 0x7FFFu + ((u >> 16) & 1u)) >> 16;   // RNE
    return (unsigned short)r;
}
__device__ __forceinline__ float loadIn(const void* p, size_t i, bool f32) {
    return f32 ? ((const float*)p)[i] : bf2f_raw(((const unsigned short*)p)[i]);
}

// ---------------- ws layout ----------------
static constexpr size_t OFF_WC0 = 0;          // cod_w0 fp32 3072
static constexpr size_t OFF_WG2 = 3072;       // gen_w2 fp32 6144
static constexpr size_t OFF_P   = 9216;
static constexpr size_t OFF_CB0 = OFF_P + 0;
static constexpr size_t OFF_CG0 = OFF_P + 64;
static constexpr size_t OFF_CBE0= OFF_P + 128;
static constexpr size_t OFF_CB1 = OFF_P + 192;
static constexpr size_t OFF_CG1 = OFF_P + 320;
static constexpr size_t OFF_CBE1= OFF_P + 448;
static constexpr size_t OFF_CB2 = OFF_P + 576;
static constexpr size_t OFF_GB0 = OFF_P + 640;
static constexpr size_t OFF_GG0 = OFF_P + 896;
static constexpr size_t OFF_GBE0= OFF_P + 1152;
static constexpr size_t OFF_GB1 = OFF_P + 1408;
static constexpr size_t OFF_GG1 = OFF_P + 1536;
static constexpr size_t OFF_GBE1= OFF_P + 1664;
static constexpr size_t OFF_GB2 = OFF_P + 1792;
static constexpr size_t OFF_SSUM  = OFF_P + 2048;   // 576
static constexpr size_t OFF_SSQ   = OFF_SSUM + 576;
static constexpr size_t OFF_SCALE = OFF_SSUM + 1152;
static constexpr size_t OFF_SHIFT = OFF_SCALE + 576;
static constexpr size_t OFF_K12   = OFF_SHIFT + 576;
static constexpr size_t OFF_FLAG  = OFF_K12 + 1024;
static constexpr size_t FP32_END  = OFF_FLAG + 16;   // floats
// ushort regions (offsets in ushorts), aligned after fp32 region:
static constexpr size_t UXT = 2 * FP32_END;            // X region: X_s2d (b,2,2,32,32,64) then X_t (b,32,32,256); 16777216
static constexpr size_t UYT = UXT + 16777216;          // Y region: Y_s2d (b,2,2,16,16,128) head, then Y_t (b,64,64,128); 33554432
static constexpr size_t UZT = UYT + 8388608;           // Z_t (b,16,16,192) = 3145728 (dead before Y_t write)
static constexpr size_t UW0 = UYT + 33554432;          // deconv0 pack 16*256*192 = 786432
static constexpr size_t UW1 = UW0 + 786432;            // deconv1 pack 16*128*256 = 524288
static constexpr size_t UWC1 = UW1 + 524288;           // conv1 pack 16*128*64 = 131072
static constexpr size_t UWC2 = UWC1 + 131072;          // conv2 pack 16*64*128 = 131072
static constexpr size_t WS_END_USHORT = UWC2 + 131072;
static constexpr size_t WS_NEED_BYTES = WS_END_USHORT * 2;   // ~109.8 MB

// stat slots: L0:0(64) L1:64(128) G0:192(256) G1:448(128)

// ---------------- input dtype detection ----------------
__global__ void detect_kernel(const unsigned short* __restrict__ imgs, int* __restrict__ flag) {
    int t = threadIdx.x;  // 256
    unsigned short u = imgs[t];
    int e = (u >> 7) & 0xFF;
    unsigned long long b = __ballot(e >= 0xC0);
    __shared__ int cnt[4];
    if ((t & 63) == 0) cnt[t >> 6] = __popcll(b);
    __syncthreads();
    if (t == 0) flag[0] = (cnt[0] + cnt[1] + cnt[2] + cnt[3] >= 4) ? 1 : 0;
}

// ---------------- small param -> fp32 conversion ----------------
struct CvtJobs {
    const void* src[16];
    float* dst[16];
    int off[17];
};

__global__ void cvt_all_kernel(CvtJobs J, int total, const int* __restrict__ flg) {
    int i = blockIdx.x * 256 + threadIdx.x;
    if (i >= total) return;
    bool f32 = flg[0] != 0;
    int k = 0;
#pragma unroll
    for (int t = 0; t < 15; ++t) { if (i >= J.off[t + 1]) k = t + 1; }
    int r = i - J.off[k];
    J.dst[k][r] = loadIn(J.src[k], r, f32);
}

__global__ void zero_kernel(float* p, int n) {
    int i = blockIdx.x * 256 + threadIdx.x;
    if (i < n) p[i] = 0.f;
}

// ---------------- deconv weight packing: wave-coalesced B fragments ----------------
// dst[(((ktap*NOCT+oct)*NK + kc)*4 + j)*512 + lane*8 + jj] = w_deconv[ic][oc][ktap]
__global__ void pack_w2_kernel(const void* __restrict__ src, unsigned short* __restrict__ dst,
                               int ICreal, int ICP, int OC, const int* __restrict__ flg) {
    bool f32 = flg[0] != 0;
    int i = blockIdx.x * 256 + threadIdx.x;
    int total = 16 * OC * ICP;
    if (i >= total) return;
    int jj = i & 7;
    int lane = (i >> 3) & 63;
    int j = (i >> 9) & 3;
    int t3 = i >> 11;
    int NK = ICP / 32;
    int kc = t3 % NK;
    int t4 = t3 / NK;
    int NOCT = OC / 64;
    int oct = t4 % NOCT;
    int ktap = t4 / NOCT;
    int kq = lane >> 4, n = lane & 15;
    int ic = kc * 32 + kq * 8 + jj;
    int oc = oct * 64 + j * 16 + n;
    unsigned short v = 0;
    if (ic < ICreal) v = f2bf(loadIn(src, ((size_t)(ic * OC + oc) << 4) + ktap, f32));
    dst[i] = v;
}

// ---------------- conv weight packing (w layout (OC,IC,4,4)) ----------------
__global__ void pack_wc_kernel(const void* __restrict__ src, unsigned short* __restrict__ dst,
                               int IC, int OC, const int* __restrict__ flg) {
    bool f32 = flg[0] != 0;
    int i = blockIdx.x * 256 + threadIdx.x;
    int total = 16 * OC * IC;
    if (i >= total) return;
    int jj = i & 7;
    int lane = (i >> 3) & 63;
    int j = (i >> 9) & 3;
    int t3 = i >> 11;
    int NK = IC / 32;
    int kc = t3 % NK;
    int t4 = t3 / NK;
    int NOCT = OC / 64;
    int oct = t4 % NOCT;
    int ktap = t4 / NOCT;
    int kq = lane >> 4, n = lane & 15;
    int ic = kc * 32 + kq * 8 + jj;
    int oc = oct * 64 + j * 16 + n;
    dst[i] = f2bf(loadIn(src, ((size_t)(oc * IC + ic) << 4) + ktap, f32));
}

// ---------------- tiny MLP ----------------
__global__ void mlp_kernel(const void* __restrict__ Zg,
                           const void* __restrict__ lW, const void* __restrict__ lb,
                           const void* __restrict__ l1W, const void* __restrict__ l1b,
                           const void* __restrict__ l2W, const void* __restrict__ l2b,
                           float* __restrict__ K12, const int* __restrict__ flg) {
    bool f32 = flg[0] != 0;
    int b = blockIdx.x;
    int t = threadIdx.x;  // 64
    __shared__ float xs[64];
    float acc = loadIn(lb, t, f32);
    for (int c = 0; c < 64; ++c)
        acc += loadIn(Zg, (size_t)(b * 64 + c) * 256, f32) * loadIn(lW, t * 64 + c, f32);
    xs[t] = fmaxf(acc, 0.f);
    __syncthreads();
    if (t < 16) {
        int p = t & 7;
        const void* Wp = (t < 8) ? l1W : l2W;
        const void* bp = (t < 8) ? l1b : l2b;
        float a = loadIn(bp, p, f32);
        for (int h = 0; h < 64; ++h) a += xs[h] * loadIn(Wp, p * 64 + h, f32);
        K12[b * 16 + t] = a;
    }
}

// ---------------- conv0: imgs (b,3,128,128) -> X_s2d (b,2,2,32,32,64), vector, LDS-tiled ----------------
__global__ void conv0_s2d_kernel(const void* __restrict__ imgs, const float* __restrict__ w,
                                 const float* __restrict__ bias, unsigned short* __restrict__ xs,
                                 const int* __restrict__ flg) {
    bool f32 = flg[0] != 0;
    int b = blockIdx.z;
    int tile = blockIdx.x;                 // 16 tiles: 4x4 of 16x16 output px
    int Y0 = (tile >> 2) * 16, X0 = (tile & 3) * 16;
    __shared__ float vin[3 * 34 * 35];
    __shared__ float wl[64 * 49];
    for (int i = threadIdx.x; i < 3 * 34 * 34; i += 256) {
        int c = i % 34; int t = i / 34; int r = t % 34; int ic = t / 34;
        int iy = 2 * Y0 - 1 + r, ix = 2 * X0 - 1 + c;
        float v = 0.f;
        if (((unsigned)iy < 128u) & ((unsigned)ix < 128u))
            v = loadIn(imgs, ((size_t)(b * 3 + ic) * 128 + iy) * 128 + ix, f32);
        vin[(ic * 34 + r) * 35 + c] = v;
    }
    for (int i = threadIdx.x; i < 3072; i += 256) {
        int oc = i / 48, idx = i % 48;
        wl[oc * 49 + idx] = w[i];
    }
    __syncthreads();
    int q = threadIdx.x >> 2;              // 64 quads
    int ocq = threadIdx.x & 3;
    int qy = q >> 3, qx = q & 7;
    float acc[4][16];
#pragma unroll
    for (int p = 0; p < 4; ++p)
#pragma unroll
        for (int o = 0; o < 16; ++o) acc[p][o] = 0.f;
    for (int ic = 0; ic < 3; ++ic) {
        float v[6][6];
#pragma unroll
        for (int r = 0; r < 6; ++r)
#pragma unroll
            for (int c = 0; c < 6; ++c)
                v[r][c] = vin[(ic * 34 + 4 * qy + r) * 35 + 4 * qx + c];
#pragma unroll
        for (int o = 0; o < 16; ++o) {
            const float* wo = wl + (ocq * 16 + o) * 49 + ic * 16;
#pragma unroll
            for (int ky = 0; ky < 4; ++ky)
#pragma unroll
                for (int kx = 0; kx < 4; ++kx) {
                    float wv = wo[ky * 4 + kx];
                    acc[0][o] = fmaf(v[ky][kx], wv, acc[0][o]);
                    acc[1][o] = fmaf(v[ky][kx + 2], wv, acc[1][o]);
                    acc[2][o] = fmaf(v[ky + 2][kx], wv, acc[2][o]);
                    acc[3][o] = fmaf(v[ky + 2][kx + 2], wv, acc[3][o]);
                }
        }
    }
    int j = (Y0 >> 1) + qy, i2 = (X0 >> 1) + qx;
#pragma unroll
    for (int p = 0; p < 4; ++p) {
        int dy = p >> 1, dx = p & 1;
        unsigned short tmp[16];
#pragma unroll
        for (int o = 0; o < 16; ++o) tmp[o] = f2bf(acc[p][o] + bias[ocq * 16 + o]);
        unsigned short* dst = xs + (((size_t)((b * 2 + dy) * 2 + dx) * 32 + j) * 32 + i2) * 64 + ocq * 16;
        *(uint4*)(dst) = *(const uint4*)(tmp);
        *(uint4*)(dst + 8) = *(const uint4*)(tmp + 8);
    }
}

// ---------------- conv1 (MFMA): X_s2d (b,2,2,32,32,64) -> Y_s2d (b,2,2,16,16,128) ----------------
__global__ void conv1_mfma_kernel(const unsigned short* __restrict__ xs,
                                  const unsigned short* __restrict__ wp,
                                  const float* __restrict__ bias,
                                  unsigned short* __restrict__ ys) {
    constexpr int STR = 72;                        // 64 + 8 pad
    __shared__ unsigned short lds[4 * 3 * 17 * STR];   // 29.4 KB
    int bid = blockIdx.x;
    int xt = bid & 1;
    int qp = (bid >> 1) & 15;
    int b = bid >> 5;
    int oy0 = qp * 2, x0 = xt * 16;
    // stage: 4 planes x 3 rows x 17 cols x 8 uint4 = 1632
    for (int i = threadIdx.x; i < 1632; i += 256) {
        int icc = i & 7; int t = i >> 3;
        int col = t % 17; int rc = t / 17;
        int row = rc % 3; int pl = rc / 3;
        int py = pl >> 1, px = pl & 1;
        int j = oy0 - py + row;
        int ci = x0 - px + col;
        uint4 v = {0u, 0u, 0u, 0u};
        if (((unsigned)j < 32u) & ((unsigned)ci < 32u))
            v = *(const uint4*)(xs + ((size_t)((b * 4 + pl) * 32 + j) * 32 + ci) * 64 + icc * 8);
        *(uint4*)(lds + ((pl * 3 + row) * 17 + col) * STR + icc * 8) = v;
    }
    __syncthreads();

    int wv = threadIdx.x >> 6, lane = threadIdx.x & 63;
    int r = wv >> 1, oct = wv & 1;
    int m = lane & 15, kq = lane >> 4;
    f32x4 acc[4];
#pragma unroll
    for (int j = 0; j < 4; ++j) acc[j] = (f32x4){0.f, 0.f, 0.f, 0.f};

    // ky -> (py, jofs): 0:(1,-1) 1:(0,0) 2:(1,0) 3:(0,1); lrow = r + (ky>>1); lcol = m + (kx>>1)
#pragma unroll
    for (int ky = 0; ky < 4; ++ky) {
        int py = (ky & 1) ^ 1;
        int lrow = r + (ky >> 1);
#pragma unroll
        for (int kx = 0; kx < 4; ++kx) {
            int px = (kx & 1) ^ 1;
            int pl = py * 2 + px;
            int lcol = m + (kx >> 1);
            const unsigned short* lp = lds + ((pl * 3 + lrow) * 17 + lcol) * STR + kq * 8;
            int ktap = ky * 4 + kx;
            const unsigned short* bb = wp + (size_t)(ktap * 2 + oct) * 4096;
#pragma unroll
            for (int kc = 0; kc < 2; ++kc) {
                bf16x8 a = *(const bf16x8*)(lp + kc * 32);
                const unsigned short* bk = bb + kc * 2048 + lane * 8;
                bf16x8 b0 = *(const bf16x8*)(bk);
                bf16x8 b1 = *(const bf16x8*)(bk + 512);
                bf16x8 b2 = *(const bf16x8*)(bk + 1024);
                bf16x8 b3 = *(const bf16x8*)(bk + 1536);
                acc[0] = __builtin_amdgcn_mfma_f32_16x16x32_bf16(a, b0, acc[0], 0, 0, 0);
                acc[1] = __builtin_amdgcn_mfma_f32_16x16x32_bf16(a, b1, acc[1], 0, 0, 0);
                acc[2] = __builtin_amdgcn_mfma_f32_16x16x32_bf16(a, b2, acc[2], 0, 0, 0);
                acc[3] = __builtin_amdgcn_mfma_f32_16x16x32_bf16(a, b3, acc[3], 0, 0, 0);
            }
        }
    }
    int oy = oy0 + r;
    int pyo = oy & 1, jo = oy >> 1;
    int n = m;
    float bv0 = bias[oct * 64 + n], bv1 = bias[oct * 64 + 16 + n];
    float bv2 = bias[oct * 64 + 32 + n], bv3 = bias[oct * 64 + 48 + n];
#pragma unroll
    for (int reg = 0; reg < 4; ++reg) {
        int mm = kq * 4 + reg;
        int ox = x0 + mm;
        int pxo = ox & 1, io = ox >> 1;
        size_t base = (((size_t)((b * 2 + pyo) * 2 + pxo) * 16 + jo) * 16 + io) * 128 + oct * 64 + n;
        ys[base]      = f2bf(acc[0][reg] + bv0);
        ys[base + 16] = f2bf(acc[1][reg] + bv1);
        ys[base + 32] = f2bf(acc[2][reg] + bv2);
        ys[base + 48] = f2bf(acc[3][reg] + bv3);
    }
}

// ---------------- conv2 (MFMA) + tanh: Y_s2d (b,2,2,16,16,128) -> Z_t (b,16,16,192)[0:64) ----------------
__global__ void conv2_mfma_kernel(const unsigned short* __restrict__ ys,
                                  const unsigned short* __restrict__ wp,
                                  const float* __restrict__ bias,
                                  unsigned short* __restrict__ zt) {
    constexpr int STR = 136;                       // 128 + 8 pad
    __shared__ unsigned short lds[4 * 3 * 17 * STR];   // 55.5 KB
    int bid = blockIdx.x;
    int qp = bid & 7;
    int b = bid >> 3;
    int oy0 = qp * 2;
    // stage: 4 planes x 3 rows x 17 cols x 16 uint4 = 3264
    for (int i = threadIdx.x; i < 3264; i += 256) {
        int icc = i & 15; int t = i >> 4;
        int col = t % 17; int rc = t / 17;
        int row = rc % 3; int pl = rc / 3;
        int py = pl >> 1, px = pl & 1;
        int j = oy0 - py + row;
        int ci = col - px;
        uint4 v = {0u, 0u, 0u, 0u};
        if (((unsigned)j < 16u) & ((unsigned)ci < 16u))
            v = *(const uint4*)(ys + ((size_t)((b * 4 + pl) * 16 + j) * 16 + ci) * 128 + icc * 8);
        *(uint4*)(lds + ((pl * 3 + row) * 17 + col) * STR + icc * 8) = v;
    }
    __syncthreads();

    int wv = threadIdx.x >> 6, lane = threadIdx.x & 63;
    int r = wv >> 1, jh = wv & 1;
    int m = lane & 15, kq = lane >> 4;
    f32x4 acc[2];
    acc[0] = (f32x4){0.f, 0.f, 0.f, 0.f};
    acc[1] = acc[0];
#pragma unroll
    for (int ky = 0; ky < 4; ++ky) {
        int py = (ky & 1) ^ 1;
        int lrow = r + (ky >> 1);
#pragma unroll
        for (int kx = 0; kx < 4; ++kx) {
            int px = (kx & 1) ^ 1;
            int pl = py * 2 + px;
            int lcol = m + (kx >> 1);
            const unsigned short* lp = lds + ((pl * 3 + lrow) * 17 + lcol) * STR + kq * 8;
            int ktap = ky * 4 + kx;
            const unsigned short* bb = wp + (size_t)ktap * 8192;
#pragma unroll
            for (int kc = 0; kc < 4; ++kc) {
                bf16x8 a = *(const bf16x8*)(lp + kc * 32);
                const unsigned short* bk = bb + kc * 2048 + (jh * 2) * 512 + lane * 8;
                bf16x8 b0 = *(const bf16x8*)(bk);
                bf16x8 b1 = *(const bf16x8*)(bk + 512);
                acc[0] = __builtin_amdgcn_mfma_f32_16x16x32_bf16(a, b0, acc[0], 0, 0, 0);
                acc[1] = __builtin_amdgcn_mfma_f32_16x16x32_bf16(a, b1, acc[1], 0, 0, 0);
            }
        }
    }
    int oy = oy0 + r;
    int n = m;
    float bv0 = bias[(jh * 2) * 16 + n], bv1 = bias[(jh * 2 + 1) * 16 + n];
#pragma unroll
    for (int reg = 0; reg < 4; ++reg) {
        int x = kq * 4 + reg;
        size_t base = ((size_t)(b * 16 + oy) * 16 + x) * 192 + (jh * 2) * 16 + n;
        zt[base]      = f2bf(tanhf(acc[0][reg] + bv0));
        zt[base + 16] = f2bf(tanhf(acc[1][reg] + bv1));
    }
}

// ---------------- assemble Z_t[...][64:168) ----------------
__global__ void assemble_z(const void* __restrict__ Zl, const void* __restrict__ Zg,
                           const void* __restrict__ phi, const float* __restrict__ K12,
                           unsigned short* __restrict__ zt, const int* __restrict__ flg) {
    bool f32 = flg[0] != 0;
    int i = blockIdx.x * 256 + threadIdx.x;
    const int TOT = 64 * 104 * 256;
    if (i >= TOT) return;
    int pos = i & 255;
    int t = i >> 8;
    int c104 = t % 104;
    int b = t / 104;
    float val;
    if (c104 < 32) {
        val = loadIn(Zl, ((size_t)(b * 32 + c104) << 8) + pos, f32);
    } else if (c104 < 96) {
        val = loadIn(Zg, ((size_t)(b * 64 + (c104 - 32)) << 8) + pos, f32);
    } else {
        int p = c104 - 96;
        int y = pos >> 4, x = pos & 15;
        float k1 = K12[b * 16 + p];
        float k2 = K12[b * 16 + 8 + p];
        val = sinf(k1 * (float)y + k2 * (float)x + loadIn(phi, b * 8 + p, f32) * TWO_PI_F);
    }
    zt[((size_t)(b * 256 + pos)) * 192 + 64 + c104] = f2bf(val);
}

// ---------------- MFMA transposed-conv v2 (unchanged, verified) ----------------
template <int ICP, int Q, int OC>
__global__ void deconv_mfma2_kernel(const unsigned short* __restrict__ in_t,
                                    const unsigned short* __restrict__ wp2,
                                    const float* __restrict__ bias,
                                    unsigned short* __restrict__ out_t) {
    constexpr int NOCT = OC / 64;
    constexpr int NK = ICP / 32;
    constexpr int XT = Q / 16;
    constexpr int NQB = Q / 2;
    constexpr int STRIDE = ICP + 8;
    __shared__ unsigned short lds[4 * 18 * STRIDE];

    int bid = blockIdx.x;
    int xt = bid % XT;
    int t2 = bid / XT;
    int qp = t2 % NQB;
    int b = t2 / NQB;
    int qy0 = qp * 2;
    int x0 = xt * 16;

    constexpr int P8 = ICP / 8;
    constexpr int E8 = 4 * 18 * P8;
    for (int i = threadIdx.x; i < E8; i += 256) {
        int icc = i % P8;
        int rc = i / P8;
        int row = rc / 18, col = rc % 18;
        int y = qy0 - 1 + row, x = x0 - 1 + col;
        uint4 val = {0u, 0u, 0u, 0u};
        if (((unsigned)y < (unsigned)Q) & ((unsigned)x < (unsigned)Q))
            val = *(const uint4*)(in_t + (size_t)((b * Q + y) * Q + x) * ICP + icc * 8);
        *(uint4*)(lds + rc * STRIDE + icc * 8) = val;
    }
    __syncthreads();

    int wv = threadIdx.x >> 6, lane = threadIdx.x & 63;
    int dy = wv >> 1, dx = wv & 1;
    int m = lane & 15, kq = lane >> 4;

    for (int oct = 0; oct < NOCT; ++oct) {
        f32x4 acc[2][4];
#pragma unroll
        for (int q = 0; q < 2; ++q)
#pragma unroll
            for (int j = 0; j < 4; ++j) acc[q][j] = (f32x4){0.f, 0.f, 0.f, 0.f};

#pragma unroll
        for (int t = 0; t < 4; ++t) {
            int rr = t >> 1, cc = t & 1;
            int ktap = ((3 - dy) - 2 * rr) * 4 + ((3 - dx) - 2 * cc);
            int col = m + dx + cc;
            int row0 = dy + rr;
            const unsigned short* bbase = wp2 + (size_t)((ktap * NOCT + oct) * NK) * 2048;
#pragma unroll
            for (int kc = 0; kc < NK; ++kc) {
                bf16x8 a0 = *(const bf16x8*)(lds + (row0 * 18 + col) * STRIDE + kc * 32 + kq * 8);
                bf16x8 a1 = *(const bf16x8*)(lds + ((row0 + 1) * 18 + col) * STRIDE + kc * 32 + kq * 8);
                bf16x8 b0 = *(const bf16x8*)(bbase + (kc * 4 + 0) * 512 + lane * 8);
                bf16x8 b1 = *(const bf16x8*)(bbase + (kc * 4 + 1) * 512 + lane * 8);
                bf16x8 b2 = *(const bf16x8*)(bbase + (kc * 4 + 2) * 512 + lane * 8);
                bf16x8 b3 = *(const bf16x8*)(bbase + (kc * 4 + 3) * 512 + lane * 8);
                acc[0][0] = __builtin_amdgcn_mfma_f32_16x16x32_bf16(a0, b0, acc[0][0], 0, 0, 0);
                acc[0][1] = __builtin_amdgcn_mfma_f32_16x16x32_bf16(a0, b1, acc[0][1], 0, 0, 0);
                acc[0][2] = __builtin_amdgcn_mfma_f32_16x16x32_bf16(a0, b2, acc[0][2], 0, 0, 0);
                acc[0][3] = __builtin_amdgcn_mfma_f32_16x16x32_bf16(a0, b3, acc[0][3], 0, 0, 0);
                acc[1][0] = __builtin_amdgcn_mfma_f32_16x16x32_bf16(a1, b0, acc[1][0], 0, 0, 0);
                acc[1][1] = __builtin_amdgcn_mfma_f32_16x16x32_bf16(a1, b1, acc[1][1], 0, 0, 0);
                acc[1][2] = __builtin_amdgcn_mfma_f32_16x16x32_bf16(a1, b2, acc[1][2], 0, 0, 0);
                acc[1][3] = __builtin_amdgcn_mfma_f32_16x16x32_bf16(a1, b3, acc[1][3], 0, 0, 0);
            }
        }
        int n = m;
        float bv0 = bias[oct * 64 + n];
        float bv1 = bias[oct * 64 + 16 + n];
        float bv2 = bias[oct * 64 + 32 + n];
        float bv3 = bias[oct * 64 + 48 + n];
#pragma unroll
        for (int qyl = 0; qyl < 2; ++qyl) {
            int oy = 2 * (qy0 + qyl) + dy;
#pragma unroll
            for (int reg = 0; reg < 4; ++reg) {
                int mm = kq * 4 + reg;
                int ox = 2 * (x0 + mm) + dx;
                size_t base = ((size_t)((b * 2 * Q + oy) * (2 * Q) + ox)) * OC + oct * 64 + n;
                out_t[base]      = f2bf(acc[qyl][0][reg] + bv0);
                out_t[base + 16] = f2bf(acc[qyl][1][reg] + bv1);
                out_t[base + 32] = f2bf(acc[qyl][2][reg] + bv2);
                out_t[base + 48] = f2bf(acc[qyl][3][reg] + bv3);
            }
        }
    }
}

// ---------------- channel-last BN stat reduction ----------------
template <int C>
__global__ void stat_reduce_t(const unsigned short* __restrict__ x, int total4,
                              float* __restrict__ ssum, float* __restrict__ ssq, int statoff) {
    __shared__ float ls[C], lq[C];
    for (int c = threadIdx.x; c < C; c += 256) { ls[c] = 0.f; lq[c] = 0.f; }
    __syncthreads();
    int i0 = blockIdx.x * 256 + threadIdx.x;
    int stride = gridDim.x * 256;
    int c0 = (i0 << 2) & (C - 1);
    float s0 = 0, s1 = 0, s2 = 0, s3 = 0, q0 = 0, q1 = 0, q2 = 0, q3 = 0;
    for (int i = i0; i < total4; i += stride) {
        ushort4 v = *(const ushort4*)(x + ((size_t)i << 2));
        float f0 = bf2f_raw(v.x), f1 = bf2f_raw(v.y), f2 = bf2f_raw(v.z), f3 = bf2f_raw(v.w);
        s0 += f0; s1 += f1; s2 += f2; s3 += f3;
        q0 += f0 * f0; q1 += f1 * f1; q2 += f2 * f2; q3 += f3 * f3;
    }
    atomicAdd(&ls[c0], s0); atomicAdd(&ls[c0 + 1], s1); atomicAdd(&ls[c0 + 2], s2); atomicAdd(&ls[c0 + 3], s3);
    atomicAdd(&lq[c0], q0); atomicAdd(&lq[c0 + 1], q1); atomicAdd(&lq[c0 + 2], q2); atomicAdd(&lq[c0 + 3], q3);
    __syncthreads();
    for (int c = threadIdx.x; c < C; c += 256) {
        atomicAdd(&ssum[statoff + c], ls[c]);
        atomicAdd(&ssq[statoff + c], lq[c]);
    }
}

// ---------------- BN finalize ----------------
__global__ void bn_fin_kernel(const float* __restrict__ ssum, const float* __restrict__ ssq,
                              const float* __restrict__ g, const float* __restrict__ be,
                              float* __restrict__ scale, float* __restrict__ shift,
                              int statoff, int C, float invN) {
    int c = threadIdx.x;
    if (c >= C) return;
    float m = ssum[statoff + c] * invN;
    float v = ssq[statoff + c] * invN - m * m;
    v = fmaxf(v, 0.f);
    float sc = g[c] * rsqrtf(v + 1e-5f);
    scale[statoff + c] = sc;
    shift[statoff + c] = be[c] - m * sc;
}

// ---------------- BN affine + (leaky)relu, channel-LAST ----------------
template <int C>
__global__ void bn_act_t_kernel(unsigned short* __restrict__ x, int total4,
                                const float* __restrict__ scale, const float* __restrict__ shift,
                                int statoff, float slope) {
    int i = blockIdx.x * 256 + threadIdx.x;
    if (i >= total4) return;
    int c0 = (i << 2) & (C - 1);
    float4 sc = *(const float4*)(scale + statoff + c0);
    float4 sh = *(const float4*)(shift + statoff + c0);
    ushort4 v = *(ushort4*)(x + ((size_t)i << 2));
    float f0 = bf2f_raw(v.x) * sc.x + sh.x; f0 = f0 > 0.f ? f0 : slope * f0;
    float f1 = bf2f_raw(v.y) * sc.y + sh.y; f1 = f1 > 0.f ? f1 : slope * f1;
    float f2 = bf2f_raw(v.z) * sc.z + sh.z; f2 = f2 > 0.f ? f2 : slope * f2;
    float f3 = bf2f_raw(v.w) * sc.w + sh.w; f3 = f3 > 0.f ? f3 : slope * f3;
    v.x = f2bf(f0); v.y = f2bf(f1); v.z = f2bf(f2); v.w = f2bf(f3);
    *(ushort4*)(x + ((size_t)i << 2)) = v;
}

// ---------------- final transposed conv (channel-last input) + tanh -> fp32 d_out ----------------
__global__ void deconv2_out_t_kernel(const unsigned short* __restrict__ yt,  // (64,64,64,128)
                                     const float* __restrict__ w,            // fp32 (128,3,4,4)
                                     const float* __restrict__ bias,
                                     float* __restrict__ outp) {
    int b = blockIdx.z;
    int tX = blockIdx.x & 3, tY = blockIdx.x >> 2;
    int qx = tX * 16 + (threadIdx.x & 15);
    int qy = tY * 16 + (threadIdx.x >> 4);
    float acc[3][4];
#pragma unroll
    for (int o = 0; o < 3; ++o) { acc[o][0] = acc[o][1] = acc[o][2] = acc[o][3] = 0.f; }
    for (int ic0 = 0; ic0 < 128; ic0 += 4) {
        float v[3][3][4];
#pragma unroll
        for (int r = 0; r < 3; ++r) {
            int y = qy - 1 + r;
            bool rv = (unsigned)y < 64u;
#pragma unroll
            for (int c = 0; c < 3; ++c) {
                int xx = qx - 1 + c;
                bool ok = rv & ((unsigned)xx < 64u);
                ushort4 u = {0, 0, 0, 0};
                if (ok) u = *(const ushort4*)(yt + ((size_t)((b * 64 + y) * 64 + xx) * 128) + ic0);
                v[r][c][0] = bf2f_raw(u.x); v[r][c][1] = bf2f_raw(u.y);
                v[r][c][2] = bf2f_raw(u.z); v[r][c][3] = bf2f_raw(u.w);
            }
        }
#pragma unroll
        for (int q = 0; q < 4; ++q) {
            const float* wic = w + (size_t)(ic0 + q) * 48;
#pragma unroll
            for (int o = 0; o < 3; ++o) {
                const float* wo = wic + o * 16;
                acc[o][0] = fmaf(v[1][1][q], wo[5],  acc[o][0]); acc[o][0] = fmaf(v[1][0][q], wo[7],  acc[o][0]);
                acc[o][0] = fmaf(v[0][1][q], wo[13], acc[o][0]); acc[o][0] = fmaf(v[0][0][q], wo[15], acc[o][0]);
                acc[o][1] = fmaf(v[1][2][q], wo[4],  acc[o][1]); acc[o][1] = fmaf(v[1][1][q], wo[6],  acc[o][1]);
                acc[o][1] = fmaf(v[0][2][q], wo[12], acc[o][1]); acc[o][1] = fmaf(v[0][1][q], wo[14], acc[o][1]);
                acc[o][2] = fmaf(v[2][1][q], wo[1],  acc[o][2]); acc[o][2] = fmaf(v[2][0][q], wo[3],  acc[o][2]);
                acc[o][2] = fmaf(v[1][1][q], wo[9],  acc[o][2]); acc[o][2] = fmaf(v[1][0][q], wo[11], acc[o][2]);
                acc[o][3] = fmaf(v[2][2][q], wo[0],  acc[o][3]); acc[o][3] = fmaf(v[2][1][q], wo[2],  acc[o][3]);
                acc[o][3] = fmaf(v[1][2][q], wo[8],  acc[o][3]); acc[o][3] = fmaf(v[1][1][q], wo[10], acc[o][3]);
            }
        }
    }
    int oy = 2 * qy, ox = 2 * qx;
#pragma unroll
    for (int o = 0; o < 3; ++o) {
        float bv = bias[o];
        size_t ob = (size_t)(b * 3 + o) * 128 * 128;
        outp[ob + (size_t)oy * 128 + ox]           = tanhf(acc[o][0] + bv);
        outp[ob + (size_t)oy * 128 + ox + 1]       = tanhf(acc[o][1] + bv);
        outp[ob + (size_t)(oy + 1) * 128 + ox]     = tanhf(acc[o][2] + bv);
        outp[ob + (size_t)(oy + 1) * 128 + ox + 1] = tanhf(acc[o][3] + bv);
    }
}

extern "C" void kernel_launch(void* const* d_in, const int* in_sizes, int n_in,
                              void* d_out, int out_size, void* d_ws, size_t ws_size,
                              hipStream_t stream) {
    if (ws_size < WS_NEED_BYTES) {
        hipMemsetAsync(d_out, 0, (size_t)out_size * 4, stream);
        return;
    }

    float* W = (float*)d_ws;
    unsigned short* U = (unsigned short*)d_ws;
    int* FLG = (int*)(W + OFF_FLAG);

    detect_kernel<<<1, 256, 0, stream>>>((const unsigned short*)d_in[2], FLG);

    // small fp32 conversions: cod_w0, gen_w2, all bias/gamma/beta
    CvtJobs J;
    const int srcIdx[16] = {10, 28, 11, 12, 13, 15, 16, 17, 19, 21, 22, 23, 25, 26, 27, 29};
    const int cnt[16]    = {3072, 6144, 64, 64, 64, 128, 128, 128, 64, 256, 256, 256, 128, 128, 128, 3};
    float* dsts[16] = {W + OFF_WC0, W + OFF_WG2,
                       W + OFF_CB0, W + OFF_CG0, W + OFF_CBE0, W + OFF_CB1, W + OFF_CG1, W + OFF_CBE1,
                       W + OFF_CB2, W + OFF_GB0, W + OFF_GG0, W + OFF_GBE0, W + OFF_GB1, W + OFF_GG1,
                       W + OFF_GBE1, W + OFF_GB2};
    int off = 0;
    for (int k = 0; k < 16; ++k) {
        J.src[k] = d_in[srcIdx[k]];
        J.dst[k] = dsts[k];
        J.off[k] = off;
        off += cnt[k];
    }
    J.off[16] = off;
    cvt_all_kernel<<<(off + 255) / 256, 256, 0, stream>>>(J, off, FLG);

    zero_kernel<<<5, 256, 0, stream>>>(W + OFF_SSUM, 1152);
    zero_kernel<<<6144, 256, 0, stream>>>((float*)(U + UZT), 1572864);   // Z_t incl. pad ch

    // weight packs
    pack_w2_kernel<<<3072, 256, 0, stream>>>(d_in[20], U + UW0, 168, 192, 256, FLG);
    pack_w2_kernel<<<2048, 256, 0, stream>>>(d_in[24], U + UW1, 256, 256, 128, FLG);
    pack_wc_kernel<<<512, 256, 0, stream>>>(d_in[14], U + UWC1, 64, 128, FLG);
    pack_wc_kernel<<<512, 256, 0, stream>>>(d_in[18], U + UWC2, 128, 64, FLG);

    mlp_kernel<<<64, 64, 0, stream>>>(d_in[1], d_in[4], d_in[5], d_in[6], d_in[7],
                                      d_in[8], d_in[9], W + OFF_K12, FLG);

    // ---- conv0 -> X_s2d ----
    conv0_s2d_kernel<<<dim3(16, 1, 64), 256, 0, stream>>>(d_in[2], W + OFF_WC0, W + OFF_CB0,
                                                          U + UXT, FLG);
    stat_reduce_t<64><<<1024, 256, 0, stream>>>(U + UXT, 4194304, W + OFF_SSUM, W + OFF_SSQ, 0);
    bn_fin_kernel<<<1, 256, 0, stream>>>(W + OFF_SSUM, W + OFF_SSQ, W + OFF_CG0, W + OFF_CBE0,
                                         W + OFF_SCALE, W + OFF_SHIFT, 0, 64, 1.f / 262144.f);
    bn_act_t_kernel<64><<<16384, 256, 0, stream>>>(U + UXT, 4194304, W + OFF_SCALE, W + OFF_SHIFT, 0, 0.2f);

    // ---- conv1 (MFMA) -> Y_s2d ----
    conv1_mfma_kernel<<<2048, 256, 0, stream>>>(U + UXT, U + UWC1, W + OFF_CB1, U + UYT);
    stat_reduce_t<128><<<1024, 256, 0, stream>>>(U + UYT, 2097152, W + OFF_SSUM, W + OFF_SSQ, 64);
    bn_fin_kernel<<<1, 256, 0, stream>>>(W + OFF_SSUM, W + OFF_SSQ, W + OFF_CG1, W + OFF_CBE1,
                                         W + OFF_SCALE, W + OFF_SHIFT, 64, 128, 1.f / 65536.f);
    bn_act_t_kernel<128><<<8192, 256, 0, stream>>>(U + UYT, 2097152, W + OFF_SCALE, W + OFF_SHIFT, 64, 0.2f);

    // ---- conv2 (MFMA) + tanh -> Z_t[0:64) ----
    conv2_mfma_kernel<<<512, 256, 0, stream>>>(U + UYT, U + UWC2, W + OFF_CB2, U + UZT);

    // ---- Z_t[64:168) ----
    assemble_z<<<6656, 256, 0, stream>>>(d_in[0], d_in[1], d_in[3], W + OFF_K12, U + UZT, FLG);

    // ---- gen deconv0 (MFMA): Z_t -> X_t(32,32,256) ----
    deconv_mfma2_kernel<192, 16, 256><<<512, 256, 0, stream>>>(U + UZT, U + UW0, W + OFF_GB0, U + UXT);
    stat_reduce_t<256><<<1024, 256, 0, stream>>>(U + UXT, 4194304, W + OFF_SSUM, W + OFF_SSQ, 192);
    bn_fin_kernel<<<1, 256, 0, stream>>>(W + OFF_SSUM, W + OFF_SSQ, W + OFF_GG0, W + OFF_GBE0,
                                         W + OFF_SCALE, W + OFF_SHIFT, 192, 256, 1.f / 65536.f);
    bn_act_t_kernel<256><<<16384, 256, 0, stream>>>(U + UXT, 4194304, W + OFF_SCALE, W + OFF_SHIFT, 192, 0.f);

    // ---- gen deconv1 (MFMA): X_t -> Y_t(64,64,128) ----
    deconv_mfma2_kernel<256, 32, 128><<<2048, 256, 0, stream>>>(U + UXT, U + UW1, W + OFF_GB1, U + UYT);
    stat_reduce_t<128><<<1024, 256, 0, stream>>>(U + UYT, 8388608, W + OFF_SSUM, W + OFF_SSQ, 448);
    bn_fin_kernel<<<1, 256, 0, stream>>>(W + OFF_SSUM, W + OFF_SSQ, W + OFF_GG1, W + OFF_GBE1,
                                         W + OFF_SCALE, W + OFF_SHIFT, 448, 128, 1.f / 262144.f);
    bn_act_t_kernel<128><<<32768, 256, 0, stream>>>(U + UYT, 8388608, W + OFF_SCALE, W + OFF_SHIFT, 448, 0.f);

    // ---- gen deconv2 + tanh -> d_out fp32 ----
    deconv2_out_t_kernel<<<dim3(16, 1, 64), 256, 0, stream>>>(U + UYT, W + OFF_WG2, W + OFF_GB2,
                                                              (float*)d_out);
}

// Round 9
// 793.791 us; speedup vs baseline: 13.1833x; 1.4738x over previous
//
#include <hip/hip_runtime.h>
#include <hip/hip_bf16.h>

#define TWO_PI_F 6.2831853071795864769f

typedef __attribute__((ext_vector_type(8))) __bf16 bf16x8;
typedef __attribute__((ext_vector_type(4))) float f32x4;

__device__ __forceinline__ float bf2f_raw(unsigned short u) {
    return __uint_as_float(((unsigned int)u) << 16);
}
__device__ __forceinline__ unsigned short f2bf(float f) {
    unsigned int u = __float_as_uint(f);
    unsigned int r = (u + 0x7FFFu + ((u >> 16) & 1u)) >> 16;   // RNE
    return (unsigned short)r;
}
__device__ __forceinline__ float loadIn(const void* p, size_t i, bool f32) {
    return f32 ? ((const float*)p)[i] : bf2f_raw(((const unsigned short*)p)[i]);
}

// ---------------- ws layout ----------------
static constexpr size_t OFF_WC0 = 0;          // cod_w0 fp32 3072
static constexpr size_t OFF_WG2 = 3072;       // gen_w2 fp32 6144 (legacy, unused)
static constexpr size_t OFF_P   = 9216;
static constexpr size_t OFF_CB0 = OFF_P + 0;
static constexpr size_t OFF_CG0 = OFF_P + 64;
static constexpr size_t OFF_CBE0= OFF_P + 128;
static constexpr size_t OFF_CB1 = OFF_P + 192;
static constexpr size_t OFF_CG1 = OFF_P + 320;
static constexpr size_t OFF_CBE1= OFF_P + 448;
static constexpr size_t OFF_CB2 = OFF_P + 576;
static constexpr size_t OFF_GB0 = OFF_P + 640;
static constexpr size_t OFF_GG0 = OFF_P + 896;
static constexpr size_t OFF_GBE0= OFF_P + 1152;
static constexpr size_t OFF_GB1 = OFF_P + 1408;
static constexpr size_t OFF_GG1 = OFF_P + 1536;
static constexpr size_t OFF_GBE1= OFF_P + 1664;
static constexpr size_t OFF_GB2 = OFF_P + 1792;
static constexpr size_t OFF_SSUM  = OFF_P + 2048;   // 576
static constexpr size_t OFF_SSQ   = OFF_SSUM + 576;
static constexpr size_t OFF_SCALE = OFF_SSUM + 1152;
static constexpr size_t OFF_SHIFT = OFF_SCALE + 576;
static constexpr size_t OFF_K12   = OFF_SHIFT + 576;
static constexpr size_t OFF_FLAG  = OFF_K12 + 1024;
static constexpr size_t FP32_END  = OFF_FLAG + 16;   // floats
// ushort regions:
static constexpr size_t UXT = 2 * FP32_END;            // X region: X_s2d (b,2,2,32,32,64) then X_t (b,32,32,256); 16777216
static constexpr size_t UYT = UXT + 16777216;          // Y region: Y_s2d (b,2,2,16,16,128) head, then Y_t (b,64,64,128); 33554432
static constexpr size_t UZT = UYT + 8388608;           // Z_t (b,16,16,192) = 3145728 (dead before Y_t write)
static constexpr size_t UW0 = UYT + 33554432;          // deconv0 pack 16*256*192 = 786432
static constexpr size_t UW1 = UW0 + 786432;            // deconv1 pack 16*128*256 = 524288
static constexpr size_t UWC1 = UW1 + 524288;           // conv1 pack 16*128*64 = 131072
static constexpr size_t UWC2 = UWC1 + 131072;          // conv2 pack 16*64*128 = 131072
static constexpr size_t UW2 = UWC2 + 131072;           // deconv2 pack 16*4*512 = 32768 (oc padded 3->16)
static constexpr size_t WS_END_USHORT = UW2 + 32768;
static constexpr size_t WS_NEED_BYTES = WS_END_USHORT * 2;   // ~109.9 MB

// stat slots: L0:0(64) L1:64(128) G0:192(256) G1:448(128)

// ---------------- input dtype detection ----------------
__global__ void detect_kernel(const unsigned short* __restrict__ imgs, int* __restrict__ flag) {
    int t = threadIdx.x;  // 256
    unsigned short u = imgs[t];
    int e = (u >> 7) & 0xFF;
    unsigned long long b = __ballot(e >= 0xC0);
    __shared__ int cnt[4];
    if ((t & 63) == 0) cnt[t >> 6] = __popcll(b);
    __syncthreads();
    if (t == 0) flag[0] = (cnt[0] + cnt[1] + cnt[2] + cnt[3] >= 4) ? 1 : 0;
}

// ---------------- small param -> fp32 conversion ----------------
struct CvtJobs {
    const void* src[16];
    float* dst[16];
    int off[17];
};

__global__ void cvt_all_kernel(CvtJobs J, int total, const int* __restrict__ flg) {
    int i = blockIdx.x * 256 + threadIdx.x;
    if (i >= total) return;
    bool f32 = flg[0] != 0;
    int k = 0;
#pragma unroll
    for (int t = 0; t < 15; ++t) { if (i >= J.off[t + 1]) k = t + 1; }
    int r = i - J.off[k];
    J.dst[k][r] = loadIn(J.src[k], r, f32);
}

__global__ void zero_kernel(float* p, int n) {
    int i = blockIdx.x * 256 + threadIdx.x;
    if (i < n) p[i] = 0.f;
}

// ---------------- deconv weight packing: wave-coalesced B fragments ----------------
// dst[(((ktap*NOCT+oct)*NK + kc)*4 + j)*512 + lane*8 + jj] = w_deconv[ic][oc][ktap]
__global__ void pack_w2_kernel(const void* __restrict__ src, unsigned short* __restrict__ dst,
                               int ICreal, int ICP, int OC, const int* __restrict__ flg) {
    bool f32 = flg[0] != 0;
    int i = blockIdx.x * 256 + threadIdx.x;
    int total = 16 * OC * ICP;
    if (i >= total) return;
    int jj = i & 7;
    int lane = (i >> 3) & 63;
    int j = (i >> 9) & 3;
    int t3 = i >> 11;
    int NK = ICP / 32;
    int kc = t3 % NK;
    int t4 = t3 / NK;
    int NOCT = OC / 64;
    int oct = t4 % NOCT;
    int ktap = t4 / NOCT;
    int kq = lane >> 4, n = lane & 15;
    int ic = kc * 32 + kq * 8 + jj;
    int oc = oct * 64 + j * 16 + n;
    unsigned short v = 0;
    if (ic < ICreal) v = f2bf(loadIn(src, ((size_t)(ic * OC + oc) << 4) + ktap, f32));
    dst[i] = v;
}

// ---------------- deconv2 (small-OC) packing: dst[(ktap*NK+kc)*512 + lane*8 + jj], oc=n (pad 3->16) ----------------
__global__ void pack_w2s_kernel(const void* __restrict__ src, unsigned short* __restrict__ dst,
                                int ICP, int OCreal, const int* __restrict__ flg) {
    bool f32 = flg[0] != 0;
    int i = blockIdx.x * 256 + threadIdx.x;
    int NK = ICP / 32;
    int total = 16 * NK * 512;
    if (i >= total) return;
    int jj = i & 7;
    int lane = (i >> 3) & 63;
    int t3 = i >> 9;
    int kc = t3 % NK;
    int ktap = t3 / NK;
    int kq = lane >> 4, n = lane & 15;
    int ic = kc * 32 + kq * 8 + jj;
    unsigned short v = 0;
    if (n < OCreal) v = f2bf(loadIn(src, ((size_t)(ic * OCreal + n) << 4) + ktap, f32));
    dst[i] = v;
}

// ---------------- conv weight packing (w layout (OC,IC,4,4)) ----------------
__global__ void pack_wc_kernel(const void* __restrict__ src, unsigned short* __restrict__ dst,
                               int IC, int OC, const int* __restrict__ flg) {
    bool f32 = flg[0] != 0;
    int i = blockIdx.x * 256 + threadIdx.x;
    int total = 16 * OC * IC;
    if (i >= total) return;
    int jj = i & 7;
    int lane = (i >> 3) & 63;
    int j = (i >> 9) & 3;
    int t3 = i >> 11;
    int NK = IC / 32;
    int kc = t3 % NK;
    int t4 = t3 / NK;
    int NOCT = OC / 64;
    int oct = t4 % NOCT;
    int ktap = t4 / NOCT;
    int kq = lane >> 4, n = lane & 15;
    int ic = kc * 32 + kq * 8 + jj;
    int oc = oct * 64 + j * 16 + n;
    dst[i] = f2bf(loadIn(src, ((size_t)(oc * IC + ic) << 4) + ktap, f32));
}

// ---------------- tiny MLP ----------------
__global__ void mlp_kernel(const void* __restrict__ Zg,
                           const void* __restrict__ lW, const void* __restrict__ lb,
                           const void* __restrict__ l1W, const void* __restrict__ l1b,
                           const void* __restrict__ l2W, const void* __restrict__ l2b,
                           float* __restrict__ K12, const int* __restrict__ flg) {
    bool f32 = flg[0] != 0;
    int b = blockIdx.x;
    int t = threadIdx.x;  // 64
    __shared__ float xs[64];
    float acc = loadIn(lb, t, f32);
    for (int c = 0; c < 64; ++c)
        acc += loadIn(Zg, (size_t)(b * 64 + c) * 256, f32) * loadIn(lW, t * 64 + c, f32);
    xs[t] = fmaxf(acc, 0.f);
    __syncthreads();
    if (t < 16) {
        int p = t & 7;
        const void* Wp = (t < 8) ? l1W : l2W;
        const void* bp = (t < 8) ? l1b : l2b;
        float a = loadIn(bp, p, f32);
        for (int h = 0; h < 64; ++h) a += xs[h] * loadIn(Wp, p * 64 + h, f32);
        K12[b * 16 + t] = a;
    }
}

// ---------------- conv0: imgs (b,3,128,128) -> X_s2d (b,2,2,32,32,64), vector, LDS-tiled ----------------
__global__ void conv0_s2d_kernel(const void* __restrict__ imgs, const float* __restrict__ w,
                                 const float* __restrict__ bias, unsigned short* __restrict__ xs,
                                 const int* __restrict__ flg) {
    bool f32 = flg[0] != 0;
    int b = blockIdx.z;
    int tile = blockIdx.x;                 // 16 tiles: 4x4 of 16x16 output px
    int Y0 = (tile >> 2) * 16, X0 = (tile & 3) * 16;
    __shared__ float vin[3 * 34 * 35];
    __shared__ float wl[64 * 49];
    for (int i = threadIdx.x; i < 3 * 34 * 34; i += 256) {
        int c = i % 34; int t = i / 34; int r = t % 34; int ic = t / 34;
        int iy = 2 * Y0 - 1 + r, ix = 2 * X0 - 1 + c;
        float v = 0.f;
        if (((unsigned)iy < 128u) & ((unsigned)ix < 128u))
            v = loadIn(imgs, ((size_t)(b * 3 + ic) * 128 + iy) * 128 + ix, f32);
        vin[(ic * 34 + r) * 35 + c] = v;
    }
    for (int i = threadIdx.x; i < 3072; i += 256) {
        int oc = i / 48, idx = i % 48;
        wl[oc * 49 + idx] = w[i];
    }
    __syncthreads();
    int q = threadIdx.x >> 2;              // 64 quads
    int ocq = threadIdx.x & 3;
    int qy = q >> 3, qx = q & 7;
    float acc[4][16];
#pragma unroll
    for (int p = 0; p < 4; ++p)
#pragma unroll
        for (int o = 0; o < 16; ++o) acc[p][o] = 0.f;
    for (int ic = 0; ic < 3; ++ic) {
        float v[6][6];
#pragma unroll
        for (int r = 0; r < 6; ++r)
#pragma unroll
            for (int c = 0; c < 6; ++c)
                v[r][c] = vin[(ic * 34 + 4 * qy + r) * 35 + 4 * qx + c];
#pragma unroll
        for (int o = 0; o < 16; ++o) {
            const float* wo = wl + (ocq * 16 + o) * 49 + ic * 16;
#pragma unroll
            for (int ky = 0; ky < 4; ++ky)
#pragma unroll
                for (int kx = 0; kx < 4; ++kx) {
                    float wv = wo[ky * 4 + kx];
                    acc[0][o] = fmaf(v[ky][kx], wv, acc[0][o]);
                    acc[1][o] = fmaf(v[ky][kx + 2], wv, acc[1][o]);
                    acc[2][o] = fmaf(v[ky + 2][kx], wv, acc[2][o]);
                    acc[3][o] = fmaf(v[ky + 2][kx + 2], wv, acc[3][o]);
                }
        }
    }
    int j = (Y0 >> 1) + qy, i2 = (X0 >> 1) + qx;
#pragma unroll
    for (int p = 0; p < 4; ++p) {
        int dy = p >> 1, dx = p & 1;
        unsigned short tmp[16];
#pragma unroll
        for (int o = 0; o < 16; ++o) tmp[o] = f2bf(acc[p][o] + bias[ocq * 16 + o]);
        unsigned short* dst = xs + (((size_t)((b * 2 + dy) * 2 + dx) * 32 + j) * 32 + i2) * 64 + ocq * 16;
        *(uint4*)(dst) = *(const uint4*)(tmp);
        *(uint4*)(dst + 8) = *(const uint4*)(tmp + 8);
    }
}

// ---------------- conv1 (MFMA): X_s2d (b,2,2,32,32,64) -> Y_s2d (b,2,2,16,16,128) ----------------
__global__ void conv1_mfma_kernel(const unsigned short* __restrict__ xs,
                                  const unsigned short* __restrict__ wp,
                                  const float* __restrict__ bias,
                                  unsigned short* __restrict__ ys) {
    constexpr int STR = 72;                        // 64 + 8 pad
    __shared__ unsigned short lds[4 * 3 * 17 * STR];   // 29.4 KB
    int bid = blockIdx.x;
    int xt = bid & 1;
    int qp = (bid >> 1) & 15;
    int b = bid >> 5;
    int oy0 = qp * 2, x0 = xt * 16;
    for (int i = threadIdx.x; i < 1632; i += 256) {
        int icc = i & 7; int t = i >> 3;
        int col = t % 17; int rc = t / 17;
        int row = rc % 3; int pl = rc / 3;
        int py = pl >> 1, px = pl & 1;
        int j = oy0 - py + row;
        int ci = x0 - px + col;
        uint4 v = {0u, 0u, 0u, 0u};
        if (((unsigned)j < 32u) & ((unsigned)ci < 32u))
            v = *(const uint4*)(xs + ((size_t)((b * 4 + pl) * 32 + j) * 32 + ci) * 64 + icc * 8);
        *(uint4*)(lds + ((pl * 3 + row) * 17 + col) * STR + icc * 8) = v;
    }
    __syncthreads();

    int wv = threadIdx.x >> 6, lane = threadIdx.x & 63;
    int r = wv >> 1, oct = wv & 1;
    int m = lane & 15, kq = lane >> 4;
    f32x4 acc[4];
#pragma unroll
    for (int j = 0; j < 4; ++j) acc[j] = (f32x4){0.f, 0.f, 0.f, 0.f};

#pragma unroll
    for (int ky = 0; ky < 4; ++ky) {
        int py = (ky & 1) ^ 1;
        int lrow = r + (ky >> 1);
#pragma unroll
        for (int kx = 0; kx < 4; ++kx) {
            int px = (kx & 1) ^ 1;
            int pl = py * 2 + px;
            int lcol = m + (kx >> 1);
            const unsigned short* lp = lds + ((pl * 3 + lrow) * 17 + lcol) * STR + kq * 8;
            int ktap = ky * 4 + kx;
            const unsigned short* bb = wp + (size_t)(ktap * 2 + oct) * 4096;
#pragma unroll
            for (int kc = 0; kc < 2; ++kc) {
                bf16x8 a = *(const bf16x8*)(lp + kc * 32);
                const unsigned short* bk = bb + kc * 2048 + lane * 8;
                bf16x8 b0 = *(const bf16x8*)(bk);
                bf16x8 b1 = *(const bf16x8*)(bk + 512);
                bf16x8 b2 = *(const bf16x8*)(bk + 1024);
                bf16x8 b3 = *(const bf16x8*)(bk + 1536);
                acc[0] = __builtin_amdgcn_mfma_f32_16x16x32_bf16(a, b0, acc[0], 0, 0, 0);
                acc[1] = __builtin_amdgcn_mfma_f32_16x16x32_bf16(a, b1, acc[1], 0, 0, 0);
                acc[2] = __builtin_amdgcn_mfma_f32_16x16x32_bf16(a, b2, acc[2], 0, 0, 0);
                acc[3] = __builtin_amdgcn_mfma_f32_16x16x32_bf16(a, b3, acc[3], 0, 0, 0);
            }
        }
    }
    int oy = oy0 + r;
    int pyo = oy & 1, jo = oy >> 1;
    int n = m;
    float bv0 = bias[oct * 64 + n], bv1 = bias[oct * 64 + 16 + n];
    float bv2 = bias[oct * 64 + 32 + n], bv3 = bias[oct * 64 + 48 + n];
#pragma unroll
    for (int reg = 0; reg < 4; ++reg) {
        int mm = kq * 4 + reg;
        int ox = x0 + mm;
        int pxo = ox & 1, io = ox >> 1;
        size_t base = (((size_t)((b * 2 + pyo) * 2 + pxo) * 16 + jo) * 16 + io) * 128 + oct * 64 + n;
        ys[base]      = f2bf(acc[0][reg] + bv0);
        ys[base + 16] = f2bf(acc[1][reg] + bv1);
        ys[base + 32] = f2bf(acc[2][reg] + bv2);
        ys[base + 48] = f2bf(acc[3][reg] + bv3);
    }
}

// ---------------- conv2 (MFMA) + tanh: Y_s2d (b,2,2,16,16,128) -> Z_t (b,16,16,192)[0:64) ----------------
__global__ void conv2_mfma_kernel(const unsigned short* __restrict__ ys,
                                  const unsigned short* __restrict__ wp,
                                  const float* __restrict__ bias,
                                  unsigned short* __restrict__ zt) {
    constexpr int STR = 136;                       // 128 + 8 pad
    __shared__ unsigned short lds[4 * 3 * 17 * STR];   // 55.5 KB
    int bid = blockIdx.x;
    int qp = bid & 7;
    int b = bid >> 3;
    int oy0 = qp * 2;
    for (int i = threadIdx.x; i < 3264; i += 256) {
        int icc = i & 15; int t = i >> 4;
        int col = t % 17; int rc = t / 17;
        int row = rc % 3; int pl = rc / 3;
        int py = pl >> 1, px = pl & 1;
        int j = oy0 - py + row;
        int ci = col - px;
        uint4 v = {0u, 0u, 0u, 0u};
        if (((unsigned)j < 16u) & ((unsigned)ci < 16u))
            v = *(const uint4*)(ys + ((size_t)((b * 4 + pl) * 16 + j) * 16 + ci) * 128 + icc * 8);
        *(uint4*)(lds + ((pl * 3 + row) * 17 + col) * STR + icc * 8) = v;
    }
    __syncthreads();

    int wv = threadIdx.x >> 6, lane = threadIdx.x & 63;
    int r = wv >> 1, jh = wv & 1;
    int m = lane & 15, kq = lane >> 4;
    f32x4 acc[2];
    acc[0] = (f32x4){0.f, 0.f, 0.f, 0.f};
    acc[1] = acc[0];
#pragma unroll
    for (int ky = 0; ky < 4; ++ky) {
        int py = (ky & 1) ^ 1;
        int lrow = r + (ky >> 1);
#pragma unroll
        for (int kx = 0; kx < 4; ++kx) {
            int px = (kx & 1) ^ 1;
            int pl = py * 2 + px;
            int lcol = m + (kx >> 1);
            const unsigned short* lp = lds + ((pl * 3 + lrow) * 17 + lcol) * STR + kq * 8;
            int ktap = ky * 4 + kx;
            const unsigned short* bb = wp + (size_t)ktap * 8192;
#pragma unroll
            for (int kc = 0; kc < 4; ++kc) {
                bf16x8 a = *(const bf16x8*)(lp + kc * 32);
                const unsigned short* bk = bb + kc * 2048 + (jh * 2) * 512 + lane * 8;
                bf16x8 b0 = *(const bf16x8*)(bk);
                bf16x8 b1 = *(const bf16x8*)(bk + 512);
                acc[0] = __builtin_amdgcn_mfma_f32_16x16x32_bf16(a, b0, acc[0], 0, 0, 0);
                acc[1] = __builtin_amdgcn_mfma_f32_16x16x32_bf16(a, b1, acc[1], 0, 0, 0);
            }
        }
    }
    int oy = oy0 + r;
    int n = m;
    float bv0 = bias[(jh * 2) * 16 + n], bv1 = bias[(jh * 2 + 1) * 16 + n];
#pragma unroll
    for (int reg = 0; reg < 4; ++reg) {
        int x = kq * 4 + reg;
        size_t base = ((size_t)(b * 16 + oy) * 16 + x) * 192 + (jh * 2) * 16 + n;
        zt[base]      = f2bf(tanhf(acc[0][reg] + bv0));
        zt[base + 16] = f2bf(tanhf(acc[1][reg] + bv1));
    }
}

// ---------------- assemble Z_t[...][64:168) ----------------
__global__ void assemble_z(const void* __restrict__ Zl, const void* __restrict__ Zg,
                           const void* __restrict__ phi, const float* __restrict__ K12,
                           unsigned short* __restrict__ zt, const int* __restrict__ flg) {
    bool f32 = flg[0] != 0;
    int i = blockIdx.x * 256 + threadIdx.x;
    const int TOT = 64 * 104 * 256;
    if (i >= TOT) return;
    int pos = i & 255;
    int t = i >> 8;
    int c104 = t % 104;
    int b = t / 104;
    float val;
    if (c104 < 32) {
        val = loadIn(Zl, ((size_t)(b * 32 + c104) << 8) + pos, f32);
    } else if (c104 < 96) {
        val = loadIn(Zg, ((size_t)(b * 64 + (c104 - 32)) << 8) + pos, f32);
    } else {
        int p = c104 - 96;
        int y = pos >> 4, x = pos & 15;
        float k1 = K12[b * 16 + p];
        float k2 = K12[b * 16 + 8 + p];
        val = sinf(k1 * (float)y + k2 * (float)x + loadIn(phi, b * 8 + p, f32) * TWO_PI_F);
    }
    zt[((size_t)(b * 256 + pos)) * 192 + 64 + c104] = f2bf(val);
}

// ---------------- MFMA transposed-conv v2 (verified) ----------------
template <int ICP, int Q, int OC>
__global__ void deconv_mfma2_kernel(const unsigned short* __restrict__ in_t,
                                    const unsigned short* __restrict__ wp2,
                                    const float* __restrict__ bias,
                                    unsigned short* __restrict__ out_t) {
    constexpr int NOCT = OC / 64;
    constexpr int NK = ICP / 32;
    constexpr int XT = Q / 16;
    constexpr int NQB = Q / 2;
    constexpr int STRIDE = ICP + 8;
    __shared__ unsigned short lds[4 * 18 * STRIDE];

    int bid = blockIdx.x;
    int xt = bid % XT;
    int t2 = bid / XT;
    int qp = t2 % NQB;
    int b = t2 / NQB;
    int qy0 = qp * 2;
    int x0 = xt * 16;

    constexpr int P8 = ICP / 8;
    constexpr int E8 = 4 * 18 * P8;
    for (int i = threadIdx.x; i < E8; i += 256) {
        int icc = i % P8;
        int rc = i / P8;
        int row = rc / 18, col = rc % 18;
        int y = qy0 - 1 + row, x = x0 - 1 + col;
        uint4 val = {0u, 0u, 0u, 0u};
        if (((unsigned)y < (unsigned)Q) & ((unsigned)x < (unsigned)Q))
            val = *(const uint4*)(in_t + (size_t)((b * Q + y) * Q + x) * ICP + icc * 8);
        *(uint4*)(lds + rc * STRIDE + icc * 8) = val;
    }
    __syncthreads();

    int wv = threadIdx.x >> 6, lane = threadIdx.x & 63;
    int dy = wv >> 1, dx = wv & 1;
    int m = lane & 15, kq = lane >> 4;

    for (int oct = 0; oct < NOCT; ++oct) {
        f32x4 acc[2][4];
#pragma unroll
        for (int q = 0; q < 2; ++q)
#pragma unroll
            for (int j = 0; j < 4; ++j) acc[q][j] = (f32x4){0.f, 0.f, 0.f, 0.f};

#pragma unroll
        for (int t = 0; t < 4; ++t) {
            int rr = t >> 1, cc = t & 1;
            int ktap = ((3 - dy) - 2 * rr) * 4 + ((3 - dx) - 2 * cc);
            int col = m + dx + cc;
            int row0 = dy + rr;
            const unsigned short* bbase = wp2 + (size_t)((ktap * NOCT + oct) * NK) * 2048;
#pragma unroll
            for (int kc = 0; kc < NK; ++kc) {
                bf16x8 a0 = *(const bf16x8*)(lds + (row0 * 18 + col) * STRIDE + kc * 32 + kq * 8);
                bf16x8 a1 = *(const bf16x8*)(lds + ((row0 + 1) * 18 + col) * STRIDE + kc * 32 + kq * 8);
                bf16x8 b0 = *(const bf16x8*)(bbase + (kc * 4 + 0) * 512 + lane * 8);
                bf16x8 b1 = *(const bf16x8*)(bbase + (kc * 4 + 1) * 512 + lane * 8);
                bf16x8 b2 = *(const bf16x8*)(bbase + (kc * 4 + 2) * 512 + lane * 8);
                bf16x8 b3 = *(const bf16x8*)(bbase + (kc * 4 + 3) * 512 + lane * 8);
                acc[0][0] = __builtin_amdgcn_mfma_f32_16x16x32_bf16(a0, b0, acc[0][0], 0, 0, 0);
                acc[0][1] = __builtin_amdgcn_mfma_f32_16x16x32_bf16(a0, b1, acc[0][1], 0, 0, 0);
                acc[0][2] = __builtin_amdgcn_mfma_f32_16x16x32_bf16(a0, b2, acc[0][2], 0, 0, 0);
                acc[0][3] = __builtin_amdgcn_mfma_f32_16x16x32_bf16(a0, b3, acc[0][3], 0, 0, 0);
                acc[1][0] = __builtin_amdgcn_mfma_f32_16x16x32_bf16(a1, b0, acc[1][0], 0, 0, 0);
                acc[1][1] = __builtin_amdgcn_mfma_f32_16x16x32_bf16(a1, b1, acc[1][1], 0, 0, 0);
                acc[1][2] = __builtin_amdgcn_mfma_f32_16x16x32_bf16(a1, b2, acc[1][2], 0, 0, 0);
                acc[1][3] = __builtin_amdgcn_mfma_f32_16x16x32_bf16(a1, b3, acc[1][3], 0, 0, 0);
            }
        }
        int n = m;
        float bv0 = bias[oct * 64 + n];
        float bv1 = bias[oct * 64 + 16 + n];
        float bv2 = bias[oct * 64 + 32 + n];
        float bv3 = bias[oct * 64 + 48 + n];
#pragma unroll
        for (int qyl = 0; qyl < 2; ++qyl) {
            int oy = 2 * (qy0 + qyl) + dy;
#pragma unroll
            for (int reg = 0; reg < 4; ++reg) {
                int mm = kq * 4 + reg;
                int ox = 2 * (x0 + mm) + dx;
                size_t base = ((size_t)((b * 2 * Q + oy) * (2 * Q) + ox)) * OC + oct * 64 + n;
                out_t[base]      = f2bf(acc[qyl][0][reg] + bv0);
                out_t[base + 16] = f2bf(acc[qyl][1][reg] + bv1);
                out_t[base + 32] = f2bf(acc[qyl][2][reg] + bv2);
                out_t[base + 48] = f2bf(acc[qyl][3][reg] + bv3);
            }
        }
    }
}

// ---------------- deconv2 (MFMA, OC=3 padded to 16) + tanh -> fp32 NCHW d_out ----------------
__global__ void deconv2_mfma_kernel(const unsigned short* __restrict__ yt,   // (64,64,64,128)
                                    const unsigned short* __restrict__ wp,   // pack_w2s
                                    const float* __restrict__ bias,
                                    float* __restrict__ outp) {
    constexpr int Q = 64, ICP = 128, NK = 4, STRIDE = 136;
    __shared__ unsigned short lds[4 * 18 * STRIDE];   // 19.6 KB
    int bid = blockIdx.x;
    int xt = bid & 3;
    int t2 = bid >> 2;
    int qp = t2 & 31;
    int b = t2 >> 5;
    int qy0 = qp * 2, x0 = xt * 16;

    for (int i = threadIdx.x; i < 4 * 18 * 16; i += 256) {
        int icc = i & 15;
        int rc = i >> 4;
        int row = rc / 18, col = rc % 18;
        int y = qy0 - 1 + row, x = x0 - 1 + col;
        uint4 v = {0u, 0u, 0u, 0u};
        if (((unsigned)y < (unsigned)Q) & ((unsigned)x < (unsigned)Q))
            v = *(const uint4*)(yt + (size_t)((b * Q + y) * Q + x) * ICP + icc * 8);
        *(uint4*)(lds + rc * STRIDE + icc * 8) = v;
    }
    __syncthreads();

    int wv = threadIdx.x >> 6, lane = threadIdx.x & 63;
    int dy = wv >> 1, dx = wv & 1;
    int m = lane & 15, kq = lane >> 4;
    f32x4 acc0 = {0.f, 0.f, 0.f, 0.f}, acc1 = acc0;

#pragma unroll
    for (int t = 0; t < 4; ++t) {
        int rr = t >> 1, cc = t & 1;
        int ktap = ((3 - dy) - 2 * rr) * 4 + ((3 - dx) - 2 * cc);
        int col = m + dx + cc;
        int row0 = dy + rr;
        const unsigned short* bb = wp + (size_t)(ktap * NK) * 512;
#pragma unroll
        for (int kc = 0; kc < NK; ++kc) {
            bf16x8 a0 = *(const bf16x8*)(lds + (row0 * 18 + col) * STRIDE + kc * 32 + kq * 8);
            bf16x8 a1 = *(const bf16x8*)(lds + ((row0 + 1) * 18 + col) * STRIDE + kc * 32 + kq * 8);
            bf16x8 b0 = *(const bf16x8*)(bb + kc * 512 + lane * 8);
            acc0 = __builtin_amdgcn_mfma_f32_16x16x32_bf16(a0, b0, acc0, 0, 0, 0);
            acc1 = __builtin_amdgcn_mfma_f32_16x16x32_bf16(a1, b0, acc1, 0, 0, 0);
        }
    }
    int n = m;
    if (n < 3) {
        float bv = bias[n];
#pragma unroll
        for (int reg = 0; reg < 4; ++reg) {
            int mm = kq * 4 + reg;
            int ox = 2 * (x0 + mm) + dx;
            int oy0_ = 2 * qy0 + dy;
            size_t ob = (size_t)(b * 3 + n) * 16384;
            outp[ob + (size_t)oy0_ * 128 + ox]       = tanhf(acc0[reg] + bv);
            outp[ob + (size_t)(oy0_ + 2) * 128 + ox] = tanhf(acc1[reg] + bv);
        }
    }
}

// ---------------- channel-last BN stat reduction ----------------
template <int C>
__global__ void stat_reduce_t(const unsigned short* __restrict__ x, int total4,
                              float* __restrict__ ssum, float* __restrict__ ssq, int statoff) {
    __shared__ float ls[C], lq[C];
    for (int c = threadIdx.x; c < C; c += 256) { ls[c] = 0.f; lq[c] = 0.f; }
    __syncthreads();
    int i0 = blockIdx.x * 256 + threadIdx.x;
    int stride = gridDim.x * 256;
    int c0 = (i0 << 2) & (C - 1);
    float s0 = 0, s1 = 0, s2 = 0, s3 = 0, q0 = 0, q1 = 0, q2 = 0, q3 = 0;
    for (int i = i0; i < total4; i += stride) {
        ushort4 v = *(const ushort4*)(x + ((size_t)i << 2));
        float f0 = bf2f_raw(v.x), f1 = bf2f_raw(v.y), f2 = bf2f_raw(v.z), f3 = bf2f_raw(v.w);
        s0 += f0; s1 += f1; s2 += f2; s3 += f3;
        q0 += f0 * f0; q1 += f1 * f1; q2 += f2 * f2; q3 += f3 * f3;
    }
    atomicAdd(&ls[c0], s0); atomicAdd(&ls[c0 + 1], s1); atomicAdd(&ls[c0 + 2], s2); atomicAdd(&ls[c0 + 3], s3);
    atomicAdd(&lq[c0], q0); atomicAdd(&lq[c0 + 1], q1); atomicAdd(&lq[c0 + 2], q2); atomicAdd(&lq[c0 + 3], q3);
    __syncthreads();
    for (int c = threadIdx.x; c < C; c += 256) {
        atomicAdd(&ssum[statoff + c], ls[c]);
        atomicAdd(&ssq[statoff + c], lq[c]);
    }
}

// ---------------- BN finalize ----------------
__global__ void bn_fin_kernel(const float* __restrict__ ssum, const float* __restrict__ ssq,
                              const float* __restrict__ g, const float* __restrict__ be,
                              float* __restrict__ scale, float* __restrict__ shift,
                              int statoff, int C, float invN) {
    int c = threadIdx.x;
    if (c >= C) return;
    float m = ssum[statoff + c] * invN;
    float v = ssq[statoff + c] * invN - m * m;
    v = fmaxf(v, 0.f);
    float sc = g[c] * rsqrtf(v + 1e-5f);
    scale[statoff + c] = sc;
    shift[statoff + c] = be[c] - m * sc;
}

// ---------------- BN affine + (leaky)relu, channel-LAST ----------------
template <int C>
__global__ void bn_act_t_kernel(unsigned short* __restrict__ x, int total4,
                                const float* __restrict__ scale, const float* __restrict__ shift,
                                int statoff, float slope) {
    int i = blockIdx.x * 256 + threadIdx.x;
    if (i >= total4) return;
    int c0 = (i << 2) & (C - 1);
    float4 sc = *(const float4*)(scale + statoff + c0);
    float4 sh = *(const float4*)(shift + statoff + c0);
    ushort4 v = *(ushort4*)(x + ((size_t)i << 2));
    float f0 = bf2f_raw(v.x) * sc.x + sh.x; f0 = f0 > 0.f ? f0 : slope * f0;
    float f1 = bf2f_raw(v.y) * sc.y + sh.y; f1 = f1 > 0.f ? f1 : slope * f1;
    float f2 = bf2f_raw(v.z) * sc.z + sh.z; f2 = f2 > 0.f ? f2 : slope * f2;
    float f3 = bf2f_raw(v.w) * sc.w + sh.w; f3 = f3 > 0.f ? f3 : slope * f3;
    v.x = f2bf(f0); v.y = f2bf(f1); v.z = f2bf(f2); v.w = f2bf(f3);
    *(ushort4*)(x + ((size_t)i << 2)) = v;
}

extern "C" void kernel_launch(void* const* d_in, const int* in_sizes, int n_in,
                              void* d_out, int out_size, void* d_ws, size_t ws_size,
                              hipStream_t stream) {
    if (ws_size < WS_NEED_BYTES) {
        hipMemsetAsync(d_out, 0, (size_t)out_size * 4, stream);
        return;
    }

    float* W = (float*)d_ws;
    unsigned short* U = (unsigned short*)d_ws;
    int* FLG = (int*)(W + OFF_FLAG);

    detect_kernel<<<1, 256, 0, stream>>>((const unsigned short*)d_in[2], FLG);

    // small fp32 conversions: cod_w0, gen_w2(unused but cheap), all bias/gamma/beta
    CvtJobs J;
    const int srcIdx[16] = {10, 28, 11, 12, 13, 15, 16, 17, 19, 21, 22, 23, 25, 26, 27, 29};
    const int cnt[16]    = {3072, 6144, 64, 64, 64, 128, 128, 128, 64, 256, 256, 256, 128, 128, 128, 3};
    float* dsts[16] = {W + OFF_WC0, W + OFF_WG2,
                       W + OFF_CB0, W + OFF_CG0, W + OFF_CBE0, W + OFF_CB1, W + OFF_CG1, W + OFF_CBE1,
                       W + OFF_CB2, W + OFF_GB0, W + OFF_GG0, W + OFF_GBE0, W + OFF_GB1, W + OFF_GG1,
                       W + OFF_GBE1, W + OFF_GB2};
    int off = 0;
    for (int k = 0; k < 16; ++k) {
        J.src[k] = d_in[srcIdx[k]];
        J.dst[k] = dsts[k];
        J.off[k] = off;
        off += cnt[k];
    }
    J.off[16] = off;
    cvt_all_kernel<<<(off + 255) / 256, 256, 0, stream>>>(J, off, FLG);

    zero_kernel<<<5, 256, 0, stream>>>(W + OFF_SSUM, 1152);
    zero_kernel<<<6144, 256, 0, stream>>>((float*)(U + UZT), 1572864);   // Z_t incl. pad ch

    // weight packs
    pack_w2_kernel<<<3072, 256, 0, stream>>>(d_in[20], U + UW0, 168, 192, 256, FLG);
    pack_w2_kernel<<<2048, 256, 0, stream>>>(d_in[24], U + UW1, 256, 256, 128, FLG);
    pack_wc_kernel<<<512, 256, 0, stream>>>(d_in[14], U + UWC1, 64, 128, FLG);
    pack_wc_kernel<<<512, 256, 0, stream>>>(d_in[18], U + UWC2, 128, 64, FLG);
    pack_w2s_kernel<<<128, 256, 0, stream>>>(d_in[28], U + UW2, 128, 3, FLG);

    mlp_kernel<<<64, 64, 0, stream>>>(d_in[1], d_in[4], d_in[5], d_in[6], d_in[7],
                                      d_in[8], d_in[9], W + OFF_K12, FLG);

    // ---- conv0 -> X_s2d ----
    conv0_s2d_kernel<<<dim3(16, 1, 64), 256, 0, stream>>>(d_in[2], W + OFF_WC0, W + OFF_CB0,
                                                          U + UXT, FLG);
    stat_reduce_t<64><<<1024, 256, 0, stream>>>(U + UXT, 4194304, W + OFF_SSUM, W + OFF_SSQ, 0);
    bn_fin_kernel<<<1, 256, 0, stream>>>(W + OFF_SSUM, W + OFF_SSQ, W + OFF_CG0, W + OFF_CBE0,
                                         W + OFF_SCALE, W + OFF_SHIFT, 0, 64, 1.f / 262144.f);
    bn_act_t_kernel<64><<<16384, 256, 0, stream>>>(U + UXT, 4194304, W + OFF_SCALE, W + OFF_SHIFT, 0, 0.2f);

    // ---- conv1 (MFMA) -> Y_s2d ----
    conv1_mfma_kernel<<<2048, 256, 0, stream>>>(U + UXT, U + UWC1, W + OFF_CB1, U + UYT);
    stat_reduce_t<128><<<1024, 256, 0, stream>>>(U + UYT, 2097152, W + OFF_SSUM, W + OFF_SSQ, 64);
    bn_fin_kernel<<<1, 256, 0, stream>>>(W + OFF_SSUM, W + OFF_SSQ, W + OFF_CG1, W + OFF_CBE1,
                                         W + OFF_SCALE, W + OFF_SHIFT, 64, 128, 1.f / 65536.f);
    bn_act_t_kernel<128><<<8192, 256, 0, stream>>>(U + UYT, 2097152, W + OFF_SCALE, W + OFF_SHIFT, 64, 0.2f);

    // ---- conv2 (MFMA) + tanh -> Z_t[0:64) ----
    conv2_mfma_kernel<<<512, 256, 0, stream>>>(U + UYT, U + UWC2, W + OFF_CB2, U + UZT);

    // ---- Z_t[64:168) ----
    assemble_z<<<6656, 256, 0, stream>>>(d_in[0], d_in[1], d_in[3], W + OFF_K12, U + UZT, FLG);

    // ---- gen deconv0 (MFMA): Z_t -> X_t(32,32,256) ----
    deconv_mfma2_kernel<192, 16, 256><<<512, 256, 0, stream>>>(U + UZT, U + UW0, W + OFF_GB0, U + UXT);
    stat_reduce_t<256><<<1024, 256, 0, stream>>>(U + UXT, 4194304, W + OFF_SSUM, W + OFF_SSQ, 192);
    bn_fin_kernel<<<1, 256, 0, stream>>>(W + OFF_SSUM, W + OFF_SSQ, W + OFF_GG0, W + OFF_GBE0,
                                         W + OFF_SCALE, W + OFF_SHIFT, 192, 256, 1.f / 65536.f);
    bn_act_t_kernel<256><<<16384, 256, 0, stream>>>(U + UXT, 4194304, W + OFF_SCALE, W + OFF_SHIFT, 192, 0.f);

    // ---- gen deconv1 (MFMA): X_t -> Y_t(64,64,128) ----
    deconv_mfma2_kernel<256, 32, 128><<<2048, 256, 0, stream>>>(U + UXT, U + UW1, W + OFF_GB1, U + UYT);
    stat_reduce_t<128><<<1024, 256, 0, stream>>>(U + UYT, 8388608, W + OFF_SSUM, W + OFF_SSQ, 448);
    bn_fin_kernel<<<1, 256, 0, stream>>>(W + OFF_SSUM, W + OFF_SSQ, W + OFF_GG1, W + OFF_GBE1,
                                         W + OFF_SCALE, W + OFF_SHIFT, 448, 128, 1.f / 262144.f);
    bn_act_t_kernel<128><<<32768, 256, 0, stream>>>(U + UYT, 8388608, W + OFF_SCALE, W + OFF_SHIFT, 448, 0.f);

    // ---- gen deconv2 (MFMA) + tanh -> d_out fp32 ----
    deconv2_mfma_kernel<<<8192, 256, 0, stream>>>(U + UYT, U + UW2, W + OFF_GB2, (float*)d_out);
}